// Round 4
// baseline (1360.688 us; speedup 1.0000x reference)
//
#include <hip/hip_runtime.h>
#include <cstdint>
#include <cstddef>

// RWKV-7 Tmix forward, MI355X gfx950 — ROUND 8: v-split scan + DPP butterflies.
// Round-7: scan = 470 µs (~1100 cy/step): 4 ds_swizzle lgkmcnt(0) stalls on the
// serial chain + 84 LDS-read instr/step through ONE CU's LDS pipe (4 waves).
// Fix: (1) quad butterflies via DPP quad_perm (VALU, ~4cy, no LDS);
// (2) split each (b,h) chain's 64 v-rows over 4 blocks -> 256 blocks x 1 wave,
// 21 LDS instr/step/CU, all 256 CUs used. o-over-ain WAR across siblings is
// fenced by a per-chunk device-scope counter handshake (all 256 blocks
// co-resident: 1 block/CU). GEMMs: split-bf16 MFMA (round-6, verified).

#define DI __device__ __forceinline__
static constexpr int T_ = 1024, C_ = 2048, H_ = 32;

typedef __attribute__((ext_vector_type(8))) __bf16 bf16x8;
typedef __attribute__((ext_vector_type(4))) float f32x4;
typedef __attribute__((ext_vector_type(8))) unsigned short us8v;
typedef __attribute__((ext_vector_type(4))) unsigned short us4v;
typedef __attribute__((ext_vector_type(2))) unsigned short us2v;

DI float sig_(float z) { return 1.0f / (1.0f + expf(-z)); }

DI unsigned short f2bf(float f) {           // round-to-nearest-even f32 -> bf16
  union { float f; uint32_t u; } v; v.f = f;
  uint32_t u = v.u;
  return (unsigned short)((u + 0x7FFFu + ((u >> 16) & 1u)) >> 16);
}
DI float bf2f(unsigned short h) {
  union { uint32_t u; float f; } v; v.u = ((uint32_t)h) << 16;
  return v.f;
}

// intra-quad butterfly adds via DPP quad_perm (kq == lane&3): VALU-only.
DI float dpp_xor1_add(float x) {
  int r = __builtin_amdgcn_update_dpp(0, __float_as_int(x), 0xB1, 0xF, 0xF, true);
  return x + __int_as_float(r);
}
DI float dpp_xor2_add(float x) {
  int r = __builtin_amdgcn_update_dpp(0, __float_as_int(x), 0x4E, 0xF, 0xF, true);
  return x + __int_as_float(r);
}

// async global -> LDS DMA, 16 B per lane (dest = wave-uniform base + lane*16).
DI void gload16(const float* g, float* l) {
  __builtin_amdgcn_global_load_lds(
      (const __attribute__((address_space(1))) uint32_t*)g,
      (__attribute__((address_space(3))) uint32_t*)l, 16, 0, 0);
}

// ---------------- fp32 oracle GEMM (kept for G2: K<=128 LoRA-up jobs) ----------------
struct Job {
  const float* A; const float* W; float* C; const float* bias;
  const float* mixv; const float* x; const float* shift;
  int N, K, ntn, aact, epi, tile_end;
};
struct Jobs { Job j[7]; };

__global__ __launch_bounds__(256) void gemm_oracle(Jobs P) {
  __shared__ float As[64][33];
  __shared__ float Ws[32][65];
  int bx = blockIdx.x, ji = 0;
  while (bx >= P.j[ji].tile_end) ++ji;
  Job J = P.j[ji];
  int tix = bx - (ji ? P.j[ji - 1].tile_end : 0);
  int mt = tix / J.ntn, nt = tix % J.ntn;
  int m0 = mt * 64, n0 = nt * 64;
  int tid = threadIdx.x, tx = tid & 15, ty = tid >> 4;
  float acc[4][4] = {};
  for (int k0 = 0; k0 < J.K; k0 += 32) {
    #pragma unroll
    for (int p = 0; p < 8; ++p) {
      int idx = p * 256 + tid;
      int r = idx >> 5, kc = idx & 31;
      int m = m0 + r, k = k0 + kc;
      float a;
      if (J.mixv) {
        float xv = J.x[(size_t)m * C_ + k];
        int t = m & (T_ - 1);
        float xp = (t == 0) ? J.shift[(size_t)(m >> 10) * C_ + k]
                            : J.x[(size_t)(m - 1) * C_ + k];
        a = xv + (xp - xv) * J.mixv[k];
      } else {
        a = J.A[(size_t)m * J.K + k];
        if (J.aact == 1) a = tanhf(a);
        else if (J.aact == 2) a = sig_(a);
      }
      As[r][kc] = a;
    }
    #pragma unroll
    for (int p = 0; p < 8; ++p) {
      int idx = p * 256 + tid;
      int kr = idx >> 6, nc = idx & 63;
      int n = n0 + nc;
      Ws[kr][nc] = (n < J.N) ? J.W[(size_t)(k0 + kr) * J.N + n] : 0.0f;
    }
    __syncthreads();
    #pragma unroll 4
    for (int kc = 0; kc < 32; ++kc) {
      float av[4], bv[4];
      #pragma unroll
      for (int i = 0; i < 4; ++i) av[i] = As[ty * 4 + i][kc];
      #pragma unroll
      for (int jn = 0; jn < 4; ++jn) bv[jn] = Ws[kc][tx * 4 + jn];
      #pragma unroll
      for (int i = 0; i < 4; ++i)
        #pragma unroll
        for (int jn = 0; jn < 4; ++jn) acc[i][jn] += av[i] * bv[jn];
    }
    __syncthreads();
  }
  #pragma unroll
  for (int i = 0; i < 4; ++i) {
    int rw = m0 + ty * 4 + i;
    #pragma unroll
    for (int jn = 0; jn < 4; ++jn) {
      int col = n0 + tx * 4 + jn;
      if (col < J.N) {
        float v = acc[i][jn];
        if (J.epi == 1) v = sig_(J.bias[col] + v);
        else if (J.epi == 2) v = 0.60653065971263342f * sig_(J.bias[col] + v);
        J.C[(size_t)rw * J.N + col] = v;
      }
    }
  }
}

// -------- weight transpose+split: src fp32 [K=2048][N] -> hi/lo bf16 [Npad][2048] --------
struct TJob { const float* src; unsigned short* dh; unsigned short* dl; int N, ntn, tile_end; };
struct TJobs { TJob j[4]; };

__global__ __launch_bounds__(256) void wtrans(TJobs P) {
  __shared__ float t[64][65];
  int bx = blockIdx.x, ji = 0;
  while (bx >= P.j[ji].tile_end) ++ji;
  TJob J = P.j[ji];
  int tix = bx - (ji ? P.j[ji - 1].tile_end : 0);
  int kt = tix / J.ntn, nt = tix % J.ntn;
  int k0 = kt * 64, n0 = nt * 64;
  int tid = threadIdx.x;
  #pragma unroll
  for (int p = 0; p < 16; ++p) {
    int flat = p * 256 + tid;
    int r = flat >> 6, c = flat & 63;
    int n = n0 + c;
    t[r][c] = (n < J.N) ? J.src[(size_t)(k0 + r) * J.N + n] : 0.0f;
  }
  __syncthreads();
  #pragma unroll
  for (int p = 0; p < 8; ++p) {
    int flat = p * 256 + tid;
    int rr = flat >> 5, cc = (flat & 31) * 2;
    float w0v = t[cc][rr], w1v = t[cc + 1][rr];
    unsigned short h0 = f2bf(w0v), h1 = f2bf(w1v);
    us2v oh, ol;
    oh.x = h0; oh.y = h1;
    ol.x = f2bf(w0v - bf2f(h0));
    ol.y = f2bf(w1v - bf2f(h1));
    size_t off = (size_t)(n0 + rr) * 2048 + k0 + cc;
    *(us2v*)(J.dh + off) = oh;
    *(us2v*)(J.dl + off) = ol;
  }
}

// ------------- split-bf16 MFMA GEMM: C[M=2048,N] = A[M,K] @ Wt[N,K]^T -------------
struct GJob {
  const float* A; const unsigned short* Wh; const unsigned short* Wl; float* C;
  const float* mixv; const float* shift;
  int N, K, ntn, tile_end;
};
struct GJobs { GJob j[4]; };

__global__ __launch_bounds__(256) void gemm_split(GJobs P) {
  __shared__ unsigned short Ash[128][40];
  __shared__ unsigned short Asl[128][40];
  __shared__ unsigned short Bsh[128][40];
  __shared__ unsigned short Bsl[128][40];
  int bx = blockIdx.x, ji = 0;
  while (bx >= P.j[ji].tile_end) ++ji;
  GJob J = P.j[ji];
  int tix = bx - (ji ? P.j[ji - 1].tile_end : 0);
  int mt = tix / J.ntn, nt = tix % J.ntn;
  int m0 = mt * 128, n0 = nt * 128;
  int tid = threadIdx.x;
  int lane = tid & 63, wid = tid >> 6;
  int wr = wid >> 1, wc = wid & 1;
  int l15 = lane & 15, lg = lane >> 4;
  f32x4 acc[4][4] = {};

  for (int k0 = 0; k0 < J.K; k0 += 32) {
    #pragma unroll
    for (int p = 0; p < 4; ++p) {
      int flat = p * 256 + tid;
      int r = flat >> 3, kq = flat & 7;
      int m = m0 + r;
      int kk = k0 + kq * 4;
      const float* xp0 = J.A + (size_t)m * J.K + kk;
      float4 xv = *(const float4*)xp0;
      float va[4];
      if (J.mixv) {
        const float* pp = ((m & (T_ - 1)) == 0)
            ? (J.shift + (size_t)(m >> 10) * C_ + kk)
            : (xp0 - C_);
        float4 xq = *(const float4*)pp;
        float4 mv = *(const float4*)(J.mixv + kk);
        va[0] = xv.x + (xq.x - xv.x) * mv.x;
        va[1] = xv.y + (xq.y - xv.y) * mv.y;
        va[2] = xv.z + (xq.z - xv.z) * mv.z;
        va[3] = xv.w + (xq.w - xv.w) * mv.w;
      } else {
        va[0] = xv.x; va[1] = xv.y; va[2] = xv.z; va[3] = xv.w;
      }
      us4v oh, ol;
      #pragma unroll
      for (int q = 0; q < 4; ++q) {
        unsigned short h = f2bf(va[q]);
        oh[q] = h;
        ol[q] = f2bf(va[q] - bf2f(h));
      }
      *(us4v*)&Ash[r][kq * 4] = oh;
      *(us4v*)&Asl[r][kq * 4] = ol;
    }
    #pragma unroll
    for (int p = 0; p < 2; ++p) {
      int flat = p * 256 + tid;
      int r = flat >> 2, ko = (flat & 3) * 8;
      size_t off = (size_t)(n0 + r) * J.K + k0 + ko;
      *(us8v*)&Bsh[r][ko] = *(const us8v*)(J.Wh + off);
      *(us8v*)&Bsl[r][ko] = *(const us8v*)(J.Wl + off);
    }
    __syncthreads();
    bf16x8 afh[4], afl[4], bwh[4], bwl[4];
    #pragma unroll
    for (int i = 0; i < 4; ++i) {
      int rr = wr * 64 + i * 16 + l15;
      afh[i] = __builtin_bit_cast(bf16x8, *(const us8v*)&Ash[rr][lg * 8]);
      afl[i] = __builtin_bit_cast(bf16x8, *(const us8v*)&Asl[rr][lg * 8]);
    }
    #pragma unroll
    for (int i = 0; i < 4; ++i) {
      int rr = wc * 64 + i * 16 + l15;
      bwh[i] = __builtin_bit_cast(bf16x8, *(const us8v*)&Bsh[rr][lg * 8]);
      bwl[i] = __builtin_bit_cast(bf16x8, *(const us8v*)&Bsl[rr][lg * 8]);
    }
    #pragma unroll
    for (int i = 0; i < 4; ++i)
      #pragma unroll
      for (int jn = 0; jn < 4; ++jn) {
        acc[i][jn] = __builtin_amdgcn_mfma_f32_16x16x32_bf16(
            afh[i], bwh[jn], acc[i][jn], 0, 0, 0);
        acc[i][jn] = __builtin_amdgcn_mfma_f32_16x16x32_bf16(
            afl[i], bwh[jn], acc[i][jn], 0, 0, 0);
        acc[i][jn] = __builtin_amdgcn_mfma_f32_16x16x32_bf16(
            afh[i], bwl[jn], acc[i][jn], 0, 0, 0);
      }
    __syncthreads();
  }
  int orow0 = m0 + wr * 64 + 4 * lg;
  int ocol0 = n0 + wc * 64 + l15;
  #pragma unroll
  for (int i = 0; i < 4; ++i) {
    #pragma unroll
    for (int jn = 0; jn < 4; ++jn) {
      int col = ocol0 + jn * 16;
      if (col < J.N) {
        #pragma unroll
        for (int rr = 0; rr < 4; ++rr)
          J.C[(size_t)(orow0 + i * 16 + rr) * J.N + col] = acc[i][jn][rr];
      }
    }
  }
}

// ---------------- prescan: one block per (b,t,h); also zeros scan counters ----------------
__global__ __launch_bounds__(64) void prescan(
    float* __restrict__ kio, float* __restrict__ vio,
    float* __restrict__ amat_ain, float* __restrict__ vmix_bin,
    const float* __restrict__ vfirst,
    const float* __restrict__ k_k, const float* __restrict__ k_a,
    uint32_t* __restrict__ cnt) {
  __shared__ float red[64];
  int bid = blockIdx.x, tid = threadIdx.x;
  if (bid < 32) cnt[bid * 64 + tid] = 0u;     // 64 chains x 32 chunks
  int h = bid & (H_ - 1);
  size_t base = (size_t)bid * 64 + tid;
  int cc = h * 64 + tid;
  float kv = kio[base];
  float kkv = kv * k_k[cc];
  red[tid] = kkv * kkv;
  __syncthreads();
  for (int s = 32; s > 0; s >>= 1) { if (tid < s) red[tid] += red[tid + s]; __syncthreads(); }
  float nrm = fmaxf(sqrtf(red[0]), 1e-12f);
  float kkn = kkv / nrm;
  float av = amat_ain[base];
  float vmv = vmix_bin[base];
  float vv = vio[base];
  kio[base] = kv * (1.0f + (av - 1.0f) * k_a[cc]);
  vio[base] = vv + (vfirst[base] - vv) * vmv;
  amat_ain[base] = -kkn;
  vmix_bin[base] = kkn * av;
}

// ------- wkv scan v3: 256 blocks (4 per (b,h) chain, 16 v-rows each) x 64 thr -------
// Lane: vl = lane>>2 (16 v-rows), kq = lane&3 (k-quarter); S[16] in VGPRs.
// Butterflies via DPP quad_perm (VALU). Inputs chunk-staged (CH=32) into
// double-buffered LDS via global_load_lds. o overwrites ain: per-chunk counter
// handshake guarantees all 4 sibling blocks have staged chunk c before any
// sibling writes o into it (all 256 blocks co-resident: 1 block/CU).
static constexpr int CH = 32;

__global__ __launch_bounds__(64) void wkv_scan_split(
    const float* __restrict__ r, const float* __restrict__ k2,
    const float* __restrict__ w, const float* __restrict__ ain,
    const float* __restrict__ bin, const float* __restrict__ vp,
    const float* __restrict__ sInit, float* __restrict__ o,
    uint32_t* __restrict__ cnt) {
  __shared__ float lds[2][5][CH][64];      // 80 KiB
  __shared__ float vtl[2][CH][16];         // 4 KiB
  int bid = blockIdx.x;
  int chain = bid >> 2, vblk = bid & 3;
  int b = chain >> 5, h = chain & 31;
  int v0 = vblk * 16;
  int lane = threadIdx.x;
  int vl = lane >> 2, kq = lane & 3;
  int kb = kq * 16;
  size_t bh = (size_t)(b * T_) * 2048 + (size_t)h * 64;   // float offset at t=0

  float S[16];
  {
    const float* sp = sInit + (((size_t)(chain) * 64 + v0 + vl) * 64) + kb;
    #pragma unroll
    for (int i = 0; i < 16; i += 4) {
      float4 sv = *(const float4*)(sp + i);
      S[i] = sv.x; S[i + 1] = sv.y; S[i + 2] = sv.z; S[i + 3] = sv.w;
    }
  }

  const float* arr[5] = {r, k2, w, ain, bin};

  // stage chunk t0 into buf: 5 arrays x 32 steps x 64 floats (40 DMA) + vt (2 DMA).
  auto stage = [&](int buf, int t0) {
    #pragma unroll
    for (int a = 0; a < 5; ++a) {
      #pragma unroll
      for (int jj = 0; jj < 8; ++jj) {
        size_t gofs = bh + (size_t)(t0 + jj * 4 + (lane >> 4)) * 2048 + (lane & 15) * 4;
        gload16(arr[a] + gofs, &lds[buf][a][jj * 4][0]);
      }
    }
    #pragma unroll
    for (int di = 0; di < 2; ++di) {
      size_t gofs = bh + (size_t)(t0 + di * 16 + (lane >> 2)) * 2048 + v0 + (lane & 3) * 4;
      gload16(vp + gofs, &vtl[buf][di * 16][0]);
    }
  };

  stage(0, 0);
  asm volatile("s_waitcnt vmcnt(0)" ::: "memory");
  __syncthreads();

  uint32_t* mycnt = cnt + chain * 32;
  for (int c = 0; c < T_ / CH; ++c) {
    int cur = c & 1;
    if (c + 1 < T_ / CH) stage(cur ^ 1, (c + 1) * CH);
    // handshake: all 4 siblings must have staged chunk c before we write o into it.
    if (lane == 0) {
      __hip_atomic_fetch_add(&mycnt[c], 1u, __ATOMIC_ACQ_REL, __HIP_MEMORY_SCOPE_AGENT);
      while (__hip_atomic_load(&mycnt[c], __ATOMIC_ACQUIRE, __HIP_MEMORY_SCOPE_AGENT) < 4u) {
        __builtin_amdgcn_s_sleep(1);
      }
    }
    __syncthreads();
    int t0 = c * CH;
    #pragma unroll 4
    for (int s = 0; s < CH; ++s) {
      float aa[16];
      #pragma unroll
      for (int i = 0; i < 16; i += 4)
        *(float4*)&aa[i] = *(const float4*)&lds[cur][3][s][kb + i];
      float p0 = 0.f, p1 = 0.f, p2 = 0.f, p3 = 0.f;
      #pragma unroll
      for (int i = 0; i < 16; i += 4) {
        p0 = fmaf(S[i], aa[i], p0);
        p1 = fmaf(S[i + 1], aa[i + 1], p1);
        p2 = fmaf(S[i + 2], aa[i + 2], p2);
        p3 = fmaf(S[i + 3], aa[i + 3], p3);
      }
      float sa = (p0 + p1) + (p2 + p3);
      sa = dpp_xor1_add(sa);
      sa = dpp_xor2_add(sa);
      float vt = vtl[cur][s][vl];
      float ww[16], kk[16], bb[16], rr[16];
      #pragma unroll
      for (int i = 0; i < 16; i += 4) {
        *(float4*)&ww[i] = *(const float4*)&lds[cur][2][s][kb + i];
        *(float4*)&kk[i] = *(const float4*)&lds[cur][1][s][kb + i];
        *(float4*)&bb[i] = *(const float4*)&lds[cur][4][s][kb + i];
        *(float4*)&rr[i] = *(const float4*)&lds[cur][0][s][kb + i];
      }
      float y0 = 0.f, y1 = 0.f, y2 = 0.f, y3 = 0.f;
      #pragma unroll
      for (int i = 0; i < 16; i += 4) {
        S[i]     = fmaf(S[i],     ww[i],     fmaf(vt, kk[i],     sa * bb[i]));
        S[i + 1] = fmaf(S[i + 1], ww[i + 1], fmaf(vt, kk[i + 1], sa * bb[i + 1]));
        S[i + 2] = fmaf(S[i + 2], ww[i + 2], fmaf(vt, kk[i + 2], sa * bb[i + 2]));
        S[i + 3] = fmaf(S[i + 3], ww[i + 3], fmaf(vt, kk[i + 3], sa * bb[i + 3]));
        y0 = fmaf(S[i], rr[i], y0);
        y1 = fmaf(S[i + 1], rr[i + 1], y1);
        y2 = fmaf(S[i + 2], rr[i + 2], y2);
        y3 = fmaf(S[i + 3], rr[i + 3], y3);
      }
      float y = (y0 + y1) + (y2 + y3);
      y = dpp_xor1_add(y);
      y = dpp_xor2_add(y);
      if (kq == 0) o[bh + (size_t)(t0 + s) * 2048 + v0 + vl] = y;
    }
    asm volatile("s_waitcnt vmcnt(0)" ::: "memory");
    __syncthreads();
  }
}

// ---------------- post: GroupNorm + bonus + gate; one block per (b,t,h) ----------------
__global__ __launch_bounds__(64) void post(
    const float* __restrict__ o, const float* __restrict__ r,
    const float* __restrict__ k2, const float* __restrict__ vp,
    const float* __restrict__ g, const float* __restrict__ r_k,
    const float* __restrict__ lnw, const float* __restrict__ lnb,
    float* __restrict__ afin) {
  __shared__ float red[64];
  int bid = blockIdx.x, tid = threadIdx.x;
  int h = bid & 31;
  size_t base = (size_t)bid * 64 + tid;
  int cc = h * 64 + tid;
  float ov = o[base];
  red[tid] = ov; __syncthreads();
  for (int s = 32; s > 0; s >>= 1) { if (tid < s) red[tid] += red[tid + s]; __syncthreads(); }
  float mu = red[0] * (1.0f / 64.0f);
  __syncthreads();
  float dv = ov - mu;
  red[tid] = dv * dv; __syncthreads();
  for (int s = 32; s > 0; s >>= 1) { if (tid < s) red[tid] += red[tid + s]; __syncthreads(); }
  float var = red[0] * (1.0f / 64.0f);
  __syncthreads();
  float on = dv * rsqrtf(var + 6.4e-4f) * lnw[cc] + lnb[cc];
  float pr = r[base] * k2[base] * r_k[cc];
  red[tid] = pr; __syncthreads();
  for (int s = 32; s > 0; s >>= 1) { if (tid < s) red[tid] += red[tid + s]; __syncthreads(); }
  float dot = red[0];
  float val = (on + dot * vp[base]) * g[base];
  afin[base] = val;
}

// ---------------- host ----------------
static constexpr size_t KB = 1024;
static constexpr size_t O_R    = 0;
static constexpr size_t O_K    = 16384;
static constexpr size_t O_V    = 32768;
static constexpr size_t O_WDEC = 49152;
static constexpr size_t O_AMAT = 65536;
static constexpr size_t O_VMIX = 81920;
static constexpr size_t O_HW   = 98304;    // hg inputs; dead after G2 -> scan counters live here
static constexpr size_t O_HA   = 98816;
static constexpr size_t O_HV   = 99328;
static constexpr size_t O_HG   = 99584;
static constexpr size_t O_AIN  = O_AMAT;
static constexpr size_t O_O    = O_AMAT;
static constexpr size_t O_BIN  = O_VMIX;
static constexpr size_t O_AFIN = O_VMIX;
static constexpr size_t O_CNT  = O_HW;     // 8 KiB of counters (zeroed by prescan)
static constexpr size_t O_WRT_H = 49152, O_WRT_L = 57344;
static constexpr size_t O_WKT_H = 65536, O_WKT_L = 73728;
static constexpr size_t O_WVT_H = 81920, O_WVT_L = 90112;
static constexpr size_t O_W1T_H = 49152, O_W1T_L = 49664;
static constexpr size_t O_A1T_H = 50176, O_A1T_L = 50688;
static constexpr size_t O_V1T_H = 51200, O_V1T_L = 51712;
static constexpr size_t O_G1T_H = 52224, O_G1T_L = 52736;
static constexpr size_t O_WOT_H = 0, O_WOT_L = 8192;

extern "C" void kernel_launch(void* const* d_in, const int* in_sizes, int n_in,
                              void* d_out, int out_size, void* d_ws, size_t ws_size,
                              hipStream_t stream) {
  const float* x      = (const float*)d_in[0];
  const float* vfirst = (const float*)d_in[1];
  const float* shift  = (const float*)d_in[2];
  const float* wkv0   = (const float*)d_in[3];
  const float* x_r = (const float*)d_in[4];
  const float* x_w = (const float*)d_in[5];
  const float* x_k = (const float*)d_in[6];
  const float* x_v = (const float*)d_in[7];
  const float* x_a = (const float*)d_in[8];
  const float* x_g = (const float*)d_in[9];
  const float* w0 = (const float*)d_in[10];
  const float* w1 = (const float*)d_in[11];
  const float* w2 = (const float*)d_in[12];
  const float* a0 = (const float*)d_in[13];
  const float* a1 = (const float*)d_in[14];
  const float* a2 = (const float*)d_in[15];
  const float* v0 = (const float*)d_in[16];
  const float* v1 = (const float*)d_in[17];
  const float* v2 = (const float*)d_in[18];
  const float* g1 = (const float*)d_in[19];
  const float* g2 = (const float*)d_in[20];
  const float* k_k = (const float*)d_in[21];
  const float* k_a = (const float*)d_in[22];
  const float* r_k = (const float*)d_in[23];
  const float* W_r = (const float*)d_in[24];
  const float* W_k = (const float*)d_in[25];
  const float* W_v = (const float*)d_in[26];
  const float* W_o = (const float*)d_in[27];
  const float* ln_w = (const float*)d_in[28];
  const float* ln_b = (const float*)d_in[29];

  char* ws = (char*)d_ws;
  auto F = [&](size_t kb) { return (float*)(ws + kb * KB); };
  auto U = [&](size_t kb) { return (unsigned short*)(ws + kb * KB); };
  float* outp = (float*)d_out;

  // T1a: transpose+split the three big weights into dead WDEC/AMAT/VMIX regions.
  {
    TJobs TG{};
    int cum = 0, i = 0;
    auto addT = [&](const float* src, size_t hkb, size_t lkb) {
      cum += 32 * 32;
      TG.j[i++] = TJob{src, U(hkb), U(lkb), 2048, 32, cum};
    };
    addT(W_r, O_WRT_H, O_WRT_L);
    addT(W_k, O_WKT_H, O_WKT_L);
    addT(W_v, O_WVT_H, O_WVT_L);
    wtrans<<<dim3(cum), dim3(256), 0, stream>>>(TG);
  }

  // G1a (split MFMA): r, k, v with fused token-shift mixes.
  {
    GJobs G{};
    int cum = 0, i = 0;
    auto add = [&](size_t hkb, size_t lkb, float* Cp, const float* mixv) {
      cum += 16 * 16;
      G.j[i++] = GJob{x, U(hkb), U(lkb), Cp, mixv, shift, 2048, 2048, 16, cum};
    };
    add(O_WRT_H, O_WRT_L, F(O_R), x_r);
    add(O_WKT_H, O_WKT_L, F(O_K), x_k);
    add(O_WVT_H, O_WVT_L, F(O_V), x_v);
    gemm_split<<<dim3(cum), dim3(256), 0, stream>>>(G);
  }

  // T1b: transpose+split small LoRA-down weights over dead W_rt space.
  {
    TJobs TG{};
    int cum = 0, i = 0;
    auto addT = [&](const float* src, size_t hkb, size_t lkb, int N) {
      cum += 32 * 2;
      TG.j[i++] = TJob{src, U(hkb), U(lkb), N, 2, cum};
    };
    addT(w1, O_W1T_H, O_W1T_L, 64);
    addT(a1, O_A1T_H, O_A1T_L, 64);
    addT(v1, O_V1T_H, O_V1T_L, 32);
    addT(g1, O_G1T_H, O_G1T_L, 128);
    wtrans<<<dim3(cum), dim3(256), 0, stream>>>(TG);
  }

  // G1b (split MFMA): the four LoRA-down projections.
  {
    GJobs G{};
    int cum = 0, i = 0;
    auto add = [&](size_t hkb, size_t lkb, float* Cp, const float* mixv, int N) {
      cum += 16;
      G.j[i++] = GJob{x, U(hkb), U(lkb), Cp, mixv, shift, N, 2048, 1, cum};
    };
    add(O_W1T_H, O_W1T_L, F(O_HW), x_w, 64);
    add(O_A1T_H, O_A1T_L, F(O_HA), x_a, 64);
    add(O_V1T_H, O_V1T_L, F(O_HV), x_v, 32);
    add(O_G1T_H, O_G1T_L, F(O_HG), x_g, 128);
    gemm_split<<<dim3(cum), dim3(256), 0, stream>>>(G);
  }

  // G2 (fp32 oracle): LoRA-up with fused activations/epilogues.
  {
    Jobs G{};
    int cum = 0, i = 0;
    auto add = [&](const float* A, const float* W, float* C, const float* bias,
                   int K, int aact, int epi) {
      cum += 32 * 32;
      G.j[i++] = Job{A, W, C, bias, nullptr, nullptr, nullptr, 2048, K, 32, aact, epi, cum};
    };
    add(F(O_HW), w2, F(O_WDEC), w0, 64, 1, 2);
    add(F(O_HA), a2, F(O_AMAT), a0, 64, 0, 1);
    add(F(O_HV), v2, F(O_VMIX), v0, 32, 0, 1);
    add(F(O_HG), g2, outp,     nullptr, 128, 2, 0);
    gemm_oracle<<<dim3(cum), dim3(256), 0, stream>>>(G);
  }

  // prescan: kk-norm; k->k2, v->v', amat->a_in, vmix->b_in; zero scan counters.
  prescan<<<dim3(65536), dim3(64), 0, stream>>>(F(O_K), F(O_V), F(O_AMAT), F(O_VMIX),
                                                vfirst, k_k, k_a, (uint32_t*)F(O_CNT));

  // scan v3: 256 blocks (4 per chain) x 64 threads; counter-fenced o-over-ain.
  wkv_scan_split<<<dim3(256), dim3(64), 0, stream>>>(F(O_R), F(O_K), F(O_WDEC), F(O_AIN),
                                                     F(O_BIN), F(O_V), wkv0, F(O_O),
                                                     (uint32_t*)F(O_CNT));

  // post: GroupNorm + bonus + gate -> afin.
  post<<<dim3(65536), dim3(64), 0, stream>>>(F(O_O), F(O_R), F(O_K), F(O_V),
                                             outp, r_k, ln_w, ln_b, F(O_AFIN));

  // T2: W_o transpose+split into dead r region, then G3 (split MFMA): out = afin @ W_o.
  {
    TJobs TO{};
    TO.j[0] = TJob{W_o, U(O_WOT_H), U(O_WOT_L), 2048, 32, 1024};
    wtrans<<<dim3(1024), dim3(256), 0, stream>>>(TO);
    GJobs G{};
    G.j[0] = GJob{F(O_AFIN), U(O_WOT_H), U(O_WOT_L), outp, nullptr, nullptr,
                  2048, 2048, 16, 256};
    gemm_split<<<dim3(256), dim3(256), 0, stream>>>(G);
  }

  (void)in_sizes; (void)n_in; (void)out_size; (void)ws_size;
}

// Round 5
// 1131.760 us; speedup vs baseline: 1.2023x; 1.2023x over previous
//
#include <hip/hip_runtime.h>
#include <cstdint>
#include <cstddef>

// RWKV-7 Tmix forward, MI355X gfx950 — ROUND 9: scan v4.
// r8 lesson: v-split topology was right, but (a) the device-scope handshake
// added µs-scale serial cost per chunk, (b) siblings on different XCDs made
// staging re-fetch HBM (FETCH 181 MB), (c) per-step LDS batches were exposed
// on the serial chain (1 wave/SIMD, no TLP). Fixes: o stored as bf16 into the
// free half of d_out (g also bf16 in the other half) -> no in-place WAR, no
// handshake; XCD-swizzled grid so a chain's 4 siblings share one L2; explicit
// 2-step register pipeline so LDS latency hides under compute.
// GEMMs: split-bf16 MFMA (round-6, verified). Workspace high-water unchanged.

#define DI __device__ __forceinline__
static constexpr int T_ = 1024, C_ = 2048, H_ = 32;

typedef __attribute__((ext_vector_type(8))) __bf16 bf16x8;
typedef __attribute__((ext_vector_type(4))) float f32x4;
typedef __attribute__((ext_vector_type(8))) unsigned short us8v;
typedef __attribute__((ext_vector_type(4))) unsigned short us4v;
typedef __attribute__((ext_vector_type(2))) unsigned short us2v;

DI float sig_(float z) { return 1.0f / (1.0f + expf(-z)); }

DI unsigned short f2bf(float f) {           // round-to-nearest-even f32 -> bf16
  union { float f; uint32_t u; } v; v.f = f;
  uint32_t u = v.u;
  return (unsigned short)((u + 0x7FFFu + ((u >> 16) & 1u)) >> 16);
}
DI float bf2f(unsigned short h) {
  union { uint32_t u; float f; } v; v.u = ((uint32_t)h) << 16;
  return v.f;
}

// intra-quad butterfly adds via DPP quad_perm (kq == lane&3): VALU-only.
DI float dpp_xor1_add(float x) {
  int r = __builtin_amdgcn_update_dpp(0, __float_as_int(x), 0xB1, 0xF, 0xF, true);
  return x + __int_as_float(r);
}
DI float dpp_xor2_add(float x) {
  int r = __builtin_amdgcn_update_dpp(0, __float_as_int(x), 0x4E, 0xF, 0xF, true);
  return x + __int_as_float(r);
}

// async global -> LDS DMA, 16 B per lane (dest = wave-uniform base + lane*16).
DI void gload16(const float* g, float* l) {
  __builtin_amdgcn_global_load_lds(
      (const __attribute__((address_space(1))) uint32_t*)g,
      (__attribute__((address_space(3))) uint32_t*)l, 16, 0, 0);
}

// ---------------- fp32 oracle GEMM (kept for G2: K<=128 LoRA-up jobs) ----------------
// epi: 0 fp32 store; 1 sigmoid(bias+v); 2 e^-0.5*sigmoid(bias+v); 3 bf16 store.
struct Job {
  const float* A; const float* W; float* C; const float* bias;
  const float* mixv; const float* x; const float* shift;
  int N, K, ntn, aact, epi, tile_end;
};
struct Jobs { Job j[7]; };

__global__ __launch_bounds__(256) void gemm_oracle(Jobs P) {
  __shared__ float As[64][33];
  __shared__ float Ws[32][65];
  int bx = blockIdx.x, ji = 0;
  while (bx >= P.j[ji].tile_end) ++ji;
  Job J = P.j[ji];
  int tix = bx - (ji ? P.j[ji - 1].tile_end : 0);
  int mt = tix / J.ntn, nt = tix % J.ntn;
  int m0 = mt * 64, n0 = nt * 64;
  int tid = threadIdx.x, tx = tid & 15, ty = tid >> 4;
  float acc[4][4] = {};
  for (int k0 = 0; k0 < J.K; k0 += 32) {
    #pragma unroll
    for (int p = 0; p < 8; ++p) {
      int idx = p * 256 + tid;
      int r = idx >> 5, kc = idx & 31;
      int m = m0 + r, k = k0 + kc;
      float a;
      if (J.mixv) {
        float xv = J.x[(size_t)m * C_ + k];
        int t = m & (T_ - 1);
        float xp = (t == 0) ? J.shift[(size_t)(m >> 10) * C_ + k]
                            : J.x[(size_t)(m - 1) * C_ + k];
        a = xv + (xp - xv) * J.mixv[k];
      } else {
        a = J.A[(size_t)m * J.K + k];
        if (J.aact == 1) a = tanhf(a);
        else if (J.aact == 2) a = sig_(a);
      }
      As[r][kc] = a;
    }
    #pragma unroll
    for (int p = 0; p < 8; ++p) {
      int idx = p * 256 + tid;
      int kr = idx >> 6, nc = idx & 63;
      int n = n0 + nc;
      Ws[kr][nc] = (n < J.N) ? J.W[(size_t)(k0 + kr) * J.N + n] : 0.0f;
    }
    __syncthreads();
    #pragma unroll 4
    for (int kc = 0; kc < 32; ++kc) {
      float av[4], bv[4];
      #pragma unroll
      for (int i = 0; i < 4; ++i) av[i] = As[ty * 4 + i][kc];
      #pragma unroll
      for (int jn = 0; jn < 4; ++jn) bv[jn] = Ws[kc][tx * 4 + jn];
      #pragma unroll
      for (int i = 0; i < 4; ++i)
        #pragma unroll
        for (int jn = 0; jn < 4; ++jn) acc[i][jn] += av[i] * bv[jn];
    }
    __syncthreads();
  }
  #pragma unroll
  for (int i = 0; i < 4; ++i) {
    int rw = m0 + ty * 4 + i;
    #pragma unroll
    for (int jn = 0; jn < 4; ++jn) {
      int col = n0 + tx * 4 + jn;
      if (col < J.N) {
        float v = acc[i][jn];
        if (J.epi == 1) v = sig_(J.bias[col] + v);
        else if (J.epi == 2) v = 0.60653065971263342f * sig_(J.bias[col] + v);
        if (J.epi == 3) ((unsigned short*)J.C)[(size_t)rw * J.N + col] = f2bf(v);
        else            J.C[(size_t)rw * J.N + col] = v;
      }
    }
  }
}

// -------- weight transpose+split: src fp32 [K=2048][N] -> hi/lo bf16 [Npad][2048] --------
struct TJob { const float* src; unsigned short* dh; unsigned short* dl; int N, ntn, tile_end; };
struct TJobs { TJob j[4]; };

__global__ __launch_bounds__(256) void wtrans(TJobs P) {
  __shared__ float t[64][65];
  int bx = blockIdx.x, ji = 0;
  while (bx >= P.j[ji].tile_end) ++ji;
  TJob J = P.j[ji];
  int tix = bx - (ji ? P.j[ji - 1].tile_end : 0);
  int kt = tix / J.ntn, nt = tix % J.ntn;
  int k0 = kt * 64, n0 = nt * 64;
  int tid = threadIdx.x;
  #pragma unroll
  for (int p = 0; p < 16; ++p) {
    int flat = p * 256 + tid;
    int r = flat >> 6, c = flat & 63;
    int n = n0 + c;
    t[r][c] = (n < J.N) ? J.src[(size_t)(k0 + r) * J.N + n] : 0.0f;
  }
  __syncthreads();
  #pragma unroll
  for (int p = 0; p < 8; ++p) {
    int flat = p * 256 + tid;
    int rr = flat >> 5, cc = (flat & 31) * 2;
    float w0v = t[cc][rr], w1v = t[cc + 1][rr];
    unsigned short h0 = f2bf(w0v), h1 = f2bf(w1v);
    us2v oh, ol;
    oh.x = h0; oh.y = h1;
    ol.x = f2bf(w0v - bf2f(h0));
    ol.y = f2bf(w1v - bf2f(h1));
    size_t off = (size_t)(n0 + rr) * 2048 + k0 + cc;
    *(us2v*)(J.dh + off) = oh;
    *(us2v*)(J.dl + off) = ol;
  }
}

// ------------- split-bf16 MFMA GEMM: C[M=2048,N] = A[M,K] @ Wt[N,K]^T -------------
struct GJob {
  const float* A; const unsigned short* Wh; const unsigned short* Wl; float* C;
  const float* mixv; const float* shift;
  int N, K, ntn, tile_end;
};
struct GJobs { GJob j[4]; };

__global__ __launch_bounds__(256) void gemm_split(GJobs P) {
  __shared__ unsigned short Ash[128][40];
  __shared__ unsigned short Asl[128][40];
  __shared__ unsigned short Bsh[128][40];
  __shared__ unsigned short Bsl[128][40];
  int bx = blockIdx.x, ji = 0;
  while (bx >= P.j[ji].tile_end) ++ji;
  GJob J = P.j[ji];
  int tix = bx - (ji ? P.j[ji - 1].tile_end : 0);
  int mt = tix / J.ntn, nt = tix % J.ntn;
  int m0 = mt * 128, n0 = nt * 128;
  int tid = threadIdx.x;
  int lane = tid & 63, wid = tid >> 6;
  int wr = wid >> 1, wc = wid & 1;
  int l15 = lane & 15, lg = lane >> 4;
  f32x4 acc[4][4] = {};

  for (int k0 = 0; k0 < J.K; k0 += 32) {
    #pragma unroll
    for (int p = 0; p < 4; ++p) {
      int flat = p * 256 + tid;
      int r = flat >> 3, kq = flat & 7;
      int m = m0 + r;
      int kk = k0 + kq * 4;
      const float* xp0 = J.A + (size_t)m * J.K + kk;
      float4 xv = *(const float4*)xp0;
      float va[4];
      if (J.mixv) {
        const float* pp = ((m & (T_ - 1)) == 0)
            ? (J.shift + (size_t)(m >> 10) * C_ + kk)
            : (xp0 - C_);
        float4 xq = *(const float4*)pp;
        float4 mv = *(const float4*)(J.mixv + kk);
        va[0] = xv.x + (xq.x - xv.x) * mv.x;
        va[1] = xv.y + (xq.y - xv.y) * mv.y;
        va[2] = xv.z + (xq.z - xv.z) * mv.z;
        va[3] = xv.w + (xq.w - xv.w) * mv.w;
      } else {
        va[0] = xv.x; va[1] = xv.y; va[2] = xv.z; va[3] = xv.w;
      }
      us4v oh, ol;
      #pragma unroll
      for (int q = 0; q < 4; ++q) {
        unsigned short hq = f2bf(va[q]);
        oh[q] = hq;
        ol[q] = f2bf(va[q] - bf2f(hq));
      }
      *(us4v*)&Ash[r][kq * 4] = oh;
      *(us4v*)&Asl[r][kq * 4] = ol;
    }
    #pragma unroll
    for (int p = 0; p < 2; ++p) {
      int flat = p * 256 + tid;
      int r = flat >> 2, ko = (flat & 3) * 8;
      size_t off = (size_t)(n0 + r) * J.K + k0 + ko;
      *(us8v*)&Bsh[r][ko] = *(const us8v*)(J.Wh + off);
      *(us8v*)&Bsl[r][ko] = *(const us8v*)(J.Wl + off);
    }
    __syncthreads();
    bf16x8 afh[4], afl[4], bwh[4], bwl[4];
    #pragma unroll
    for (int i = 0; i < 4; ++i) {
      int rr = wr * 64 + i * 16 + l15;
      afh[i] = __builtin_bit_cast(bf16x8, *(const us8v*)&Ash[rr][lg * 8]);
      afl[i] = __builtin_bit_cast(bf16x8, *(const us8v*)&Asl[rr][lg * 8]);
    }
    #pragma unroll
    for (int i = 0; i < 4; ++i) {
      int rr = wc * 64 + i * 16 + l15;
      bwh[i] = __builtin_bit_cast(bf16x8, *(const us8v*)&Bsh[rr][lg * 8]);
      bwl[i] = __builtin_bit_cast(bf16x8, *(const us8v*)&Bsl[rr][lg * 8]);
    }
    #pragma unroll
    for (int i = 0; i < 4; ++i)
      #pragma unroll
      for (int jn = 0; jn < 4; ++jn) {
        acc[i][jn] = __builtin_amdgcn_mfma_f32_16x16x32_bf16(
            afh[i], bwh[jn], acc[i][jn], 0, 0, 0);
        acc[i][jn] = __builtin_amdgcn_mfma_f32_16x16x32_bf16(
            afl[i], bwh[jn], acc[i][jn], 0, 0, 0);
        acc[i][jn] = __builtin_amdgcn_mfma_f32_16x16x32_bf16(
            afh[i], bwl[jn], acc[i][jn], 0, 0, 0);
      }
    __syncthreads();
  }
  int orow0 = m0 + wr * 64 + 4 * lg;
  int ocol0 = n0 + wc * 64 + l15;
  #pragma unroll
  for (int i = 0; i < 4; ++i) {
    #pragma unroll
    for (int jn = 0; jn < 4; ++jn) {
      int col = ocol0 + jn * 16;
      if (col < J.N) {
        #pragma unroll
        for (int rr = 0; rr < 4; ++rr)
          J.C[(size_t)(orow0 + i * 16 + rr) * J.N + col] = acc[i][jn][rr];
      }
    }
  }
}

// ---------------- prescan: one block per (b,t,h); LDS tree reduction ----------------
__global__ __launch_bounds__(64) void prescan(
    float* __restrict__ kio, float* __restrict__ vio,
    float* __restrict__ amat_ain, float* __restrict__ vmix_bin,
    const float* __restrict__ vfirst,
    const float* __restrict__ k_k, const float* __restrict__ k_a) {
  __shared__ float red[64];
  int bid = blockIdx.x, tid = threadIdx.x;
  int h = bid & (H_ - 1);
  size_t base = (size_t)bid * 64 + tid;
  int cc = h * 64 + tid;
  float kv = kio[base];
  float kkv = kv * k_k[cc];
  red[tid] = kkv * kkv;
  __syncthreads();
  for (int s = 32; s > 0; s >>= 1) { if (tid < s) red[tid] += red[tid + s]; __syncthreads(); }
  float nrm = fmaxf(sqrtf(red[0]), 1e-12f);
  float kkn = kkv / nrm;
  float av = amat_ain[base];
  float vmv = vmix_bin[base];
  float vv = vio[base];
  kio[base] = kv * (1.0f + (av - 1.0f) * k_a[cc]);
  vio[base] = vv + (vfirst[base] - vv) * vmv;
  amat_ain[base] = -kkn;
  vmix_bin[base] = kkn * av;
}

// ------- wkv scan v4: 256 blocks (XCD-swizzled; 4 v-split siblings per chain share
// one XCD's L2) x 64 threads. Lane: vl = lane>>2, kq = lane&3; S[16] in VGPRs.
// 2-step register pipeline (named phase regs, static indices); DPP butterflies;
// o written as bf16 into d_out's upper half (no in-place WAR -> no handshake).
static constexpr int CH = 32;

#define LOADSTEP(BUF, S_, Aa, Ww, Kk, Bb, Rr, Vt)                \
  {                                                              \
    _Pragma("unroll") for (int i = 0; i < 16; i += 4) {          \
      *(float4*)&Aa[i] = *(const float4*)&lds[BUF][3][S_][kb + i]; \
      *(float4*)&Ww[i] = *(const float4*)&lds[BUF][2][S_][kb + i]; \
      *(float4*)&Kk[i] = *(const float4*)&lds[BUF][1][S_][kb + i]; \
      *(float4*)&Bb[i] = *(const float4*)&lds[BUF][4][S_][kb + i]; \
      *(float4*)&Rr[i] = *(const float4*)&lds[BUF][0][S_][kb + i]; \
    }                                                            \
    Vt = vtl[BUF][S_][vl];                                       \
  }

#define COMPSTEP(Aa, Ww, Kk, Bb, Rr, Vt, TIDX)                              \
  {                                                                         \
    float p0 = 0.f, p1 = 0.f, p2 = 0.f, p3 = 0.f;                           \
    _Pragma("unroll") for (int i = 0; i < 16; i += 4) {                     \
      p0 = fmaf(S[i], Aa[i], p0);                                           \
      p1 = fmaf(S[i + 1], Aa[i + 1], p1);                                   \
      p2 = fmaf(S[i + 2], Aa[i + 2], p2);                                   \
      p3 = fmaf(S[i + 3], Aa[i + 3], p3);                                   \
    }                                                                       \
    float sa = (p0 + p1) + (p2 + p3);                                       \
    sa = dpp_xor1_add(sa);                                                  \
    sa = dpp_xor2_add(sa);                                                  \
    float y0 = 0.f, y1 = 0.f, y2 = 0.f, y3 = 0.f;                           \
    _Pragma("unroll") for (int i = 0; i < 16; i += 4) {                     \
      S[i]     = fmaf(S[i],     Ww[i],     fmaf(Vt, Kk[i],     sa * Bb[i])); \
      S[i + 1] = fmaf(S[i + 1], Ww[i + 1], fmaf(Vt, Kk[i + 1], sa * Bb[i + 1])); \
      S[i + 2] = fmaf(S[i + 2], Ww[i + 2], fmaf(Vt, Kk[i + 2], sa * Bb[i + 2])); \
      S[i + 3] = fmaf(S[i + 3], Ww[i + 3], fmaf(Vt, Kk[i + 3], sa * Bb[i + 3])); \
      y0 = fmaf(S[i], Rr[i], y0);                                           \
      y1 = fmaf(S[i + 1], Rr[i + 1], y1);                                   \
      y2 = fmaf(S[i + 2], Rr[i + 2], y2);                                   \
      y3 = fmaf(S[i + 3], Rr[i + 3], y3);                                   \
    }                                                                       \
    float y = (y0 + y1) + (y2 + y3);                                        \
    y = dpp_xor1_add(y);                                                    \
    y = dpp_xor2_add(y);                                                    \
    if (kq == 0) obf[bh + (size_t)(TIDX)*2048 + v0 + vl] = f2bf(y);         \
  }

__global__ __launch_bounds__(64) void wkv_scan_v4(
    const float* __restrict__ r, const float* __restrict__ k2,
    const float* __restrict__ w, const float* __restrict__ ain,
    const float* __restrict__ bin, const float* __restrict__ vp,
    const float* __restrict__ sInit, unsigned short* __restrict__ obf) {
  __shared__ float lds[2][5][CH][64];      // 80 KiB
  __shared__ float vtl[2][CH][16];         // 2 KiB
  int D = blockIdx.x;
  int chain = (D & 7) + 8 * (D >> 5);      // siblings (vblk 0..3) differ by 8 in D
  int vblk = (D >> 3) & 3;                 //   -> same XCD under %8 round-robin
  int b = chain >> 5, h = chain & 31;
  int v0 = vblk * 16;
  int lane = threadIdx.x;
  int vl = lane >> 2, kq = lane & 3;
  int kb = kq * 16;
  size_t bh = (size_t)(b * T_) * 2048 + (size_t)h * 64;   // element offset at t=0

  float S[16];
  {
    const float* sp = sInit + (((size_t)(chain) * 64 + v0 + vl) * 64) + kb;
    #pragma unroll
    for (int i = 0; i < 16; i += 4) {
      float4 sv = *(const float4*)(sp + i);
      S[i] = sv.x; S[i + 1] = sv.y; S[i + 2] = sv.z; S[i + 3] = sv.w;
    }
  }

  const float* arr[5] = {r, k2, w, ain, bin};

  auto stage = [&](int buf, int t0) {
    #pragma unroll
    for (int a = 0; a < 5; ++a) {
      #pragma unroll
      for (int jj = 0; jj < 8; ++jj) {
        size_t gofs = bh + (size_t)(t0 + jj * 4 + (lane >> 4)) * 2048 + (lane & 15) * 4;
        gload16(arr[a] + gofs, &lds[buf][a][jj * 4][0]);
      }
    }
    #pragma unroll
    for (int di = 0; di < 2; ++di) {
      size_t gofs = bh + (size_t)(t0 + di * 16 + (lane >> 2)) * 2048 + v0 + (lane & 3) * 4;
      gload16(vp + gofs, &vtl[buf][di * 16][0]);
    }
  };

  stage(0, 0);
  asm volatile("s_waitcnt vmcnt(0)" ::: "memory");
  __syncthreads();

  float A0[16], W0[16], K0[16], B0[16], R0[16], vt0;
  float A1[16], W1[16], K1[16], B1[16], R1[16], vt1;

  for (int c = 0; c < T_ / CH; ++c) {
    int cur = c & 1;
    if (c + 1 < T_ / CH) stage(cur ^ 1, (c + 1) * CH);
    int t0 = c * CH;
    LOADSTEP(cur, 0, A0, W0, K0, B0, R0, vt0);
    #pragma unroll 2
    for (int s = 0; s < CH; s += 2) {
      LOADSTEP(cur, s + 1, A1, W1, K1, B1, R1, vt1);
      COMPSTEP(A0, W0, K0, B0, R0, vt0, t0 + s);
      if (s + 2 < CH) LOADSTEP(cur, s + 2, A0, W0, K0, B0, R0, vt0);
      COMPSTEP(A1, W1, K1, B1, R1, vt1, t0 + s + 1);
    }
    asm volatile("s_waitcnt vmcnt(0)" ::: "memory");
    __syncthreads();
  }
}

// ---------------- post: GroupNorm + bonus + gate; one block per (b,t,h) ----------------
// o and g are bf16 (halves of d_out); output afin fp32.
__global__ __launch_bounds__(64) void post(
    const unsigned short* __restrict__ obf, const float* __restrict__ r,
    const float* __restrict__ k2, const float* __restrict__ vp,
    const unsigned short* __restrict__ gbf, const float* __restrict__ r_k,
    const float* __restrict__ lnw, const float* __restrict__ lnb,
    float* __restrict__ afin) {
  __shared__ float red[64];
  int bid = blockIdx.x, tid = threadIdx.x;
  int h = bid & 31;
  size_t base = (size_t)bid * 64 + tid;
  int cc = h * 64 + tid;
  float ov = bf2f(obf[base]);
  red[tid] = ov; __syncthreads();
  for (int s = 32; s > 0; s >>= 1) { if (tid < s) red[tid] += red[tid + s]; __syncthreads(); }
  float mu = red[0] * (1.0f / 64.0f);
  __syncthreads();
  float dv = ov - mu;
  red[tid] = dv * dv; __syncthreads();
  for (int s = 32; s > 0; s >>= 1) { if (tid < s) red[tid] += red[tid + s]; __syncthreads(); }
  float var = red[0] * (1.0f / 64.0f);
  __syncthreads();
  float on = dv * rsqrtf(var + 6.4e-4f) * lnw[cc] + lnb[cc];
  float pr = r[base] * k2[base] * r_k[cc];
  red[tid] = pr; __syncthreads();
  for (int s = 32; s > 0; s >>= 1) { if (tid < s) red[tid] += red[tid + s]; __syncthreads(); }
  float dot = red[0];
  float val = (on + dot * vp[base]) * bf2f(gbf[base]);
  afin[base] = val;
}

// ---------------- host ----------------
static constexpr size_t KB = 1024;
static constexpr size_t O_R    = 0;
static constexpr size_t O_K    = 16384;
static constexpr size_t O_V    = 32768;
static constexpr size_t O_WDEC = 49152;
static constexpr size_t O_AMAT = 65536;
static constexpr size_t O_VMIX = 81920;
static constexpr size_t O_HW   = 98304;
static constexpr size_t O_HA   = 98816;
static constexpr size_t O_HV   = 99328;
static constexpr size_t O_HG   = 99584;
static constexpr size_t O_AIN  = O_AMAT;
static constexpr size_t O_BIN  = O_VMIX;
static constexpr size_t O_AFIN = O_VMIX;
static constexpr size_t O_WRT_H = 49152, O_WRT_L = 57344;
static constexpr size_t O_WKT_H = 65536, O_WKT_L = 73728;
static constexpr size_t O_WVT_H = 81920, O_WVT_L = 90112;
static constexpr size_t O_W1T_H = 49152, O_W1T_L = 49664;
static constexpr size_t O_A1T_H = 50176, O_A1T_L = 50688;
static constexpr size_t O_V1T_H = 51200, O_V1T_L = 51712;
static constexpr size_t O_G1T_H = 52224, O_G1T_L = 52736;
static constexpr size_t O_WOT_H = 0, O_WOT_L = 8192;

extern "C" void kernel_launch(void* const* d_in, const int* in_sizes, int n_in,
                              void* d_out, int out_size, void* d_ws, size_t ws_size,
                              hipStream_t stream) {
  const float* x      = (const float*)d_in[0];
  const float* vfirst = (const float*)d_in[1];
  const float* shift  = (const float*)d_in[2];
  const float* wkv0   = (const float*)d_in[3];
  const float* x_r = (const float*)d_in[4];
  const float* x_w = (const float*)d_in[5];
  const float* x_k = (const float*)d_in[6];
  const float* x_v = (const float*)d_in[7];
  const float* x_a = (const float*)d_in[8];
  const float* x_g = (const float*)d_in[9];
  const float* w0 = (const float*)d_in[10];
  const float* w1 = (const float*)d_in[11];
  const float* w2 = (const float*)d_in[12];
  const float* a0 = (const float*)d_in[13];
  const float* a1 = (const float*)d_in[14];
  const float* a2 = (const float*)d_in[15];
  const float* v0 = (const float*)d_in[16];
  const float* v1 = (const float*)d_in[17];
  const float* v2 = (const float*)d_in[18];
  const float* g1 = (const float*)d_in[19];
  const float* g2 = (const float*)d_in[20];
  const float* k_k = (const float*)d_in[21];
  const float* k_a = (const float*)d_in[22];
  const float* r_k = (const float*)d_in[23];
  const float* W_r = (const float*)d_in[24];
  const float* W_k = (const float*)d_in[25];
  const float* W_v = (const float*)d_in[26];
  const float* W_o = (const float*)d_in[27];
  const float* ln_w = (const float*)d_in[28];
  const float* ln_b = (const float*)d_in[29];

  char* ws = (char*)d_ws;
  auto F = [&](size_t kb) { return (float*)(ws + kb * KB); };
  auto U = [&](size_t kb) { return (unsigned short*)(ws + kb * KB); };
  float* outp = (float*)d_out;
  unsigned short* gbf = (unsigned short*)d_out;                       // 8 MiB
  unsigned short* obf = (unsigned short*)((char*)d_out + 8192 * KB);  // 8 MiB

  // T1a: transpose+split the three big weights into dead WDEC/AMAT/VMIX regions.
  {
    TJobs TG{};
    int cum = 0, i = 0;
    auto addT = [&](const float* src, size_t hkb, size_t lkb) {
      cum += 32 * 32;
      TG.j[i++] = TJob{src, U(hkb), U(lkb), 2048, 32, cum};
    };
    addT(W_r, O_WRT_H, O_WRT_L);
    addT(W_k, O_WKT_H, O_WKT_L);
    addT(W_v, O_WVT_H, O_WVT_L);
    wtrans<<<dim3(cum), dim3(256), 0, stream>>>(TG);
  }

  // G1a (split MFMA): r, k, v with fused token-shift mixes.
  {
    GJobs G{};
    int cum = 0, i = 0;
    auto add = [&](size_t hkb, size_t lkb, float* Cp, const float* mixv) {
      cum += 16 * 16;
      G.j[i++] = GJob{x, U(hkb), U(lkb), Cp, mixv, shift, 2048, 2048, 16, cum};
    };
    add(O_WRT_H, O_WRT_L, F(O_R), x_r);
    add(O_WKT_H, O_WKT_L, F(O_K), x_k);
    add(O_WVT_H, O_WVT_L, F(O_V), x_v);
    gemm_split<<<dim3(cum), dim3(256), 0, stream>>>(G);
  }

  // T1b: transpose+split small LoRA-down weights over dead W_rt space.
  {
    TJobs TG{};
    int cum = 0, i = 0;
    auto addT = [&](const float* src, size_t hkb, size_t lkb, int N) {
      cum += 32 * 2;
      TG.j[i++] = TJob{src, U(hkb), U(lkb), N, 2, cum};
    };
    addT(w1, O_W1T_H, O_W1T_L, 64);
    addT(a1, O_A1T_H, O_A1T_L, 64);
    addT(v1, O_V1T_H, O_V1T_L, 32);
    addT(g1, O_G1T_H, O_G1T_L, 128);
    wtrans<<<dim3(cum), dim3(256), 0, stream>>>(TG);
  }

  // G1b (split MFMA): the four LoRA-down projections.
  {
    GJobs G{};
    int cum = 0, i = 0;
    auto add = [&](size_t hkb, size_t lkb, float* Cp, const float* mixv, int N) {
      cum += 16;
      G.j[i++] = GJob{x, U(hkb), U(lkb), Cp, mixv, shift, N, 2048, 1, cum};
    };
    add(O_W1T_H, O_W1T_L, F(O_HW), x_w, 64);
    add(O_A1T_H, O_A1T_L, F(O_HA), x_a, 64);
    add(O_V1T_H, O_V1T_L, F(O_HV), x_v, 32);
    add(O_G1T_H, O_G1T_L, F(O_HG), x_g, 128);
    gemm_split<<<dim3(cum), dim3(256), 0, stream>>>(G);
  }

  // G2 (fp32 oracle): LoRA-up with fused activations/epilogues. g stored bf16 (epi 3).
  {
    Jobs G{};
    int cum = 0, i = 0;
    auto add = [&](const float* A, const float* W, float* C, const float* bias,
                   int K, int aact, int epi) {
      cum += 32 * 32;
      G.j[i++] = Job{A, W, C, bias, nullptr, nullptr, nullptr, 2048, K, 32, aact, epi, cum};
    };
    add(F(O_HW), w2, F(O_WDEC), w0, 64, 1, 2);
    add(F(O_HA), a2, F(O_AMAT), a0, 64, 0, 1);
    add(F(O_HV), v2, F(O_VMIX), v0, 32, 0, 1);
    add(F(O_HG), g2, (float*)gbf, nullptr, 128, 2, 3);
    gemm_oracle<<<dim3(cum), dim3(256), 0, stream>>>(G);
  }

  // prescan: kk-norm; k->k2, v->v', amat->a_in, vmix->b_in.
  prescan<<<dim3(65536), dim3(64), 0, stream>>>(F(O_K), F(O_V), F(O_AMAT), F(O_VMIX),
                                                vfirst, k_k, k_a);

  // scan v4: 256 XCD-swizzled blocks x 64 threads; o -> bf16 in d_out upper half.
  wkv_scan_v4<<<dim3(256), dim3(64), 0, stream>>>(F(O_R), F(O_K), F(O_WDEC), F(O_AIN),
                                                  F(O_BIN), F(O_V), wkv0, obf);

  // post: GroupNorm + bonus + gate -> afin (bf16 o/g inputs).
  post<<<dim3(65536), dim3(64), 0, stream>>>(obf, F(O_R), F(O_K), F(O_V),
                                             gbf, r_k, ln_w, ln_b, F(O_AFIN));

  // T2: W_o transpose+split into dead r region, then G3 (split MFMA): out = afin @ W_o.
  {
    TJobs TO{};
    TO.j[0] = TJob{W_o, U(O_WOT_H), U(O_WOT_L), 2048, 32, 1024};
    wtrans<<<dim3(1024), dim3(256), 0, stream>>>(TO);
    GJobs G{};
    G.j[0] = GJob{F(O_AFIN), U(O_WOT_H), U(O_WOT_L), outp, nullptr, nullptr,
                  2048, 2048, 16, 256};
    gemm_split<<<dim3(256), dim3(256), 0, stream>>>(G);
  }

  (void)in_sizes; (void)n_in; (void)out_size; (void)ws_size;
}

// Round 6
// 1068.328 us; speedup vs baseline: 1.2737x; 1.0594x over previous
//
#include <hip/hip_runtime.h>
#include <cstdint>
#include <cstddef>

// RWKV-7 Tmix forward, MI355X gfx950 — ROUND 10: scan v5 (8-way v-split, 2 waves/CU).
// r9 result: scan 303 µs, ~710 cy/step. VGPR=132 shows the compiler dropped the
// 2-deep register pipeline (needed ~180 floats); 1 wave/CU => zero TLP, exposed
// lgkm batches. Fix: 512 blocks (8 v-split siblings/chain, all on one XCD via
// D=(chain&7)+8*vblk+64*(chain>>3)) -> 2 waves/CU; per-wave LDS reads halve
// (10 b128/step); 8-lane k-reduce = quad_perm xor1/xor2 + row_half_mirror DPP
// (VALU only); CH=16 double-buffer (2x42 KB/CU); no per-chunk barrier (1 wave).
// GEMMs: split-bf16 MFMA (round-6, verified). o/g as bf16 in d_out (round-9).

#define DI __device__ __forceinline__
static constexpr int T_ = 1024, C_ = 2048, H_ = 32;

typedef __attribute__((ext_vector_type(8))) __bf16 bf16x8;
typedef __attribute__((ext_vector_type(4))) float f32x4;
typedef __attribute__((ext_vector_type(8))) unsigned short us8v;
typedef __attribute__((ext_vector_type(4))) unsigned short us4v;
typedef __attribute__((ext_vector_type(2))) unsigned short us2v;

DI float sig_(float z) { return 1.0f / (1.0f + expf(-z)); }

DI unsigned short f2bf(float f) {           // round-to-nearest-even f32 -> bf16
  union { float f; uint32_t u; } v; v.f = f;
  uint32_t u = v.u;
  return (unsigned short)((u + 0x7FFFu + ((u >> 16) & 1u)) >> 16);
}
DI float bf2f(unsigned short h) {
  union { uint32_t u; float f; } v; v.u = ((uint32_t)h) << 16;
  return v.f;
}

// butterfly adds over the 8 k-lanes (kq = lane&7): quad xor1, xor2, then
// row_half_mirror (lane -> 7-lane within each 8-group). All VALU DPP.
DI float dpp_xor1_add(float x) {
  int r = __builtin_amdgcn_update_dpp(0, __float_as_int(x), 0xB1, 0xF, 0xF, true);
  return x + __int_as_float(r);
}
DI float dpp_xor2_add(float x) {
  int r = __builtin_amdgcn_update_dpp(0, __float_as_int(x), 0x4E, 0xF, 0xF, true);
  return x + __int_as_float(r);
}
DI float dpp_hm_add(float x) {
  int r = __builtin_amdgcn_update_dpp(0, __float_as_int(x), 0x141, 0xF, 0xF, true);
  return x + __int_as_float(r);
}

// async global -> LDS DMA (dest = wave-uniform base + lane*size).
DI void gload16(const float* g, float* l) {
  __builtin_amdgcn_global_load_lds(
      (const __attribute__((address_space(1))) uint32_t*)g,
      (__attribute__((address_space(3))) uint32_t*)l, 16, 0, 0);
}
DI void gload4(const float* g, float* l) {
  __builtin_amdgcn_global_load_lds(
      (const __attribute__((address_space(1))) uint32_t*)g,
      (__attribute__((address_space(3))) uint32_t*)l, 4, 0, 0);
}

// ---------------- fp32 oracle GEMM (kept for G2: K<=128 LoRA-up jobs) ----------------
// epi: 0 fp32 store; 1 sigmoid(bias+v); 2 e^-0.5*sigmoid(bias+v); 3 bf16 store.
struct Job {
  const float* A; const float* W; float* C; const float* bias;
  const float* mixv; const float* x; const float* shift;
  int N, K, ntn, aact, epi, tile_end;
};
struct Jobs { Job j[7]; };

__global__ __launch_bounds__(256) void gemm_oracle(Jobs P) {
  __shared__ float As[64][33];
  __shared__ float Ws[32][65];
  int bx = blockIdx.x, ji = 0;
  while (bx >= P.j[ji].tile_end) ++ji;
  Job J = P.j[ji];
  int tix = bx - (ji ? P.j[ji - 1].tile_end : 0);
  int mt = tix / J.ntn, nt = tix % J.ntn;
  int m0 = mt * 64, n0 = nt * 64;
  int tid = threadIdx.x, tx = tid & 15, ty = tid >> 4;
  float acc[4][4] = {};
  for (int k0 = 0; k0 < J.K; k0 += 32) {
    #pragma unroll
    for (int p = 0; p < 8; ++p) {
      int idx = p * 256 + tid;
      int r = idx >> 5, kc = idx & 31;
      int m = m0 + r, k = k0 + kc;
      float a;
      if (J.mixv) {
        float xv = J.x[(size_t)m * C_ + k];
        int t = m & (T_ - 1);
        float xp = (t == 0) ? J.shift[(size_t)(m >> 10) * C_ + k]
                            : J.x[(size_t)(m - 1) * C_ + k];
        a = xv + (xp - xv) * J.mixv[k];
      } else {
        a = J.A[(size_t)m * J.K + k];
        if (J.aact == 1) a = tanhf(a);
        else if (J.aact == 2) a = sig_(a);
      }
      As[r][kc] = a;
    }
    #pragma unroll
    for (int p = 0; p < 8; ++p) {
      int idx = p * 256 + tid;
      int kr = idx >> 6, nc = idx & 63;
      int n = n0 + nc;
      Ws[kr][nc] = (n < J.N) ? J.W[(size_t)(k0 + kr) * J.N + n] : 0.0f;
    }
    __syncthreads();
    #pragma unroll 4
    for (int kc = 0; kc < 32; ++kc) {
      float av[4], bv[4];
      #pragma unroll
      for (int i = 0; i < 4; ++i) av[i] = As[ty * 4 + i][kc];
      #pragma unroll
      for (int jn = 0; jn < 4; ++jn) bv[jn] = Ws[kc][tx * 4 + jn];
      #pragma unroll
      for (int i = 0; i < 4; ++i)
        #pragma unroll
        for (int jn = 0; jn < 4; ++jn) acc[i][jn] += av[i] * bv[jn];
    }
    __syncthreads();
  }
  #pragma unroll
  for (int i = 0; i < 4; ++i) {
    int rw = m0 + ty * 4 + i;
    #pragma unroll
    for (int jn = 0; jn < 4; ++jn) {
      int col = n0 + tx * 4 + jn;
      if (col < J.N) {
        float v = acc[i][jn];
        if (J.epi == 1) v = sig_(J.bias[col] + v);
        else if (J.epi == 2) v = 0.60653065971263342f * sig_(J.bias[col] + v);
        if (J.epi == 3) ((unsigned short*)J.C)[(size_t)rw * J.N + col] = f2bf(v);
        else            J.C[(size_t)rw * J.N + col] = v;
      }
    }
  }
}

// -------- weight transpose+split: src fp32 [K=2048][N] -> hi/lo bf16 [Npad][2048] --------
struct TJob { const float* src; unsigned short* dh; unsigned short* dl; int N, ntn, tile_end; };
struct TJobs { TJob j[4]; };

__global__ __launch_bounds__(256) void wtrans(TJobs P) {
  __shared__ float t[64][65];
  int bx = blockIdx.x, ji = 0;
  while (bx >= P.j[ji].tile_end) ++ji;
  TJob J = P.j[ji];
  int tix = bx - (ji ? P.j[ji - 1].tile_end : 0);
  int kt = tix / J.ntn, nt = tix % J.ntn;
  int k0 = kt * 64, n0 = nt * 64;
  int tid = threadIdx.x;
  #pragma unroll
  for (int p = 0; p < 16; ++p) {
    int flat = p * 256 + tid;
    int r = flat >> 6, c = flat & 63;
    int n = n0 + c;
    t[r][c] = (n < J.N) ? J.src[(size_t)(k0 + r) * J.N + n] : 0.0f;
  }
  __syncthreads();
  #pragma unroll
  for (int p = 0; p < 8; ++p) {
    int flat = p * 256 + tid;
    int rr = flat >> 5, cc = (flat & 31) * 2;
    float w0v = t[cc][rr], w1v = t[cc + 1][rr];
    unsigned short h0 = f2bf(w0v), h1 = f2bf(w1v);
    us2v oh, ol;
    oh.x = h0; oh.y = h1;
    ol.x = f2bf(w0v - bf2f(h0));
    ol.y = f2bf(w1v - bf2f(h1));
    size_t off = (size_t)(n0 + rr) * 2048 + k0 + cc;
    *(us2v*)(J.dh + off) = oh;
    *(us2v*)(J.dl + off) = ol;
  }
}

// ------------- split-bf16 MFMA GEMM: C[M=2048,N] = A[M,K] @ Wt[N,K]^T -------------
struct GJob {
  const float* A; const unsigned short* Wh; const unsigned short* Wl; float* C;
  const float* mixv; const float* shift;
  int N, K, ntn, tile_end;
};
struct GJobs { GJob j[4]; };

__global__ __launch_bounds__(256) void gemm_split(GJobs P) {
  __shared__ unsigned short Ash[128][40];
  __shared__ unsigned short Asl[128][40];
  __shared__ unsigned short Bsh[128][40];
  __shared__ unsigned short Bsl[128][40];
  int bx = blockIdx.x, ji = 0;
  while (bx >= P.j[ji].tile_end) ++ji;
  GJob J = P.j[ji];
  int tix = bx - (ji ? P.j[ji - 1].tile_end : 0);
  int mt = tix / J.ntn, nt = tix % J.ntn;
  int m0 = mt * 128, n0 = nt * 128;
  int tid = threadIdx.x;
  int lane = tid & 63, wid = tid >> 6;
  int wr = wid >> 1, wc = wid & 1;
  int l15 = lane & 15, lg = lane >> 4;
  f32x4 acc[4][4] = {};

  for (int k0 = 0; k0 < J.K; k0 += 32) {
    #pragma unroll
    for (int p = 0; p < 4; ++p) {
      int flat = p * 256 + tid;
      int r = flat >> 3, kq = flat & 7;
      int m = m0 + r;
      int kk = k0 + kq * 4;
      const float* xp0 = J.A + (size_t)m * J.K + kk;
      float4 xv = *(const float4*)xp0;
      float va[4];
      if (J.mixv) {
        const float* pp = ((m & (T_ - 1)) == 0)
            ? (J.shift + (size_t)(m >> 10) * C_ + kk)
            : (xp0 - C_);
        float4 xq = *(const float4*)pp;
        float4 mv = *(const float4*)(J.mixv + kk);
        va[0] = xv.x + (xq.x - xv.x) * mv.x;
        va[1] = xv.y + (xq.y - xv.y) * mv.y;
        va[2] = xv.z + (xq.z - xv.z) * mv.z;
        va[3] = xv.w + (xq.w - xv.w) * mv.w;
      } else {
        va[0] = xv.x; va[1] = xv.y; va[2] = xv.z; va[3] = xv.w;
      }
      us4v oh, ol;
      #pragma unroll
      for (int q = 0; q < 4; ++q) {
        unsigned short hq = f2bf(va[q]);
        oh[q] = hq;
        ol[q] = f2bf(va[q] - bf2f(hq));
      }
      *(us4v*)&Ash[r][kq * 4] = oh;
      *(us4v*)&Asl[r][kq * 4] = ol;
    }
    #pragma unroll
    for (int p = 0; p < 2; ++p) {
      int flat = p * 256 + tid;
      int r = flat >> 2, ko = (flat & 3) * 8;
      size_t off = (size_t)(n0 + r) * J.K + k0 + ko;
      *(us8v*)&Bsh[r][ko] = *(const us8v*)(J.Wh + off);
      *(us8v*)&Bsl[r][ko] = *(const us8v*)(J.Wl + off);
    }
    __syncthreads();
    bf16x8 afh[4], afl[4], bwh[4], bwl[4];
    #pragma unroll
    for (int i = 0; i < 4; ++i) {
      int rr = wr * 64 + i * 16 + l15;
      afh[i] = __builtin_bit_cast(bf16x8, *(const us8v*)&Ash[rr][lg * 8]);
      afl[i] = __builtin_bit_cast(bf16x8, *(const us8v*)&Asl[rr][lg * 8]);
    }
    #pragma unroll
    for (int i = 0; i < 4; ++i) {
      int rr = wc * 64 + i * 16 + l15;
      bwh[i] = __builtin_bit_cast(bf16x8, *(const us8v*)&Bsh[rr][lg * 8]);
      bwl[i] = __builtin_bit_cast(bf16x8, *(const us8v*)&Bsl[rr][lg * 8]);
    }
    #pragma unroll
    for (int i = 0; i < 4; ++i)
      #pragma unroll
      for (int jn = 0; jn < 4; ++jn) {
        acc[i][jn] = __builtin_amdgcn_mfma_f32_16x16x32_bf16(
            afh[i], bwh[jn], acc[i][jn], 0, 0, 0);
        acc[i][jn] = __builtin_amdgcn_mfma_f32_16x16x32_bf16(
            afl[i], bwh[jn], acc[i][jn], 0, 0, 0);
        acc[i][jn] = __builtin_amdgcn_mfma_f32_16x16x32_bf16(
            afh[i], bwl[jn], acc[i][jn], 0, 0, 0);
      }
    __syncthreads();
  }
  int orow0 = m0 + wr * 64 + 4 * lg;
  int ocol0 = n0 + wc * 64 + l15;
  #pragma unroll
  for (int i = 0; i < 4; ++i) {
    #pragma unroll
    for (int jn = 0; jn < 4; ++jn) {
      int col = ocol0 + jn * 16;
      if (col < J.N) {
        #pragma unroll
        for (int rr = 0; rr < 4; ++rr)
          J.C[(size_t)(orow0 + i * 16 + rr) * J.N + col] = acc[i][jn][rr];
      }
    }
  }
}

// ---------------- prescan: one block per (b,t,h); LDS tree reduction ----------------
__global__ __launch_bounds__(64) void prescan(
    float* __restrict__ kio, float* __restrict__ vio,
    float* __restrict__ amat_ain, float* __restrict__ vmix_bin,
    const float* __restrict__ vfirst,
    const float* __restrict__ k_k, const float* __restrict__ k_a) {
  __shared__ float red[64];
  int bid = blockIdx.x, tid = threadIdx.x;
  int h = bid & (H_ - 1);
  size_t base = (size_t)bid * 64 + tid;
  int cc = h * 64 + tid;
  float kv = kio[base];
  float kkv = kv * k_k[cc];
  red[tid] = kkv * kkv;
  __syncthreads();
  for (int s = 32; s > 0; s >>= 1) { if (tid < s) red[tid] += red[tid + s]; __syncthreads(); }
  float nrm = fmaxf(sqrtf(red[0]), 1e-12f);
  float kkn = kkv / nrm;
  float av = amat_ain[base];
  float vmv = vmix_bin[base];
  float vv = vio[base];
  kio[base] = kv * (1.0f + (av - 1.0f) * k_a[cc]);
  vio[base] = vv + (vfirst[base] - vv) * vmv;
  amat_ain[base] = -kkn;
  vmix_bin[base] = kkn * av;
}

// ------- wkv scan v5: 512 blocks (8 v-split siblings/chain, same XCD) x 64 thr -------
// Lane: vl = lane>>3 (8 v-rows), kq = lane&7 (8 k-slices of 8); S[8] in VGPRs.
// k-reduce: quad xor1 + xor2 + row_half_mirror DPP adds. CH=16 double-buffered
// LDS (42 KiB) staged via global_load_lds; 2-step register pipeline; 1 wave/block
// so no barriers (vmcnt(0) alone orders DMA->LDS->read).
static constexpr int CH = 16;

#define LOADSTEP(BUF, S_, Aa, Ww, Kk, Bb, Rr, Vt)                  \
  {                                                                \
    *(float4*)&Aa[0] = *(const float4*)&lds[BUF][3][S_][kb];       \
    *(float4*)&Aa[4] = *(const float4*)&lds[BUF][3][S_][kb + 4];   \
    *(float4*)&Ww[0] = *(const float4*)&lds[BUF][2][S_][kb];       \
    *(float4*)&Ww[4] = *(const float4*)&lds[BUF][2][S_][kb + 4];   \
    *(float4*)&Kk[0] = *(const float4*)&lds[BUF][1][S_][kb];       \
    *(float4*)&Kk[4] = *(const float4*)&lds[BUF][1][S_][kb + 4];   \
    *(float4*)&Bb[0] = *(const float4*)&lds[BUF][4][S_][kb];       \
    *(float4*)&Bb[4] = *(const float4*)&lds[BUF][4][S_][kb + 4];   \
    *(float4*)&Rr[0] = *(const float4*)&lds[BUF][0][S_][kb];       \
    *(float4*)&Rr[4] = *(const float4*)&lds[BUF][0][S_][kb + 4];   \
    Vt = vtl[BUF][S_][vl];                                         \
  }

#define COMPSTEP(Aa, Ww, Kk, Bb, Rr, Vt, TIDX)                              \
  {                                                                         \
    float p0 = S[0] * Aa[0], p1 = S[1] * Aa[1];                             \
    float p2 = S[2] * Aa[2], p3 = S[3] * Aa[3];                             \
    p0 = fmaf(S[4], Aa[4], p0); p1 = fmaf(S[5], Aa[5], p1);                 \
    p2 = fmaf(S[6], Aa[6], p2); p3 = fmaf(S[7], Aa[7], p3);                 \
    float sa = (p0 + p1) + (p2 + p3);                                       \
    sa = dpp_xor1_add(sa);                                                  \
    sa = dpp_xor2_add(sa);                                                  \
    sa = dpp_hm_add(sa);                                                    \
    float y0 = 0.f, y1 = 0.f, y2 = 0.f, y3 = 0.f;                           \
    _Pragma("unroll") for (int i = 0; i < 8; i += 4) {                      \
      S[i]     = fmaf(S[i],     Ww[i],     fmaf(Vt, Kk[i],     sa * Bb[i])); \
      S[i + 1] = fmaf(S[i + 1], Ww[i + 1], fmaf(Vt, Kk[i + 1], sa * Bb[i + 1])); \
      S[i + 2] = fmaf(S[i + 2], Ww[i + 2], fmaf(Vt, Kk[i + 2], sa * Bb[i + 2])); \
      S[i + 3] = fmaf(S[i + 3], Ww[i + 3], fmaf(Vt, Kk[i + 3], sa * Bb[i + 3])); \
      y0 = fmaf(S[i], Rr[i], y0);                                           \
      y1 = fmaf(S[i + 1], Rr[i + 1], y1);                                   \
      y2 = fmaf(S[i + 2], Rr[i + 2], y2);                                   \
      y3 = fmaf(S[i + 3], Rr[i + 3], y3);                                   \
    }                                                                       \
    float y = (y0 + y1) + (y2 + y3);                                        \
    y = dpp_xor1_add(y);                                                    \
    y = dpp_xor2_add(y);                                                    \
    y = dpp_hm_add(y);                                                      \
    if (kq == 0) obf[bh + (size_t)(TIDX)*2048 + v0 + vl] = f2bf(y);         \
  }

__global__ __launch_bounds__(64) void wkv_scan_v5(
    const float* __restrict__ r, const float* __restrict__ k2,
    const float* __restrict__ w, const float* __restrict__ ain,
    const float* __restrict__ bin, const float* __restrict__ vp,
    const float* __restrict__ sInit, unsigned short* __restrict__ obf) {
  __shared__ float lds[2][5][CH][64];      // 40 KiB
  __shared__ float vtl[2][CH][8];          // 1 KiB
  int D = blockIdx.x;
  int chain = (D & 7) + 8 * (D >> 6);      // all 8 siblings share D&7 -> same XCD
  int vblk = (D >> 3) & 7;
  int b = chain >> 5, h = chain & 31;
  int v0 = vblk * 8;
  int lane = threadIdx.x;
  int vl = lane >> 3, kq = lane & 7;
  int kb = kq * 8;
  size_t bh = (size_t)(b * T_) * 2048 + (size_t)h * 64;   // element offset at t=0

  float S[8];
  {
    const float* sp = sInit + (((size_t)chain * 64 + v0 + vl) * 64) + kb;
    float4 s0 = *(const float4*)(sp);
    float4 s1 = *(const float4*)(sp + 4);
    S[0] = s0.x; S[1] = s0.y; S[2] = s0.z; S[3] = s0.w;
    S[4] = s1.x; S[5] = s1.y; S[6] = s1.z; S[7] = s1.w;
  }

  const float* arr[5] = {r, k2, w, ain, bin};

  auto stage = [&](int buf, int t0) {
    #pragma unroll
    for (int a = 0; a < 5; ++a) {
      #pragma unroll
      for (int jj = 0; jj < 4; ++jj) {     // CH=16 steps x 64 floats = 4 DMAs/array
        size_t gofs = bh + (size_t)(t0 + jj * 4 + (lane >> 4)) * 2048 + (lane & 15) * 4;
        gload16(arr[a] + gofs, &lds[buf][a][jj * 4][0]);
      }
    }
    #pragma unroll
    for (int di = 0; di < 2; ++di) {       // vt: 16 steps x 8 v = 2 x 4B DMAs
      size_t gofs = bh + (size_t)(t0 + di * 8 + (lane >> 3)) * 2048 + v0 + (lane & 7);
      gload4(vp + gofs, &vtl[buf][di * 8][0]);
    }
  };

  stage(0, 0);
  asm volatile("s_waitcnt vmcnt(0)" ::: "memory");

  float A0[8], W0[8], K0[8], B0[8], R0[8], vt0;
  float A1[8], W1[8], K1[8], B1[8], R1[8], vt1;

  for (int c = 0; c < T_ / CH; ++c) {
    int cur = c & 1;
    if (c + 1 < T_ / CH) stage(cur ^ 1, (c + 1) * CH);
    int t0 = c * CH;
    LOADSTEP(cur, 0, A0, W0, K0, B0, R0, vt0);
    #pragma unroll 2
    for (int s = 0; s < CH; s += 2) {
      LOADSTEP(cur, s + 1, A1, W1, K1, B1, R1, vt1);
      COMPSTEP(A0, W0, K0, B0, R0, vt0, t0 + s);
      if (s + 2 < CH) LOADSTEP(cur, s + 2, A0, W0, K0, B0, R0, vt0);
      COMPSTEP(A1, W1, K1, B1, R1, vt1, t0 + s + 1);
    }
    asm volatile("s_waitcnt vmcnt(0)" ::: "memory");
  }
}

// ---------------- post: GroupNorm + bonus + gate; one block per (b,t,h) ----------------
// o and g are bf16 (halves of d_out); output afin fp32.
__global__ __launch_bounds__(64) void post(
    const unsigned short* __restrict__ obf, const float* __restrict__ r,
    const float* __restrict__ k2, const float* __restrict__ vp,
    const unsigned short* __restrict__ gbf, const float* __restrict__ r_k,
    const float* __restrict__ lnw, const float* __restrict__ lnb,
    float* __restrict__ afin) {
  __shared__ float red[64];
  int bid = blockIdx.x, tid = threadIdx.x;
  int h = bid & 31;
  size_t base = (size_t)bid * 64 + tid;
  int cc = h * 64 + tid;
  float ov = bf2f(obf[base]);
  red[tid] = ov; __syncthreads();
  for (int s = 32; s > 0; s >>= 1) { if (tid < s) red[tid] += red[tid + s]; __syncthreads(); }
  float mu = red[0] * (1.0f / 64.0f);
  __syncthreads();
  float dv = ov - mu;
  red[tid] = dv * dv; __syncthreads();
  for (int s = 32; s > 0; s >>= 1) { if (tid < s) red[tid] += red[tid + s]; __syncthreads(); }
  float var = red[0] * (1.0f / 64.0f);
  __syncthreads();
  float on = dv * rsqrtf(var + 6.4e-4f) * lnw[cc] + lnb[cc];
  float pr = r[base] * k2[base] * r_k[cc];
  red[tid] = pr; __syncthreads();
  for (int s = 32; s > 0; s >>= 1) { if (tid < s) red[tid] += red[tid + s]; __syncthreads(); }
  float dot = red[0];
  float val = (on + dot * vp[base]) * bf2f(gbf[base]);
  afin[base] = val;
}

// ---------------- host ----------------
static constexpr size_t KB = 1024;
static constexpr size_t O_R    = 0;
static constexpr size_t O_K    = 16384;
static constexpr size_t O_V    = 32768;
static constexpr size_t O_WDEC = 49152;
static constexpr size_t O_AMAT = 65536;
static constexpr size_t O_VMIX = 81920;
static constexpr size_t O_HW   = 98304;
static constexpr size_t O_HA   = 98816;
static constexpr size_t O_HV   = 99328;
static constexpr size_t O_HG   = 99584;
static constexpr size_t O_AIN  = O_AMAT;
static constexpr size_t O_BIN  = O_VMIX;
static constexpr size_t O_AFIN = O_VMIX;
static constexpr size_t O_WRT_H = 49152, O_WRT_L = 57344;
static constexpr size_t O_WKT_H = 65536, O_WKT_L = 73728;
static constexpr size_t O_WVT_H = 81920, O_WVT_L = 90112;
static constexpr size_t O_W1T_H = 49152, O_W1T_L = 49664;
static constexpr size_t O_A1T_H = 50176, O_A1T_L = 50688;
static constexpr size_t O_V1T_H = 51200, O_V1T_L = 51712;
static constexpr size_t O_G1T_H = 52224, O_G1T_L = 52736;
static constexpr size_t O_WOT_H = 0, O_WOT_L = 8192;

extern "C" void kernel_launch(void* const* d_in, const int* in_sizes, int n_in,
                              void* d_out, int out_size, void* d_ws, size_t ws_size,
                              hipStream_t stream) {
  const float* x      = (const float*)d_in[0];
  const float* vfirst = (const float*)d_in[1];
  const float* shift  = (const float*)d_in[2];
  const float* wkv0   = (const float*)d_in[3];
  const float* x_r = (const float*)d_in[4];
  const float* x_w = (const float*)d_in[5];
  const float* x_k = (const float*)d_in[6];
  const float* x_v = (const float*)d_in[7];
  const float* x_a = (const float*)d_in[8];
  const float* x_g = (const float*)d_in[9];
  const float* w0 = (const float*)d_in[10];
  const float* w1 = (const float*)d_in[11];
  const float* w2 = (const float*)d_in[12];
  const float* a0 = (const float*)d_in[13];
  const float* a1 = (const float*)d_in[14];
  const float* a2 = (const float*)d_in[15];
  const float* v0 = (const float*)d_in[16];
  const float* v1 = (const float*)d_in[17];
  const float* v2 = (const float*)d_in[18];
  const float* g1 = (const float*)d_in[19];
  const float* g2 = (const float*)d_in[20];
  const float* k_k = (const float*)d_in[21];
  const float* k_a = (const float*)d_in[22];
  const float* r_k = (const float*)d_in[23];
  const float* W_r = (const float*)d_in[24];
  const float* W_k = (const float*)d_in[25];
  const float* W_v = (const float*)d_in[26];
  const float* W_o = (const float*)d_in[27];
  const float* ln_w = (const float*)d_in[28];
  const float* ln_b = (const float*)d_in[29];

  char* ws = (char*)d_ws;
  auto F = [&](size_t kb) { return (float*)(ws + kb * KB); };
  auto U = [&](size_t kb) { return (unsigned short*)(ws + kb * KB); };
  float* outp = (float*)d_out;
  unsigned short* gbf = (unsigned short*)d_out;                       // 8 MiB
  unsigned short* obf = (unsigned short*)((char*)d_out + 8192 * KB);  // 8 MiB

  // T1a: transpose+split the three big weights into dead WDEC/AMAT/VMIX regions.
  {
    TJobs TG{};
    int cum = 0, i = 0;
    auto addT = [&](const float* src, size_t hkb, size_t lkb) {
      cum += 32 * 32;
      TG.j[i++] = TJob{src, U(hkb), U(lkb), 2048, 32, cum};
    };
    addT(W_r, O_WRT_H, O_WRT_L);
    addT(W_k, O_WKT_H, O_WKT_L);
    addT(W_v, O_WVT_H, O_WVT_L);
    wtrans<<<dim3(cum), dim3(256), 0, stream>>>(TG);
  }

  // G1a (split MFMA): r, k, v with fused token-shift mixes.
  {
    GJobs G{};
    int cum = 0, i = 0;
    auto add = [&](size_t hkb, size_t lkb, float* Cp, const float* mixv) {
      cum += 16 * 16;
      G.j[i++] = GJob{x, U(hkb), U(lkb), Cp, mixv, shift, 2048, 2048, 16, cum};
    };
    add(O_WRT_H, O_WRT_L, F(O_R), x_r);
    add(O_WKT_H, O_WKT_L, F(O_K), x_k);
    add(O_WVT_H, O_WVT_L, F(O_V), x_v);
    gemm_split<<<dim3(cum), dim3(256), 0, stream>>>(G);
  }

  // T1b: transpose+split small LoRA-down weights over dead W_rt space.
  {
    TJobs TG{};
    int cum = 0, i = 0;
    auto addT = [&](const float* src, size_t hkb, size_t lkb, int N) {
      cum += 32 * 2;
      TG.j[i++] = TJob{src, U(hkb), U(lkb), N, 2, cum};
    };
    addT(w1, O_W1T_H, O_W1T_L, 64);
    addT(a1, O_A1T_H, O_A1T_L, 64);
    addT(v1, O_V1T_H, O_V1T_L, 32);
    addT(g1, O_G1T_H, O_G1T_L, 128);
    wtrans<<<dim3(cum), dim3(256), 0, stream>>>(TG);
  }

  // G1b (split MFMA): the four LoRA-down projections.
  {
    GJobs G{};
    int cum = 0, i = 0;
    auto add = [&](size_t hkb, size_t lkb, float* Cp, const float* mixv, int N) {
      cum += 16;
      G.j[i++] = GJob{x, U(hkb), U(lkb), Cp, mixv, shift, N, 2048, 1, cum};
    };
    add(O_W1T_H, O_W1T_L, F(O_HW), x_w, 64);
    add(O_A1T_H, O_A1T_L, F(O_HA), x_a, 64);
    add(O_V1T_H, O_V1T_L, F(O_HV), x_v, 32);
    add(O_G1T_H, O_G1T_L, F(O_HG), x_g, 128);
    gemm_split<<<dim3(cum), dim3(256), 0, stream>>>(G);
  }

  // G2 (fp32 oracle): LoRA-up with fused activations/epilogues. g stored bf16 (epi 3).
  {
    Jobs G{};
    int cum = 0, i = 0;
    auto add = [&](const float* A, const float* W, float* C, const float* bias,
                   int K, int aact, int epi) {
      cum += 32 * 32;
      G.j[i++] = Job{A, W, C, bias, nullptr, nullptr, nullptr, 2048, K, 32, aact, epi, cum};
    };
    add(F(O_HW), w2, F(O_WDEC), w0, 64, 1, 2);
    add(F(O_HA), a2, F(O_AMAT), a0, 64, 0, 1);
    add(F(O_HV), v2, F(O_VMIX), v0, 32, 0, 1);
    add(F(O_HG), g2, (float*)gbf, nullptr, 128, 2, 3);
    gemm_oracle<<<dim3(cum), dim3(256), 0, stream>>>(G);
  }

  // prescan: kk-norm; k->k2, v->v', amat->a_in, vmix->b_in.
  prescan<<<dim3(65536), dim3(64), 0, stream>>>(F(O_K), F(O_V), F(O_AMAT), F(O_VMIX),
                                                vfirst, k_k, k_a);

  // scan v5: 512 XCD-grouped blocks x 64 threads; o -> bf16 in d_out upper half.
  wkv_scan_v5<<<dim3(512), dim3(64), 0, stream>>>(F(O_R), F(O_K), F(O_WDEC), F(O_AIN),
                                                  F(O_BIN), F(O_V), wkv0, obf);

  // post: GroupNorm + bonus + gate -> afin (bf16 o/g inputs).
  post<<<dim3(65536), dim3(64), 0, stream>>>(obf, F(O_R), F(O_K), F(O_V),
                                             gbf, r_k, ln_w, ln_b, F(O_AFIN));

  // T2: W_o transpose+split into dead r region, then G3 (split MFMA): out = afin @ W_o.
  {
    TJobs TO{};
    TO.j[0] = TJob{W_o, U(O_WOT_H), U(O_WOT_L), 2048, 32, 1024};
    wtrans<<<dim3(1024), dim3(256), 0, stream>>>(TO);
    GJobs G{};
    G.j[0] = GJob{F(O_AFIN), U(O_WOT_H), U(O_WOT_L), outp, nullptr, nullptr,
                  2048, 2048, 16, 256};
    gemm_split<<<dim3(256), dim3(256), 0, stream>>>(G);
  }

  (void)in_sizes; (void)n_in; (void)out_size; (void)ws_size;
}

// Round 7
// 898.240 us; speedup vs baseline: 1.5148x; 1.1894x over previous
//
#include <hip/hip_runtime.h>
#include <cstdint>
#include <cstddef>

// RWKV-7 Tmix forward, MI355X gfx950 — ROUND 11: GEMM-side restructure.
// r10 profile: G1a 247 µs (Mfma 27%, VALU 30% — 2-barrier stall), G1b 64 blocks
// = 82 µs for 5% of the FLOPs, G3 256 blocks = 82 µs (1 block/CU, no TLP).
// Fixes: (1) G1b merged into G1a via exact-N bf16 planes in the O_HW region
// (hidden LoRA activations relocate to d_out upper half, dead until scan);
// (2) T14 async-stage in gemm_split: next k-step's global loads issued before
// the MFMA cluster, convert+ds_write after the barrier; (3) G3 split-K 2 with
// fp32 atomicAdd (d_out memset after post). Scan v5 unchanged (r10, verified).

#define DI __device__ __forceinline__
static constexpr int T_ = 1024, C_ = 2048, H_ = 32;

typedef __attribute__((ext_vector_type(8))) __bf16 bf16x8;
typedef __attribute__((ext_vector_type(4))) float f32x4;
typedef __attribute__((ext_vector_type(8))) unsigned short us8v;
typedef __attribute__((ext_vector_type(4))) unsigned short us4v;
typedef __attribute__((ext_vector_type(2))) unsigned short us2v;

DI float sig_(float z) { return 1.0f / (1.0f + expf(-z)); }

DI unsigned short f2bf(float f) {           // round-to-nearest-even f32 -> bf16
  union { float f; uint32_t u; } v; v.f = f;
  uint32_t u = v.u;
  return (unsigned short)((u + 0x7FFFu + ((u >> 16) & 1u)) >> 16);
}
DI float bf2f(unsigned short h) {
  union { uint32_t u; float f; } v; v.u = ((uint32_t)h) << 16;
  return v.f;
}

// DPP butterfly adds over 8 k-lanes (kq = lane&7): quad xor1, xor2, half-mirror.
DI float dpp_xor1_add(float x) {
  int r = __builtin_amdgcn_update_dpp(0, __float_as_int(x), 0xB1, 0xF, 0xF, true);
  return x + __int_as_float(r);
}
DI float dpp_xor2_add(float x) {
  int r = __builtin_amdgcn_update_dpp(0, __float_as_int(x), 0x4E, 0xF, 0xF, true);
  return x + __int_as_float(r);
}
DI float dpp_hm_add(float x) {
  int r = __builtin_amdgcn_update_dpp(0, __float_as_int(x), 0x141, 0xF, 0xF, true);
  return x + __int_as_float(r);
}

// async global -> LDS DMA (dest = wave-uniform base + lane*size).
DI void gload16(const float* g, float* l) {
  __builtin_amdgcn_global_load_lds(
      (const __attribute__((address_space(1))) uint32_t*)g,
      (__attribute__((address_space(3))) uint32_t*)l, 16, 0, 0);
}
DI void gload4(const float* g, float* l) {
  __builtin_amdgcn_global_load_lds(
      (const __attribute__((address_space(1))) uint32_t*)g,
      (__attribute__((address_space(3))) uint32_t*)l, 4, 0, 0);
}

// ---------------- fp32 oracle GEMM (G2: K<=128 LoRA-up jobs) ----------------
// epi: 0 fp32 store; 1 sigmoid(bias+v); 2 e^-0.5*sigmoid(bias+v); 3 bf16 store.
struct Job {
  const float* A; const float* W; float* C; const float* bias;
  const float* mixv; const float* x; const float* shift;
  int N, K, ntn, aact, epi, tile_end;
};
struct Jobs { Job j[7]; };

__global__ __launch_bounds__(256) void gemm_oracle(Jobs P) {
  __shared__ float As[64][33];
  __shared__ float Ws[32][65];
  int bx = blockIdx.x, ji = 0;
  while (bx >= P.j[ji].tile_end) ++ji;
  Job J = P.j[ji];
  int tix = bx - (ji ? P.j[ji - 1].tile_end : 0);
  int mt = tix / J.ntn, nt = tix % J.ntn;
  int m0 = mt * 64, n0 = nt * 64;
  int tid = threadIdx.x, tx = tid & 15, ty = tid >> 4;
  float acc[4][4] = {};
  for (int k0 = 0; k0 < J.K; k0 += 32) {
    #pragma unroll
    for (int p = 0; p < 8; ++p) {
      int idx = p * 256 + tid;
      int r = idx >> 5, kc = idx & 31;
      int m = m0 + r, k = k0 + kc;
      float a;
      if (J.mixv) {
        float xv = J.x[(size_t)m * C_ + k];
        int t = m & (T_ - 1);
        float xp = (t == 0) ? J.shift[(size_t)(m >> 10) * C_ + k]
                            : J.x[(size_t)(m - 1) * C_ + k];
        a = xv + (xp - xv) * J.mixv[k];
      } else {
        a = J.A[(size_t)m * J.K + k];
        if (J.aact == 1) a = tanhf(a);
        else if (J.aact == 2) a = sig_(a);
      }
      As[r][kc] = a;
    }
    #pragma unroll
    for (int p = 0; p < 8; ++p) {
      int idx = p * 256 + tid;
      int kr = idx >> 6, nc = idx & 63;
      int n = n0 + nc;
      Ws[kr][nc] = (n < J.N) ? J.W[(size_t)(k0 + kr) * J.N + n] : 0.0f;
    }
    __syncthreads();
    #pragma unroll 4
    for (int kc = 0; kc < 32; ++kc) {
      float av[4], bv[4];
      #pragma unroll
      for (int i = 0; i < 4; ++i) av[i] = As[ty * 4 + i][kc];
      #pragma unroll
      for (int jn = 0; jn < 4; ++jn) bv[jn] = Ws[kc][tx * 4 + jn];
      #pragma unroll
      for (int i = 0; i < 4; ++i)
        #pragma unroll
        for (int jn = 0; jn < 4; ++jn) acc[i][jn] += av[i] * bv[jn];
    }
    __syncthreads();
  }
  #pragma unroll
  for (int i = 0; i < 4; ++i) {
    int rw = m0 + ty * 4 + i;
    #pragma unroll
    for (int jn = 0; jn < 4; ++jn) {
      int col = n0 + tx * 4 + jn;
      if (col < J.N) {
        float v = acc[i][jn];
        if (J.epi == 1) v = sig_(J.bias[col] + v);
        else if (J.epi == 2) v = 0.60653065971263342f * sig_(J.bias[col] + v);
        if (J.epi == 3) ((unsigned short*)J.C)[(size_t)rw * J.N + col] = f2bf(v);
        else            J.C[(size_t)rw * J.N + col] = v;
      }
    }
  }
}

// -------- weight transpose+split: src fp32 [K=2048][N] -> hi/lo bf16 [N][2048] --------
// Exact-N planes: stores guarded (n0+rr < N); loads zero-filled (harmless).
struct TJob { const float* src; unsigned short* dh; unsigned short* dl; int N, ntn, tile_end; };
struct TJobs { TJob j[8]; };

__global__ __launch_bounds__(256) void wtrans(TJobs P) {
  __shared__ float t[64][65];
  int bx = blockIdx.x, ji = 0;
  while (bx >= P.j[ji].tile_end) ++ji;
  TJob J = P.j[ji];
  int tix = bx - (ji ? P.j[ji - 1].tile_end : 0);
  int kt = tix / J.ntn, nt = tix % J.ntn;
  int k0 = kt * 64, n0 = nt * 64;
  int tid = threadIdx.x;
  #pragma unroll
  for (int p = 0; p < 16; ++p) {
    int flat = p * 256 + tid;
    int r = flat >> 6, c = flat & 63;
    int n = n0 + c;
    t[r][c] = (n < J.N) ? J.src[(size_t)(k0 + r) * J.N + n] : 0.0f;
  }
  __syncthreads();
  #pragma unroll
  for (int p = 0; p < 8; ++p) {
    int flat = p * 256 + tid;
    int rr = flat >> 5, cc = (flat & 31) * 2;
    if (n0 + rr < J.N) {
      float w0v = t[cc][rr], w1v = t[cc + 1][rr];
      unsigned short h0 = f2bf(w0v), h1 = f2bf(w1v);
      us2v oh, ol;
      oh.x = h0; oh.y = h1;
      ol.x = f2bf(w0v - bf2f(h0));
      ol.y = f2bf(w1v - bf2f(h1));
      size_t off = (size_t)(n0 + rr) * 2048 + k0 + cc;
      *(us2v*)(J.dh + off) = oh;
      *(us2v*)(J.dl + off) = ol;
    }
  }
}

// ------------- split-bf16 MFMA GEMM: C[M=2048,N] = A[M,K] @ Wt[N,K]^T -------------
// T14 pipeline: next k-step's global loads issued before the MFMA cluster;
// convert + ds_write after the barrier. kbeg/kend enable split-K; atomicC
// accumulates partials with fp32 atomicAdd (output must be pre-zeroed).
struct GJob {
  const float* A; const unsigned short* Wh; const unsigned short* Wl; float* C;
  const float* mixv; const float* shift;
  int N, K, ntn, kbeg, kend, atomicC, tile_end;
};
struct GJobs { GJob j[8]; };

__global__ __launch_bounds__(256) void gemm_split(GJobs P) {
  __shared__ unsigned short Ash[128][40];
  __shared__ unsigned short Asl[128][40];
  __shared__ unsigned short Bsh[128][40];
  __shared__ unsigned short Bsl[128][40];
  int bx = blockIdx.x, ji = 0;
  while (bx >= P.j[ji].tile_end) ++ji;
  GJob J = P.j[ji];
  int tix = bx - (ji ? P.j[ji - 1].tile_end : 0);
  int mt = tix / J.ntn, nt = tix % J.ntn;
  int m0 = mt * 128, n0 = nt * 128;
  int tid = threadIdx.x;
  int lane = tid & 63, wid = tid >> 6;
  int wr = wid >> 1, wc = wid & 1;
  int l15 = lane & 15, lg = lane >> 4;
  f32x4 acc[4][4] = {};

  // staging geometry: A rows p*32 + (tid>>3), k-quad tid&7 (same for all p);
  // B rows p*64 + (tid>>2), k-octet (tid&3)*8.
  int sr = tid >> 3, skq = tid & 7;
  int br = tid >> 2, bko = (tid & 3) * 8;

  float ax[4][4], aq[4][4], amv[4];
  us8v vbh[2], vbl[2];

  auto loadA = [&](int k0) {
    int kk = k0 + skq * 4;
    if (J.mixv) *(float4*)amv = *(const float4*)(J.mixv + kk);
    #pragma unroll
    for (int p = 0; p < 4; ++p) {
      int m = m0 + p * 32 + sr;
      const float* xp0 = J.A + (size_t)m * J.K + kk;
      *(float4*)ax[p] = *(const float4*)xp0;
      if (J.mixv) {
        const float* pp = ((m & (T_ - 1)) == 0)
            ? (J.shift + (size_t)(m >> 10) * C_ + kk)
            : (xp0 - C_);
        *(float4*)aq[p] = *(const float4*)pp;
      }
    }
  };
  auto loadB = [&](int k0) {
    #pragma unroll
    for (int p = 0; p < 2; ++p) {
      size_t off = (size_t)(n0 + p * 64 + br) * J.K + k0 + bko;
      vbh[p] = *(const us8v*)(J.Wh + off);
      vbl[p] = *(const us8v*)(J.Wl + off);
    }
  };
  auto writeAB = [&]() {
    #pragma unroll
    for (int p = 0; p < 4; ++p) {
      us4v oh, ol;
      #pragma unroll
      for (int q = 0; q < 4; ++q) {
        float va = J.mixv ? (ax[p][q] + (aq[p][q] - ax[p][q]) * amv[q]) : ax[p][q];
        unsigned short hq = f2bf(va);
        oh[q] = hq;
        ol[q] = f2bf(va - bf2f(hq));
      }
      int r = p * 32 + sr;
      *(us4v*)&Ash[r][skq * 4] = oh;
      *(us4v*)&Asl[r][skq * 4] = ol;
    }
    #pragma unroll
    for (int p = 0; p < 2; ++p) {
      int rrow = p * 64 + br;
      *(us8v*)&Bsh[rrow][bko] = vbh[p];
      *(us8v*)&Bsl[rrow][bko] = vbl[p];
    }
  };

  loadA(J.kbeg); loadB(J.kbeg);
  writeAB();
  __syncthreads();

  for (int k0 = J.kbeg; k0 < J.kend; k0 += 32) {
    bool more = (k0 + 32 < J.kend);
    if (more) { loadA(k0 + 32); loadB(k0 + 32); }   // T14: issue before MFMA
    bf16x8 afh[4], afl[4], bwh[4], bwl[4];
    #pragma unroll
    for (int i = 0; i < 4; ++i) {
      int rr = wr * 64 + i * 16 + l15;
      afh[i] = __builtin_bit_cast(bf16x8, *(const us8v*)&Ash[rr][lg * 8]);
      afl[i] = __builtin_bit_cast(bf16x8, *(const us8v*)&Asl[rr][lg * 8]);
    }
    #pragma unroll
    for (int i = 0; i < 4; ++i) {
      int rr = wc * 64 + i * 16 + l15;
      bwh[i] = __builtin_bit_cast(bf16x8, *(const us8v*)&Bsh[rr][lg * 8]);
      bwl[i] = __builtin_bit_cast(bf16x8, *(const us8v*)&Bsl[rr][lg * 8]);
    }
    #pragma unroll
    for (int i = 0; i < 4; ++i)
      #pragma unroll
      for (int jn = 0; jn < 4; ++jn) {
        acc[i][jn] = __builtin_amdgcn_mfma_f32_16x16x32_bf16(
            afh[i], bwh[jn], acc[i][jn], 0, 0, 0);
        acc[i][jn] = __builtin_amdgcn_mfma_f32_16x16x32_bf16(
            afl[i], bwh[jn], acc[i][jn], 0, 0, 0);
        acc[i][jn] = __builtin_amdgcn_mfma_f32_16x16x32_bf16(
            afh[i], bwl[jn], acc[i][jn], 0, 0, 0);
      }
    __syncthreads();
    if (more) writeAB();                             // T14: write after barrier
    __syncthreads();
  }

  int orow0 = m0 + wr * 64 + 4 * lg;
  int ocol0 = n0 + wc * 64 + l15;
  #pragma unroll
  for (int i = 0; i < 4; ++i) {
    #pragma unroll
    for (int jn = 0; jn < 4; ++jn) {
      int col = ocol0 + jn * 16;
      if (col < J.N) {
        #pragma unroll
        for (int rr = 0; rr < 4; ++rr) {
          size_t idx = (size_t)(orow0 + i * 16 + rr) * J.N + col;
          float v = acc[i][jn][rr];
          if (J.atomicC) atomicAdd(&J.C[idx], v);
          else           J.C[idx] = v;
        }
      }
    }
  }
}

// ---------------- prescan: one block per (b,t,h); LDS tree reduction ----------------
__global__ __launch_bounds__(64) void prescan(
    float* __restrict__ kio, float* __restrict__ vio,
    float* __restrict__ amat_ain, float* __restrict__ vmix_bin,
    const float* __restrict__ vfirst,
    const float* __restrict__ k_k, const float* __restrict__ k_a) {
  __shared__ float red[64];
  int bid = blockIdx.x, tid = threadIdx.x;
  int h = bid & (H_ - 1);
  size_t base = (size_t)bid * 64 + tid;
  int cc = h * 64 + tid;
  float kv = kio[base];
  float kkv = kv * k_k[cc];
  red[tid] = kkv * kkv;
  __syncthreads();
  for (int s = 32; s > 0; s >>= 1) { if (tid < s) red[tid] += red[tid + s]; __syncthreads(); }
  float nrm = fmaxf(sqrtf(red[0]), 1e-12f);
  float kkn = kkv / nrm;
  float av = amat_ain[base];
  float vmv = vmix_bin[base];
  float vv = vio[base];
  kio[base] = kv * (1.0f + (av - 1.0f) * k_a[cc]);
  vio[base] = vv + (vfirst[base] - vv) * vmv;
  amat_ain[base] = -kkn;
  vmix_bin[base] = kkn * av;
}

// ------- wkv scan v5: 512 blocks (8 v-split siblings/chain, same XCD) x 64 thr -------
static constexpr int CH = 16;

#define LOADSTEP(BUF, S_, Aa, Ww, Kk, Bb, Rr, Vt)                  \
  {                                                                \
    *(float4*)&Aa[0] = *(const float4*)&lds[BUF][3][S_][kb];       \
    *(float4*)&Aa[4] = *(const float4*)&lds[BUF][3][S_][kb + 4];   \
    *(float4*)&Ww[0] = *(const float4*)&lds[BUF][2][S_][kb];       \
    *(float4*)&Ww[4] = *(const float4*)&lds[BUF][2][S_][kb + 4];   \
    *(float4*)&Kk[0] = *(const float4*)&lds[BUF][1][S_][kb];       \
    *(float4*)&Kk[4] = *(const float4*)&lds[BUF][1][S_][kb + 4];   \
    *(float4*)&Bb[0] = *(const float4*)&lds[BUF][4][S_][kb];       \
    *(float4*)&Bb[4] = *(const float4*)&lds[BUF][4][S_][kb + 4];   \
    *(float4*)&Rr[0] = *(const float4*)&lds[BUF][0][S_][kb];       \
    *(float4*)&Rr[4] = *(const float4*)&lds[BUF][0][S_][kb + 4];   \
    Vt = vtl[BUF][S_][vl];                                         \
  }

#define COMPSTEP(Aa, Ww, Kk, Bb, Rr, Vt, TIDX)                              \
  {                                                                         \
    float p0 = S[0] * Aa[0], p1 = S[1] * Aa[1];                             \
    float p2 = S[2] * Aa[2], p3 = S[3] * Aa[3];                             \
    p0 = fmaf(S[4], Aa[4], p0); p1 = fmaf(S[5], Aa[5], p1);                 \
    p2 = fmaf(S[6], Aa[6], p2); p3 = fmaf(S[7], Aa[7], p3);                 \
    float sa = (p0 + p1) + (p2 + p3);                                       \
    sa = dpp_xor1_add(sa);                                                  \
    sa = dpp_xor2_add(sa);                                                  \
    sa = dpp_hm_add(sa);                                                    \
    float y0 = 0.f, y1 = 0.f, y2 = 0.f, y3 = 0.f;                           \
    _Pragma("unroll") for (int i = 0; i < 8; i += 4) {                      \
      S[i]     = fmaf(S[i],     Ww[i],     fmaf(Vt, Kk[i],     sa * Bb[i])); \
      S[i + 1] = fmaf(S[i + 1], Ww[i + 1], fmaf(Vt, Kk[i + 1], sa * Bb[i + 1])); \
      S[i + 2] = fmaf(S[i + 2], Ww[i + 2], fmaf(Vt, Kk[i + 2], sa * Bb[i + 2])); \
      S[i + 3] = fmaf(S[i + 3], Ww[i + 3], fmaf(Vt, Kk[i + 3], sa * Bb[i + 3])); \
      y0 = fmaf(S[i], Rr[i], y0);                                           \
      y1 = fmaf(S[i + 1], Rr[i + 1], y1);                                   \
      y2 = fmaf(S[i + 2], Rr[i + 2], y2);                                   \
      y3 = fmaf(S[i + 3], Rr[i + 3], y3);                                   \
    }                                                                       \
    float y = (y0 + y1) + (y2 + y3);                                        \
    y = dpp_xor1_add(y);                                                    \
    y = dpp_xor2_add(y);                                                    \
    y = dpp_hm_add(y);                                                      \
    if (kq == 0) obf[bh + (size_t)(TIDX)*2048 + v0 + vl] = f2bf(y);         \
  }

__global__ __launch_bounds__(64) void wkv_scan_v5(
    const float* __restrict__ r, const float* __restrict__ k2,
    const float* __restrict__ w, const float* __restrict__ ain,
    const float* __restrict__ bin, const float* __restrict__ vp,
    const float* __restrict__ sInit, unsigned short* __restrict__ obf) {
  __shared__ float lds[2][5][CH][64];      // 40 KiB
  __shared__ float vtl[2][CH][8];          // 1 KiB
  int D = blockIdx.x;
  int chain = (D & 7) + 8 * (D >> 6);      // all 8 siblings share D&7 -> same XCD
  int vblk = (D >> 3) & 7;
  int b = chain >> 5, h = chain & 31;
  int v0 = vblk * 8;
  int lane = threadIdx.x;
  int vl = lane >> 3, kq = lane & 7;
  int kb = kq * 8;
  size_t bh = (size_t)(b * T_) * 2048 + (size_t)h * 64;

  float S[8];
  {
    const float* sp = sInit + (((size_t)chain * 64 + v0 + vl) * 64) + kb;
    float4 s0 = *(const float4*)(sp);
    float4 s1 = *(const float4*)(sp + 4);
    S[0] = s0.x; S[1] = s0.y; S[2] = s0.z; S[3] = s0.w;
    S[4] = s1.x; S[5] = s1.y; S[6] = s1.z; S[7] = s1.w;
  }

  const float* arr[5] = {r, k2, w, ain, bin};

  auto stage = [&](int buf, int t0) {
    #pragma unroll
    for (int a = 0; a < 5; ++a) {
      #pragma unroll
      for (int jj = 0; jj < 4; ++jj) {
        size_t gofs = bh + (size_t)(t0 + jj * 4 + (lane >> 4)) * 2048 + (lane & 15) * 4;
        gload16(arr[a] + gofs, &lds[buf][a][jj * 4][0]);
      }
    }
    #pragma unroll
    for (int di = 0; di < 2; ++di) {
      size_t gofs = bh + (size_t)(t0 + di * 8 + (lane >> 3)) * 2048 + v0 + (lane & 7);
      gload4(vp + gofs, &vtl[buf][di * 8][0]);
    }
  };

  stage(0, 0);
  asm volatile("s_waitcnt vmcnt(0)" ::: "memory");

  float A0[8], W0[8], K0[8], B0[8], R0[8], vt0;
  float A1[8], W1[8], K1[8], B1[8], R1[8], vt1;

  for (int c = 0; c < T_ / CH; ++c) {
    int cur = c & 1;
    if (c + 1 < T_ / CH) stage(cur ^ 1, (c + 1) * CH);
    int t0 = c * CH;
    LOADSTEP(cur, 0, A0, W0, K0, B0, R0, vt0);
    #pragma unroll 2
    for (int s = 0; s < CH; s += 2) {
      LOADSTEP(cur, s + 1, A1, W1, K1, B1, R1, vt1);
      COMPSTEP(A0, W0, K0, B0, R0, vt0, t0 + s);
      if (s + 2 < CH) LOADSTEP(cur, s + 2, A0, W0, K0, B0, R0, vt0);
      COMPSTEP(A1, W1, K1, B1, R1, vt1, t0 + s + 1);
    }
    asm volatile("s_waitcnt vmcnt(0)" ::: "memory");
  }
}

// ---------------- post: GroupNorm + bonus + gate; one block per (b,t,h) ----------------
__global__ __launch_bounds__(64) void post(
    const unsigned short* __restrict__ obf, const float* __restrict__ r,
    const float* __restrict__ k2, const float* __restrict__ vp,
    const unsigned short* __restrict__ gbf, const float* __restrict__ r_k,
    const float* __restrict__ lnw, const float* __restrict__ lnb,
    float* __restrict__ afin) {
  __shared__ float red[64];
  int bid = blockIdx.x, tid = threadIdx.x;
  int h = bid & 31;
  size_t base = (size_t)bid * 64 + tid;
  int cc = h * 64 + tid;
  float ov = bf2f(obf[base]);
  red[tid] = ov; __syncthreads();
  for (int s = 32; s > 0; s >>= 1) { if (tid < s) red[tid] += red[tid + s]; __syncthreads(); }
  float mu = red[0] * (1.0f / 64.0f);
  __syncthreads();
  float dv = ov - mu;
  red[tid] = dv * dv; __syncthreads();
  for (int s = 32; s > 0; s >>= 1) { if (tid < s) red[tid] += red[tid + s]; __syncthreads(); }
  float var = red[0] * (1.0f / 64.0f);
  __syncthreads();
  float on = dv * rsqrtf(var + 6.4e-4f) * lnw[cc] + lnb[cc];
  float pr = r[base] * k2[base] * r_k[cc];
  red[tid] = pr; __syncthreads();
  for (int s = 32; s > 0; s >>= 1) { if (tid < s) red[tid] += red[tid + s]; __syncthreads(); }
  float dot = red[0];
  float val = (on + dot * vp[base]) * bf2f(gbf[base]);
  afin[base] = val;
}

// ---------------- host ----------------
static constexpr size_t KB = 1024;
static constexpr size_t O_R    = 0;
static constexpr size_t O_K    = 16384;
static constexpr size_t O_V    = 32768;
static constexpr size_t O_WDEC = 49152;
static constexpr size_t O_AMAT = 65536;
static constexpr size_t O_VMIX = 81920;
static constexpr size_t O_AIN  = O_AMAT;
static constexpr size_t O_BIN  = O_VMIX;
static constexpr size_t O_AFIN = O_VMIX;
// big hi/lo planes fill dead WDEC/AMAT/VMIX pre-G1:
static constexpr size_t O_WRT_H = 49152, O_WRT_L = 57344;
static constexpr size_t O_WKT_H = 65536, O_WKT_L = 73728;
static constexpr size_t O_WVT_H = 81920, O_WVT_L = 90112;   // ends 98304
// exact-N small planes fill the 2304-KiB tail (98304..100608) exactly:
static constexpr size_t O_W1T_H = 98304, O_W1T_L = 98560;   // 64x2048 bf16 = 256 KiB each
static constexpr size_t O_A1T_H = 98816, O_A1T_L = 99072;
static constexpr size_t O_V1T_H = 99328, O_V1T_L = 99456;   // 32x2048 = 128 KiB each
static constexpr size_t O_G1T_H = 99584, O_G1T_L = 100096;  // 128x2048 = 512 KiB -> 100608
static constexpr size_t O_WOT_H = 0, O_WOT_L = 8192;        // over dead r, after post

extern "C" void kernel_launch(void* const* d_in, const int* in_sizes, int n_in,
                              void* d_out, int out_size, void* d_ws, size_t ws_size,
                              hipStream_t stream) {
  const float* x      = (const float*)d_in[0];
  const float* vfirst = (const float*)d_in[1];
  const float* shift  = (const float*)d_in[2];
  const float* wkv0   = (const float*)d_in[3];
  const float* x_r = (const float*)d_in[4];
  const float* x_w = (const float*)d_in[5];
  const float* x_k = (const float*)d_in[6];
  const float* x_v = (const float*)d_in[7];
  const float* x_a = (const float*)d_in[8];
  const float* x_g = (const float*)d_in[9];
  const float* w0 = (const float*)d_in[10];
  const float* w1 = (const float*)d_in[11];
  const float* w2 = (const float*)d_in[12];
  const float* a0 = (const float*)d_in[13];
  const float* a1 = (const float*)d_in[14];
  const float* a2 = (const float*)d_in[15];
  const float* v0 = (const float*)d_in[16];
  const float* v1 = (const float*)d_in[17];
  const float* v2 = (const float*)d_in[18];
  const float* g1 = (const float*)d_in[19];
  const float* g2 = (const float*)d_in[20];
  const float* k_k = (const float*)d_in[21];
  const float* k_a = (const float*)d_in[22];
  const float* r_k = (const float*)d_in[23];
  const float* W_r = (const float*)d_in[24];
  const float* W_k = (const float*)d_in[25];
  const float* W_v = (const float*)d_in[26];
  const float* W_o = (const float*)d_in[27];
  const float* ln_w = (const float*)d_in[28];
  const float* ln_b = (const float*)d_in[29];

  char* ws = (char*)d_ws;
  auto F = [&](size_t kb) { return (float*)(ws + kb * KB); };
  auto U = [&](size_t kb) { return (unsigned short*)(ws + kb * KB); };
  float* outp = (float*)d_out;
  unsigned short* gbf = (unsigned short*)d_out;                       // 8 MiB
  unsigned short* obf = (unsigned short*)((char*)d_out + 8192 * KB);  // 8 MiB
  // hidden LoRA-down activations live in d_out upper half until scan overwrites:
  float* HW2 = (float*)((char*)d_out + 8192 * KB);                    // 512 KiB
  float* HA2 = (float*)((char*)d_out + 8704 * KB);                    // 512 KiB
  float* HV2 = (float*)((char*)d_out + 9216 * KB);                    // 256 KiB
  float* HG2 = (float*)((char*)d_out + 9472 * KB);                    // 1024 KiB

  // T1: transpose+split ALL seven weights (big padded-free + small exact-N).
  {
    TJobs TG{};
    int cum = 0, i = 0;
    auto addT = [&](const float* src, size_t hkb, size_t lkb, int N) {
      int ntn = (N + 63) / 64;
      cum += 32 * ntn;
      TG.j[i++] = TJob{src, U(hkb), U(lkb), N, ntn, cum};
    };
    addT(W_r, O_WRT_H, O_WRT_L, 2048);
    addT(W_k, O_WKT_H, O_WKT_L, 2048);
    addT(W_v, O_WVT_H, O_WVT_L, 2048);
    addT(w1, O_W1T_H, O_W1T_L, 64);
    addT(a1, O_A1T_H, O_A1T_L, 64);
    addT(v1, O_V1T_H, O_V1T_L, 32);
    addT(g1, O_G1T_H, O_G1T_L, 128);
    wtrans<<<dim3(cum), dim3(256), 0, stream>>>(TG);
  }

  // G1 (split MFMA, T14): r,k,v + 4 LoRA-downs, all with fused token-shift mixes.
  {
    GJobs G{};
    int cum = 0, i = 0;
    auto add = [&](size_t hkb, size_t lkb, float* Cp, const float* mixv, int N) {
      int ntn = (N + 127) / 128;
      cum += 16 * ntn;
      G.j[i++] = GJob{x, U(hkb), U(lkb), Cp, mixv, shift, N, 2048, ntn, 0, 2048, 0, cum};
    };
    add(O_WRT_H, O_WRT_L, F(O_R), x_r, 2048);
    add(O_WKT_H, O_WKT_L, F(O_K), x_k, 2048);
    add(O_WVT_H, O_WVT_L, F(O_V), x_v, 2048);
    add(O_W1T_H, O_W1T_L, HW2, x_w, 64);
    add(O_A1T_H, O_A1T_L, HA2, x_a, 64);
    add(O_V1T_H, O_V1T_L, HV2, x_v, 32);
    add(O_G1T_H, O_G1T_L, HG2, x_g, 128);
    gemm_split<<<dim3(cum), dim3(256), 0, stream>>>(G);
  }

  // G2 (fp32 oracle): LoRA-up with fused activations/epilogues. g stored bf16 (epi 3).
  {
    Jobs G{};
    int cum = 0, i = 0;
    auto add = [&](const float* A, const float* W, float* C, const float* bias,
                   int K, int aact, int epi) {
      cum += 32 * 32;
      G.j[i++] = Job{A, W, C, bias, nullptr, nullptr, nullptr, 2048, K, 32, aact, epi, cum};
    };
    add(HW2, w2, F(O_WDEC), w0, 64, 1, 2);
    add(HA2, a2, F(O_AMAT), a0, 64, 0, 1);
    add(HV2, v2, F(O_VMIX), v0, 32, 0, 1);
    add(HG2, g2, (float*)gbf, nullptr, 128, 2, 3);
    gemm_oracle<<<dim3(cum), dim3(256), 0, stream>>>(G);
  }

  // prescan: kk-norm; k->k2, v->v', amat->a_in, vmix->b_in.
  prescan<<<dim3(65536), dim3(64), 0, stream>>>(F(O_K), F(O_V), F(O_AMAT), F(O_VMIX),
                                                vfirst, k_k, k_a);

  // scan v5: 512 XCD-grouped blocks x 64 threads; o -> bf16 in d_out upper half.
  wkv_scan_v5<<<dim3(512), dim3(64), 0, stream>>>(F(O_R), F(O_K), F(O_WDEC), F(O_AIN),
                                                  F(O_BIN), F(O_V), wkv0, obf);

  // post: GroupNorm + bonus + gate -> afin (bf16 o/g inputs).
  post<<<dim3(65536), dim3(64), 0, stream>>>(obf, F(O_R), F(O_K), F(O_V),
                                             gbf, r_k, ln_w, ln_b, F(O_AFIN));

  // d_out consumed by post -> zero it for G3's split-K atomic accumulation.
  hipMemsetAsync(d_out, 0, (size_t)16384 * KB, stream);

  // T2: W_o transpose+split into dead r region.
  {
    TJobs TO{};
    TO.j[0] = TJob{W_o, U(O_WOT_H), U(O_WOT_L), 2048, 32, 1024};
    wtrans<<<dim3(1024), dim3(256), 0, stream>>>(TO);
  }

  // G3 (split MFMA, split-K 2, atomic): out = afin @ W_o.
  {
    GJobs G{};
    G.j[0] = GJob{F(O_AFIN), U(O_WOT_H), U(O_WOT_L), outp, nullptr, nullptr,
                  2048, 2048, 16, 0, 1024, 1, 256};
    G.j[1] = GJob{F(O_AFIN), U(O_WOT_H), U(O_WOT_L), outp, nullptr, nullptr,
                  2048, 2048, 16, 1024, 2048, 1, 512};
    gemm_split<<<dim3(512), dim3(256), 0, stream>>>(G);
  }

  (void)in_sizes; (void)n_in; (void)out_size; (void)ws_size;
}

// Round 8
// 866.222 us; speedup vs baseline: 1.5708x; 1.0370x over previous
//
#include <hip/hip_runtime.h>
#include <cstdint>
#include <cstddef>

// RWKV-7 Tmix forward, MI355X gfx950 — ROUND 12: 128x256 GEMM tile + gload_lds B.
// r11 profile: G1 272 µs, MfmaUtil 27%, VALUBusy 32% — A-staging VALU (mix +
// hi/lo split) ~matches MFMA time and is repeated per nt-tile. Fix: BN 128->256
// (2x2 waves, 64x128/wave, acc[4][8]): 2x MFMA per staging; B staged via
// global_load_lds into LINEAR LDS [256][32] (zero VALU/regs; m97-proven b128
// pattern); A stays reg-staged (T14) in padded [128][40]. LDS 52 KB,
// launch_bounds(256,2) -> 2 blocks/CU. Scan v5 / prescan / post / G2 unchanged.

#define DI __device__ __forceinline__
static constexpr int T_ = 1024, C_ = 2048, H_ = 32;

typedef __attribute__((ext_vector_type(8))) __bf16 bf16x8;
typedef __attribute__((ext_vector_type(4))) float f32x4;
typedef __attribute__((ext_vector_type(8))) unsigned short us8v;
typedef __attribute__((ext_vector_type(4))) unsigned short us4v;
typedef __attribute__((ext_vector_type(2))) unsigned short us2v;

DI float sig_(float z) { return 1.0f / (1.0f + expf(-z)); }

DI unsigned short f2bf(float f) {           // round-to-nearest-even f32 -> bf16
  union { float f; uint32_t u; } v; v.f = f;
  uint32_t u = v.u;
  return (unsigned short)((u + 0x7FFFu + ((u >> 16) & 1u)) >> 16);
}
DI float bf2f(unsigned short h) {
  union { uint32_t u; float f; } v; v.u = ((uint32_t)h) << 16;
  return v.f;
}

// DPP butterfly adds over 8 k-lanes (kq = lane&7): quad xor1, xor2, half-mirror.
DI float dpp_xor1_add(float x) {
  int r = __builtin_amdgcn_update_dpp(0, __float_as_int(x), 0xB1, 0xF, 0xF, true);
  return x + __int_as_float(r);
}
DI float dpp_xor2_add(float x) {
  int r = __builtin_amdgcn_update_dpp(0, __float_as_int(x), 0x4E, 0xF, 0xF, true);
  return x + __int_as_float(r);
}
DI float dpp_hm_add(float x) {
  int r = __builtin_amdgcn_update_dpp(0, __float_as_int(x), 0x141, 0xF, 0xF, true);
  return x + __int_as_float(r);
}

// async global -> LDS DMA (dest = wave-uniform base + lane*size).
DI void gload16(const float* g, float* l) {
  __builtin_amdgcn_global_load_lds(
      (const __attribute__((address_space(1))) uint32_t*)g,
      (__attribute__((address_space(3))) uint32_t*)l, 16, 0, 0);
}
DI void gload16u(const unsigned short* g, unsigned short* l) {
  __builtin_amdgcn_global_load_lds(
      (const __attribute__((address_space(1))) uint32_t*)g,
      (__attribute__((address_space(3))) uint32_t*)l, 16, 0, 0);
}
DI void gload4(const float* g, float* l) {
  __builtin_amdgcn_global_load_lds(
      (const __attribute__((address_space(1))) uint32_t*)g,
      (__attribute__((address_space(3))) uint32_t*)l, 4, 0, 0);
}

// ---------------- fp32 oracle GEMM (G2: K<=128 LoRA-up jobs) ----------------
// epi: 0 fp32 store; 1 sigmoid(bias+v); 2 e^-0.5*sigmoid(bias+v); 3 bf16 store.
struct Job {
  const float* A; const float* W; float* C; const float* bias;
  const float* mixv; const float* x; const float* shift;
  int N, K, ntn, aact, epi, tile_end;
};
struct Jobs { Job j[7]; };

__global__ __launch_bounds__(256) void gemm_oracle(Jobs P) {
  __shared__ float As[64][33];
  __shared__ float Ws[32][65];
  int bx = blockIdx.x, ji = 0;
  while (bx >= P.j[ji].tile_end) ++ji;
  Job J = P.j[ji];
  int tix = bx - (ji ? P.j[ji - 1].tile_end : 0);
  int mt = tix / J.ntn, nt = tix % J.ntn;
  int m0 = mt * 64, n0 = nt * 64;
  int tid = threadIdx.x, tx = tid & 15, ty = tid >> 4;
  float acc[4][4] = {};
  for (int k0 = 0; k0 < J.K; k0 += 32) {
    #pragma unroll
    for (int p = 0; p < 8; ++p) {
      int idx = p * 256 + tid;
      int r = idx >> 5, kc = idx & 31;
      int m = m0 + r, k = k0 + kc;
      float a;
      if (J.mixv) {
        float xv = J.x[(size_t)m * C_ + k];
        int t = m & (T_ - 1);
        float xp = (t == 0) ? J.shift[(size_t)(m >> 10) * C_ + k]
                            : J.x[(size_t)(m - 1) * C_ + k];
        a = xv + (xp - xv) * J.mixv[k];
      } else {
        a = J.A[(size_t)m * J.K + k];
        if (J.aact == 1) a = tanhf(a);
        else if (J.aact == 2) a = sig_(a);
      }
      As[r][kc] = a;
    }
    #pragma unroll
    for (int p = 0; p < 8; ++p) {
      int idx = p * 256 + tid;
      int kr = idx >> 6, nc = idx & 63;
      int n = n0 + nc;
      Ws[kr][nc] = (n < J.N) ? J.W[(size_t)(k0 + kr) * J.N + n] : 0.0f;
    }
    __syncthreads();
    #pragma unroll 4
    for (int kc = 0; kc < 32; ++kc) {
      float av[4], bv[4];
      #pragma unroll
      for (int i = 0; i < 4; ++i) av[i] = As[ty * 4 + i][kc];
      #pragma unroll
      for (int jn = 0; jn < 4; ++jn) bv[jn] = Ws[kc][tx * 4 + jn];
      #pragma unroll
      for (int i = 0; i < 4; ++i)
        #pragma unroll
        for (int jn = 0; jn < 4; ++jn) acc[i][jn] += av[i] * bv[jn];
    }
    __syncthreads();
  }
  #pragma unroll
  for (int i = 0; i < 4; ++i) {
    int rw = m0 + ty * 4 + i;
    #pragma unroll
    for (int jn = 0; jn < 4; ++jn) {
      int col = n0 + tx * 4 + jn;
      if (col < J.N) {
        float v = acc[i][jn];
        if (J.epi == 1) v = sig_(J.bias[col] + v);
        else if (J.epi == 2) v = 0.60653065971263342f * sig_(J.bias[col] + v);
        if (J.epi == 3) ((unsigned short*)J.C)[(size_t)rw * J.N + col] = f2bf(v);
        else            J.C[(size_t)rw * J.N + col] = v;
      }
    }
  }
}

// -------- weight transpose+split: src fp32 [K=2048][N] -> hi/lo bf16 [N][2048] --------
struct TJob { const float* src; unsigned short* dh; unsigned short* dl; int N, ntn, tile_end; };
struct TJobs { TJob j[8]; };

__global__ __launch_bounds__(256) void wtrans(TJobs P) {
  __shared__ float t[64][65];
  int bx = blockIdx.x, ji = 0;
  while (bx >= P.j[ji].tile_end) ++ji;
  TJob J = P.j[ji];
  int tix = bx - (ji ? P.j[ji - 1].tile_end : 0);
  int kt = tix / J.ntn, nt = tix % J.ntn;
  int k0 = kt * 64, n0 = nt * 64;
  int tid = threadIdx.x;
  #pragma unroll
  for (int p = 0; p < 16; ++p) {
    int flat = p * 256 + tid;
    int r = flat >> 6, c = flat & 63;
    int n = n0 + c;
    t[r][c] = (n < J.N) ? J.src[(size_t)(k0 + r) * J.N + n] : 0.0f;
  }
  __syncthreads();
  #pragma unroll
  for (int p = 0; p < 8; ++p) {
    int flat = p * 256 + tid;
    int rr = flat >> 5, cc = (flat & 31) * 2;
    if (n0 + rr < J.N) {
      float w0v = t[cc][rr], w1v = t[cc + 1][rr];
      unsigned short h0 = f2bf(w0v), h1 = f2bf(w1v);
      us2v oh, ol;
      oh.x = h0; oh.y = h1;
      ol.x = f2bf(w0v - bf2f(h0));
      ol.y = f2bf(w1v - bf2f(h1));
      size_t off = (size_t)(n0 + rr) * 2048 + k0 + cc;
      *(us2v*)(J.dh + off) = oh;
      *(us2v*)(J.dl + off) = ol;
    }
  }
}

// ---------- split-bf16 MFMA GEMM, 128x256 tile: C = A[M,K] @ Wt[N,K]^T ----------
// 4 waves 2x2; per-wave 64x128 out = acc[4][8]. A: reg-staged (mix + hi/lo
// convert) into padded LDS [128][40]; B: global_load_lds direct into linear
// LDS [256][32] (bf16 planes pre-transposed). 2-barrier m97 loop, T14 A-loads.
struct GJob {
  const float* A; const unsigned short* Wh; const unsigned short* Wl; float* C;
  const float* mixv; const float* shift;
  int N, K, ntn, kbeg, kend, atomicC, tile_end;
};
struct GJobs { GJob j[8]; };

__global__ __launch_bounds__(256, 2) void gemm_w256(GJobs P) {
  __shared__ unsigned short Ash[128][40];
  __shared__ unsigned short Asl[128][40];
  __shared__ unsigned short Bsh[256][32];
  __shared__ unsigned short Bsl[256][32];
  int bx = blockIdx.x, ji = 0;
  while (bx >= P.j[ji].tile_end) ++ji;
  GJob J = P.j[ji];
  int tix = bx - (ji ? P.j[ji - 1].tile_end : 0);
  int mt = tix / J.ntn, nt = tix % J.ntn;
  int m0 = mt * 128, n0 = nt * 256;
  int tid = threadIdx.x;
  int lane = tid & 63, wid = tid >> 6;
  int wr = wid >> 1, wc = wid & 1;
  int l15 = lane & 15, lg = lane >> 4;
  f32x4 acc[4][8] = {};

  // A staging geometry: rows p*32 + (tid>>3), k-quad tid&7.
  int sr = tid >> 3, skq = tid & 7;
  float ax[4][4], aq[4][4], amv[4];

  auto loadA = [&](int k0) {
    int kk = k0 + skq * 4;
    if (J.mixv) *(float4*)amv = *(const float4*)(J.mixv + kk);
    #pragma unroll
    for (int p = 0; p < 4; ++p) {
      int m = m0 + p * 32 + sr;
      const float* xp0 = J.A + (size_t)m * J.K + kk;
      *(float4*)ax[p] = *(const float4*)xp0;
      if (J.mixv) {
        const float* pp = ((m & (T_ - 1)) == 0)
            ? (J.shift + (size_t)(m >> 10) * C_ + kk)
            : (xp0 - C_);
        *(float4*)aq[p] = *(const float4*)pp;
      }
    }
  };
  auto writeA = [&]() {
    #pragma unroll
    for (int p = 0; p < 4; ++p) {
      us4v oh, ol;
      #pragma unroll
      for (int q = 0; q < 4; ++q) {
        float va = J.mixv ? (ax[p][q] + (aq[p][q] - ax[p][q]) * amv[q]) : ax[p][q];
        unsigned short hq = f2bf(va);
        oh[q] = hq;
        ol[q] = f2bf(va - bf2f(hq));
      }
      int r = p * 32 + sr;
      *(us4v*)&Ash[r][skq * 4] = oh;
      *(us4v*)&Asl[r][skq * 4] = ol;
    }
  };
  // B staging: wave wid stages rows [wid*64, wid*64+64) per plane, 4 x 1 KB DMAs.
  auto stageB = [&](int k0) {
    #pragma unroll
    for (int j = 0; j < 4; ++j) {
      int r0 = wid * 64 + j * 16;
      int nrow = n0 + r0 + (lane >> 2);
      if (nrow >= J.N) nrow = J.N - 1;          // clamp: values unused (col>=N guarded)
      size_t gofs = (size_t)nrow * J.K + k0 + (lane & 3) * 8;
      gload16u(J.Wh + gofs, &Bsh[r0][0]);
      gload16u(J.Wl + gofs, &Bsl[r0][0]);
    }
  };

  loadA(J.kbeg);
  stageB(J.kbeg);
  writeA();
  asm volatile("s_waitcnt vmcnt(0)" ::: "memory");
  __syncthreads();

  for (int k0 = J.kbeg; k0 < J.kend; k0 += 32) {
    bool more = (k0 + 32 < J.kend);
    if (more) loadA(k0 + 32);                   // T14: A global->reg during MFMA
    bf16x8 afh[4], afl[4];
    #pragma unroll
    for (int i = 0; i < 4; ++i) {
      int rr = wr * 64 + i * 16 + l15;
      afh[i] = __builtin_bit_cast(bf16x8, *(const us8v*)&Ash[rr][lg * 8]);
      afl[i] = __builtin_bit_cast(bf16x8, *(const us8v*)&Asl[rr][lg * 8]);
    }
    #pragma unroll
    for (int jn = 0; jn < 8; ++jn) {
      int rb = wc * 128 + jn * 16 + l15;
      bf16x8 bh = __builtin_bit_cast(bf16x8, *(const us8v*)&Bsh[rb][lg * 8]);
      bf16x8 bl = __builtin_bit_cast(bf16x8, *(const us8v*)&Bsl[rb][lg * 8]);
      #pragma unroll
      for (int i = 0; i < 4; ++i) {
        acc[i][jn] = __builtin_amdgcn_mfma_f32_16x16x32_bf16(afh[i], bh, acc[i][jn], 0, 0, 0);
        acc[i][jn] = __builtin_amdgcn_mfma_f32_16x16x32_bf16(afl[i], bh, acc[i][jn], 0, 0, 0);
        acc[i][jn] = __builtin_amdgcn_mfma_f32_16x16x32_bf16(afh[i], bl, acc[i][jn], 0, 0, 0);
      }
    }
    __syncthreads();                            // all LDS reads done
    if (more) { stageB(k0 + 32); writeA(); }
    asm volatile("s_waitcnt vmcnt(0)" ::: "memory");
    __syncthreads();
  }

  int orow0 = m0 + wr * 64 + 4 * lg;
  int ocol0 = n0 + wc * 128 + l15;
  #pragma unroll
  for (int i = 0; i < 4; ++i) {
    #pragma unroll
    for (int jn = 0; jn < 8; ++jn) {
      int col = ocol0 + jn * 16;
      if (col < J.N) {
        #pragma unroll
        for (int rr = 0; rr < 4; ++rr) {
          size_t idx = (size_t)(orow0 + i * 16 + rr) * J.N + col;
          float v = acc[i][jn][rr];
          if (J.atomicC) atomicAdd(&J.C[idx], v);
          else           J.C[idx] = v;
        }
      }
    }
  }
}

// ---------------- prescan: one block per (b,t,h); LDS tree reduction ----------------
__global__ __launch_bounds__(64) void prescan(
    float* __restrict__ kio, float* __restrict__ vio,
    float* __restrict__ amat_ain, float* __restrict__ vmix_bin,
    const float* __restrict__ vfirst,
    const float* __restrict__ k_k, const float* __restrict__ k_a) {
  __shared__ float red[64];
  int bid = blockIdx.x, tid = threadIdx.x;
  int h = bid & (H_ - 1);
  size_t base = (size_t)bid * 64 + tid;
  int cc = h * 64 + tid;
  float kv = kio[base];
  float kkv = kv * k_k[cc];
  red[tid] = kkv * kkv;
  __syncthreads();
  for (int s = 32; s > 0; s >>= 1) { if (tid < s) red[tid] += red[tid + s]; __syncthreads(); }
  float nrm = fmaxf(sqrtf(red[0]), 1e-12f);
  float kkn = kkv / nrm;
  float av = amat_ain[base];
  float vmv = vmix_bin[base];
  float vv = vio[base];
  kio[base] = kv * (1.0f + (av - 1.0f) * k_a[cc]);
  vio[base] = vv + (vfirst[base] - vv) * vmv;
  amat_ain[base] = -kkn;
  vmix_bin[base] = kkn * av;
}

// ------- wkv scan v5: 512 blocks (8 v-split siblings/chain, same XCD) x 64 thr -------
static constexpr int CH = 16;

#define LOADSTEP(BUF, S_, Aa, Ww, Kk, Bb, Rr, Vt)                  \
  {                                                                \
    *(float4*)&Aa[0] = *(const float4*)&lds[BUF][3][S_][kb];       \
    *(float4*)&Aa[4] = *(const float4*)&lds[BUF][3][S_][kb + 4];   \
    *(float4*)&Ww[0] = *(const float4*)&lds[BUF][2][S_][kb];       \
    *(float4*)&Ww[4] = *(const float4*)&lds[BUF][2][S_][kb + 4];   \
    *(float4*)&Kk[0] = *(const float4*)&lds[BUF][1][S_][kb];       \
    *(float4*)&Kk[4] = *(const float4*)&lds[BUF][1][S_][kb + 4];   \
    *(float4*)&Bb[0] = *(const float4*)&lds[BUF][4][S_][kb];       \
    *(float4*)&Bb[4] = *(const float4*)&lds[BUF][4][S_][kb + 4];   \
    *(float4*)&Rr[0] = *(const float4*)&lds[BUF][0][S_][kb];       \
    *(float4*)&Rr[4] = *(const float4*)&lds[BUF][0][S_][kb + 4];   \
    Vt = vtl[BUF][S_][vl];                                         \
  }

#define COMPSTEP(Aa, Ww, Kk, Bb, Rr, Vt, TIDX)                              \
  {                                                                         \
    float p0 = S[0] * Aa[0], p1 = S[1] * Aa[1];                             \
    float p2 = S[2] * Aa[2], p3 = S[3] * Aa[3];                             \
    p0 = fmaf(S[4], Aa[4], p0); p1 = fmaf(S[5], Aa[5], p1);                 \
    p2 = fmaf(S[6], Aa[6], p2); p3 = fmaf(S[7], Aa[7], p3);                 \
    float sa = (p0 + p1) + (p2 + p3);                                       \
    sa = dpp_xor1_add(sa);                                                  \
    sa = dpp_xor2_add(sa);                                                  \
    sa = dpp_hm_add(sa);                                                    \
    float y0 = 0.f, y1 = 0.f, y2 = 0.f, y3 = 0.f;                           \
    _Pragma("unroll") for (int i = 0; i < 8; i += 4) {                      \
      S[i]     = fmaf(S[i],     Ww[i],     fmaf(Vt, Kk[i],     sa * Bb[i])); \
      S[i + 1] = fmaf(S[i + 1], Ww[i + 1], fmaf(Vt, Kk[i + 1], sa * Bb[i + 1])); \
      S[i + 2] = fmaf(S[i + 2], Ww[i + 2], fmaf(Vt, Kk[i + 2], sa * Bb[i + 2])); \
      S[i + 3] = fmaf(S[i + 3], Ww[i + 3], fmaf(Vt, Kk[i + 3], sa * Bb[i + 3])); \
      y0 = fmaf(S[i], Rr[i], y0);                                           \
      y1 = fmaf(S[i + 1], Rr[i + 1], y1);                                   \
      y2 = fmaf(S[i + 2], Rr[i + 2], y2);                                   \
      y3 = fmaf(S[i + 3], Rr[i + 3], y3);                                   \
    }                                                                       \
    float y = (y0 + y1) + (y2 + y3);                                        \
    y = dpp_xor1_add(y);                                                    \
    y = dpp_xor2_add(y);                                                    \
    y = dpp_hm_add(y);                                                      \
    if (kq == 0) obf[bh + (size_t)(TIDX)*2048 + v0 + vl] = f2bf(y);         \
  }

__global__ __launch_bounds__(64) void wkv_scan_v5(
    const float* __restrict__ r, const float* __restrict__ k2,
    const float* __restrict__ w, const float* __restrict__ ain,
    const float* __restrict__ bin, const float* __restrict__ vp,
    const float* __restrict__ sInit, unsigned short* __restrict__ obf) {
  __shared__ float lds[2][5][CH][64];      // 40 KiB
  __shared__ float vtl[2][CH][8];          // 1 KiB
  int D = blockIdx.x;
  int chain = (D & 7) + 8 * (D >> 6);      // all 8 siblings share D&7 -> same XCD
  int vblk = (D >> 3) & 7;
  int b = chain >> 5, h = chain & 31;
  int v0 = vblk * 8;
  int lane = threadIdx.x;
  int vl = lane >> 3, kq = lane & 7;
  int kb = kq * 8;
  size_t bh = (size_t)(b * T_) * 2048 + (size_t)h * 64;

  float S[8];
  {
    const float* sp = sInit + (((size_t)chain * 64 + v0 + vl) * 64) + kb;
    float4 s0 = *(const float4*)(sp);
    float4 s1 = *(const float4*)(sp + 4);
    S[0] = s0.x; S[1] = s0.y; S[2] = s0.z; S[3] = s0.w;
    S[4] = s1.x; S[5] = s1.y; S[6] = s1.z; S[7] = s1.w;
  }

  const float* arr[5] = {r, k2, w, ain, bin};

  auto stage = [&](int buf, int t0) {
    #pragma unroll
    for (int a = 0; a < 5; ++a) {
      #pragma unroll
      for (int jj = 0; jj < 4; ++jj) {
        size_t gofs = bh + (size_t)(t0 + jj * 4 + (lane >> 4)) * 2048 + (lane & 15) * 4;
        gload16(arr[a] + gofs, &lds[buf][a][jj * 4][0]);
      }
    }
    #pragma unroll
    for (int di = 0; di < 2; ++di) {
      size_t gofs = bh + (size_t)(t0 + di * 8 + (lane >> 3)) * 2048 + v0 + (lane & 7);
      gload4(vp + gofs, &vtl[buf][di * 8][0]);
    }
  };

  stage(0, 0);
  asm volatile("s_waitcnt vmcnt(0)" ::: "memory");

  float A0[8], W0[8], K0[8], B0[8], R0[8], vt0;
  float A1[8], W1[8], K1[8], B1[8], R1[8], vt1;

  for (int c = 0; c < T_ / CH; ++c) {
    int cur = c & 1;
    if (c + 1 < T_ / CH) stage(cur ^ 1, (c + 1) * CH);
    int t0 = c * CH;
    LOADSTEP(cur, 0, A0, W0, K0, B0, R0, vt0);
    #pragma unroll 2
    for (int s = 0; s < CH; s += 2) {
      LOADSTEP(cur, s + 1, A1, W1, K1, B1, R1, vt1);
      COMPSTEP(A0, W0, K0, B0, R0, vt0, t0 + s);
      if (s + 2 < CH) LOADSTEP(cur, s + 2, A0, W0, K0, B0, R0, vt0);
      COMPSTEP(A1, W1, K1, B1, R1, vt1, t0 + s + 1);
    }
    asm volatile("s_waitcnt vmcnt(0)" ::: "memory");
  }
}

// ---------------- post: GroupNorm + bonus + gate; one block per (b,t,h) ----------------
__global__ __launch_bounds__(64) void post(
    const unsigned short* __restrict__ obf, const float* __restrict__ r,
    const float* __restrict__ k2, const float* __restrict__ vp,
    const unsigned short* __restrict__ gbf, const float* __restrict__ r_k,
    const float* __restrict__ lnw, const float* __restrict__ lnb,
    float* __restrict__ afin) {
  __shared__ float red[64];
  int bid = blockIdx.x, tid = threadIdx.x;
  int h = bid & 31;
  size_t base = (size_t)bid * 64 + tid;
  int cc = h * 64 + tid;
  float ov = bf2f(obf[base]);
  red[tid] = ov; __syncthreads();
  for (int s = 32; s > 0; s >>= 1) { if (tid < s) red[tid] += red[tid + s]; __syncthreads(); }
  float mu = red[0] * (1.0f / 64.0f);
  __syncthreads();
  float dv = ov - mu;
  red[tid] = dv * dv; __syncthreads();
  for (int s = 32; s > 0; s >>= 1) { if (tid < s) red[tid] += red[tid + s]; __syncthreads(); }
  float var = red[0] * (1.0f / 64.0f);
  __syncthreads();
  float on = dv * rsqrtf(var + 6.4e-4f) * lnw[cc] + lnb[cc];
  float pr = r[base] * k2[base] * r_k[cc];
  red[tid] = pr; __syncthreads();
  for (int s = 32; s > 0; s >>= 1) { if (tid < s) red[tid] += red[tid + s]; __syncthreads(); }
  float dot = red[0];
  float val = (on + dot * vp[base]) * bf2f(gbf[base]);
  afin[base] = val;
}

// ---------------- host ----------------
static constexpr size_t KB = 1024;
static constexpr size_t O_R    = 0;
static constexpr size_t O_K    = 16384;
static constexpr size_t O_V    = 32768;
static constexpr size_t O_WDEC = 49152;
static constexpr size_t O_AMAT = 65536;
static constexpr size_t O_VMIX = 81920;
static constexpr size_t O_AIN  = O_AMAT;
static constexpr size_t O_BIN  = O_VMIX;
static constexpr size_t O_AFIN = O_VMIX;
static constexpr size_t O_WRT_H = 49152, O_WRT_L = 57344;
static constexpr size_t O_WKT_H = 65536, O_WKT_L = 73728;
static constexpr size_t O_WVT_H = 81920, O_WVT_L = 90112;   // ends 98304
static constexpr size_t O_W1T_H = 98304, O_W1T_L = 98560;
static constexpr size_t O_A1T_H = 98816, O_A1T_L = 99072;
static constexpr size_t O_V1T_H = 99328, O_V1T_L = 99456;
static constexpr size_t O_G1T_H = 99584, O_G1T_L = 100096;  // ends 100608
static constexpr size_t O_WOT_H = 0, O_WOT_L = 8192;

extern "C" void kernel_launch(void* const* d_in, const int* in_sizes, int n_in,
                              void* d_out, int out_size, void* d_ws, size_t ws_size,
                              hipStream_t stream) {
  const float* x      = (const float*)d_in[0];
  const float* vfirst = (const float*)d_in[1];
  const float* shift  = (const float*)d_in[2];
  const float* wkv0   = (const float*)d_in[3];
  const float* x_r = (const float*)d_in[4];
  const float* x_w = (const float*)d_in[5];
  const float* x_k = (const float*)d_in[6];
  const float* x_v = (const float*)d_in[7];
  const float* x_a = (const float*)d_in[8];
  const float* x_g = (const float*)d_in[9];
  const float* w0 = (const float*)d_in[10];
  const float* w1 = (const float*)d_in[11];
  const float* w2 = (const float*)d_in[12];
  const float* a0 = (const float*)d_in[13];
  const float* a1 = (const float*)d_in[14];
  const float* a2 = (const float*)d_in[15];
  const float* v0 = (const float*)d_in[16];
  const float* v1 = (const float*)d_in[17];
  const float* v2 = (const float*)d_in[18];
  const float* g1 = (const float*)d_in[19];
  const float* g2 = (const float*)d_in[20];
  const float* k_k = (const float*)d_in[21];
  const float* k_a = (const float*)d_in[22];
  const float* r_k = (const float*)d_in[23];
  const float* W_r = (const float*)d_in[24];
  const float* W_k = (const float*)d_in[25];
  const float* W_v = (const float*)d_in[26];
  const float* W_o = (const float*)d_in[27];
  const float* ln_w = (const float*)d_in[28];
  const float* ln_b = (const float*)d_in[29];

  char* ws = (char*)d_ws;
  auto F = [&](size_t kb) { return (float*)(ws + kb * KB); };
  auto U = [&](size_t kb) { return (unsigned short*)(ws + kb * KB); };
  float* outp = (float*)d_out;
  unsigned short* gbf = (unsigned short*)d_out;                       // 8 MiB
  unsigned short* obf = (unsigned short*)((char*)d_out + 8192 * KB);  // 8 MiB
  float* HW2 = (float*)((char*)d_out + 8192 * KB);                    // 512 KiB
  float* HA2 = (float*)((char*)d_out + 8704 * KB);                    // 512 KiB
  float* HV2 = (float*)((char*)d_out + 9216 * KB);                    // 256 KiB
  float* HG2 = (float*)((char*)d_out + 9472 * KB);                    // 1024 KiB

  // T1: transpose+split ALL seven weights (big + small exact-N).
  {
    TJobs TG{};
    int cum = 0, i = 0;
    auto addT = [&](const float* src, size_t hkb, size_t lkb, int N) {
      int ntn = (N + 63) / 64;
      cum += 32 * ntn;
      TG.j[i++] = TJob{src, U(hkb), U(lkb), N, ntn, cum};
    };
    addT(W_r, O_WRT_H, O_WRT_L, 2048);
    addT(W_k, O_WKT_H, O_WKT_L, 2048);
    addT(W_v, O_WVT_H, O_WVT_L, 2048);
    addT(w1, O_W1T_H, O_W1T_L, 64);
    addT(a1, O_A1T_H, O_A1T_L, 64);
    addT(v1, O_V1T_H, O_V1T_L, 32);
    addT(g1, O_G1T_H, O_G1T_L, 128);
    wtrans<<<dim3(cum), dim3(256), 0, stream>>>(TG);
  }

  // G1 (split MFMA, 128x256 tile): r,k,v + 4 LoRA-downs with fused mixes.
  {
    GJobs G{};
    int cum = 0, i = 0;
    auto add = [&](size_t hkb, size_t lkb, float* Cp, const float* mixv, int N) {
      int ntn = (N + 255) / 256;
      cum += 16 * ntn;
      G.j[i++] = GJob{x, U(hkb), U(lkb), Cp, mixv, shift, N, 2048, ntn, 0, 2048, 0, cum};
    };
    add(O_WRT_H, O_WRT_L, F(O_R), x_r, 2048);
    add(O_WKT_H, O_WKT_L, F(O_K), x_k, 2048);
    add(O_WVT_H, O_WVT_L, F(O_V), x_v, 2048);
    add(O_W1T_H, O_W1T_L, HW2, x_w, 64);
    add(O_A1T_H, O_A1T_L, HA2, x_a, 64);
    add(O_V1T_H, O_V1T_L, HV2, x_v, 32);
    add(O_G1T_H, O_G1T_L, HG2, x_g, 128);
    gemm_w256<<<dim3(cum), dim3(256), 0, stream>>>(G);
  }

  // G2 (fp32 oracle): LoRA-up with fused activations/epilogues. g stored bf16 (epi 3).
  {
    Jobs G{};
    int cum = 0, i = 0;
    auto add = [&](const float* A, const float* W, float* C, const float* bias,
                   int K, int aact, int epi) {
      cum += 32 * 32;
      G.j[i++] = Job{A, W, C, bias, nullptr, nullptr, nullptr, 2048, K, 32, aact, epi, cum};
    };
    add(HW2, w2, F(O_WDEC), w0, 64, 1, 2);
    add(HA2, a2, F(O_AMAT), a0, 64, 0, 1);
    add(HV2, v2, F(O_VMIX), v0, 32, 0, 1);
    add(HG2, g2, (float*)gbf, nullptr, 128, 2, 3);
    gemm_oracle<<<dim3(cum), dim3(256), 0, stream>>>(G);
  }

  // prescan: kk-norm; k->k2, v->v', amat->a_in, vmix->b_in.
  prescan<<<dim3(65536), dim3(64), 0, stream>>>(F(O_K), F(O_V), F(O_AMAT), F(O_VMIX),
                                                vfirst, k_k, k_a);

  // scan v5: 512 XCD-grouped blocks x 64 threads; o -> bf16 in d_out upper half.
  wkv_scan_v5<<<dim3(512), dim3(64), 0, stream>>>(F(O_R), F(O_K), F(O_WDEC), F(O_AIN),
                                                  F(O_BIN), F(O_V), wkv0, obf);

  // post: GroupNorm + bonus + gate -> afin (bf16 o/g inputs).
  post<<<dim3(65536), dim3(64), 0, stream>>>(obf, F(O_R), F(O_K), F(O_V),
                                             gbf, r_k, ln_w, ln_b, F(O_AFIN));

  // d_out consumed by post -> zero it for G3's split-K atomic accumulation.
  hipMemsetAsync(d_out, 0, (size_t)16384 * KB, stream);

  // T2: W_o transpose+split into dead r region.
  {
    TJobs TO{};
    TO.j[0] = TJob{W_o, U(O_WOT_H), U(O_WOT_L), 2048, 32, 1024};
    wtrans<<<dim3(1024), dim3(256), 0, stream>>>(TO);
  }

  // G3 (split MFMA 128x256, split-K 2, atomic): out = afin @ W_o.
  {
    GJobs G{};
    G.j[0] = GJob{F(O_AFIN), U(O_WOT_H), U(O_WOT_L), outp, nullptr, nullptr,
                  2048, 2048, 8, 0, 1024, 1, 128};
    G.j[1] = GJob{F(O_AFIN), U(O_WOT_H), U(O_WOT_L), outp, nullptr, nullptr,
                  2048, 2048, 8, 1024, 2048, 1, 256};
    gemm_w256<<<dim3(256), dim3(256), 0, stream>>>(G);
  }

  (void)in_sizes; (void)n_in; (void)out_size; (void)ws_size;
}

// Round 9
// 833.438 us; speedup vs baseline: 1.6326x; 1.0393x over previous
//
#include <hip/hip_runtime.h>
#include <cstdint>
#include <cstddef>

// RWKV-7 Tmix forward, MI355X gfx950 — ROUND 13: scan v6 (16-way v-split).
// r12: scan back on top at 242 µs (567 cy/step): ~50 VALU instr + 11 LDS
// reads/step per wave, 1 wave/SIMD (exposed lgkm). Gradient that worked
// r7->r8->r10: cut per-wave work/step + raise CU overlap. v6: 1024 blocks
// (16 v-split siblings/chain, same XCD), 4 v-rows/block, lane=(vl,kq 0..15),
// S[4]/lane; LDS reads 11->6/step, VALU ~50->~28; 16-lane k-reduce = DPP
// xor1/xor2/half_mirror/row_mirror (VALU only); CH=8 dbuf (21 KB LDS).
// GEMMs: w256 split-bf16 MFMA (r12); G2 oracle; post/prescan unchanged.

#define DI __device__ __forceinline__
static constexpr int T_ = 1024, C_ = 2048, H_ = 32;

typedef __attribute__((ext_vector_type(8))) __bf16 bf16x8;
typedef __attribute__((ext_vector_type(4))) float f32x4;
typedef __attribute__((ext_vector_type(8))) unsigned short us8v;
typedef __attribute__((ext_vector_type(4))) unsigned short us4v;
typedef __attribute__((ext_vector_type(2))) unsigned short us2v;

DI float sig_(float z) { return 1.0f / (1.0f + expf(-z)); }

DI unsigned short f2bf(float f) {           // round-to-nearest-even f32 -> bf16
  union { float f; uint32_t u; } v; v.f = f;
  uint32_t u = v.u;
  return (unsigned short)((u + 0x7FFFu + ((u >> 16) & 1u)) >> 16);
}
DI float bf2f(unsigned short h) {
  union { uint32_t u; float f; } v; v.u = ((uint32_t)h) << 16;
  return v.f;
}

// DPP butterfly adds over 16 k-lanes (kq = lane&15): quad xor1, xor2,
// row_half_mirror (within 8), row_mirror (within 16). All VALU.
DI float dpp_xor1_add(float x) {
  int r = __builtin_amdgcn_update_dpp(0, __float_as_int(x), 0xB1, 0xF, 0xF, true);
  return x + __int_as_float(r);
}
DI float dpp_xor2_add(float x) {
  int r = __builtin_amdgcn_update_dpp(0, __float_as_int(x), 0x4E, 0xF, 0xF, true);
  return x + __int_as_float(r);
}
DI float dpp_hm_add(float x) {
  int r = __builtin_amdgcn_update_dpp(0, __float_as_int(x), 0x141, 0xF, 0xF, true);
  return x + __int_as_float(r);
}
DI float dpp_mir_add(float x) {
  int r = __builtin_amdgcn_update_dpp(0, __float_as_int(x), 0x140, 0xF, 0xF, true);
  return x + __int_as_float(r);
}

// async global -> LDS DMA (dest = wave-uniform base + lane*size).
DI void gload16(const float* g, float* l) {
  __builtin_amdgcn_global_load_lds(
      (const __attribute__((address_space(1))) uint32_t*)g,
      (__attribute__((address_space(3))) uint32_t*)l, 16, 0, 0);
}
DI void gload16u(const unsigned short* g, unsigned short* l) {
  __builtin_amdgcn_global_load_lds(
      (const __attribute__((address_space(1))) uint32_t*)g,
      (__attribute__((address_space(3))) uint32_t*)l, 16, 0, 0);
}
DI void gload4(const float* g, float* l) {
  __builtin_amdgcn_global_load_lds(
      (const __attribute__((address_space(1))) uint32_t*)g,
      (__attribute__((address_space(3))) uint32_t*)l, 4, 0, 0);
}

// ---------------- fp32 oracle GEMM (G2: K<=128 LoRA-up jobs) ----------------
// epi: 0 fp32 store; 1 sigmoid(bias+v); 2 e^-0.5*sigmoid(bias+v); 3 bf16 store.
struct Job {
  const float* A; const float* W; float* C; const float* bias;
  const float* mixv; const float* x; const float* shift;
  int N, K, ntn, aact, epi, tile_end;
};
struct Jobs { Job j[7]; };

__global__ __launch_bounds__(256) void gemm_oracle(Jobs P) {
  __shared__ float As[64][33];
  __shared__ float Ws[32][65];
  int bx = blockIdx.x, ji = 0;
  while (bx >= P.j[ji].tile_end) ++ji;
  Job J = P.j[ji];
  int tix = bx - (ji ? P.j[ji - 1].tile_end : 0);
  int mt = tix / J.ntn, nt = tix % J.ntn;
  int m0 = mt * 64, n0 = nt * 64;
  int tid = threadIdx.x, tx = tid & 15, ty = tid >> 4;
  float acc[4][4] = {};
  for (int k0 = 0; k0 < J.K; k0 += 32) {
    #pragma unroll
    for (int p = 0; p < 8; ++p) {
      int idx = p * 256 + tid;
      int r = idx >> 5, kc = idx & 31;
      int m = m0 + r, k = k0 + kc;
      float a;
      if (J.mixv) {
        float xv = J.x[(size_t)m * C_ + k];
        int t = m & (T_ - 1);
        float xp = (t == 0) ? J.shift[(size_t)(m >> 10) * C_ + k]
                            : J.x[(size_t)(m - 1) * C_ + k];
        a = xv + (xp - xv) * J.mixv[k];
      } else {
        a = J.A[(size_t)m * J.K + k];
        if (J.aact == 1) a = tanhf(a);
        else if (J.aact == 2) a = sig_(a);
      }
      As[r][kc] = a;
    }
    #pragma unroll
    for (int p = 0; p < 8; ++p) {
      int idx = p * 256 + tid;
      int kr = idx >> 6, nc = idx & 63;
      int n = n0 + nc;
      Ws[kr][nc] = (n < J.N) ? J.W[(size_t)(k0 + kr) * J.N + n] : 0.0f;
    }
    __syncthreads();
    #pragma unroll 4
    for (int kc = 0; kc < 32; ++kc) {
      float av[4], bv[4];
      #pragma unroll
      for (int i = 0; i < 4; ++i) av[i] = As[ty * 4 + i][kc];
      #pragma unroll
      for (int jn = 0; jn < 4; ++jn) bv[jn] = Ws[kc][tx * 4 + jn];
      #pragma unroll
      for (int i = 0; i < 4; ++i)
        #pragma unroll
        for (int jn = 0; jn < 4; ++jn) acc[i][jn] += av[i] * bv[jn];
    }
    __syncthreads();
  }
  #pragma unroll
  for (int i = 0; i < 4; ++i) {
    int rw = m0 + ty * 4 + i;
    #pragma unroll
    for (int jn = 0; jn < 4; ++jn) {
      int col = n0 + tx * 4 + jn;
      if (col < J.N) {
        float v = acc[i][jn];
        if (J.epi == 1) v = sig_(J.bias[col] + v);
        else if (J.epi == 2) v = 0.60653065971263342f * sig_(J.bias[col] + v);
        if (J.epi == 3) ((unsigned short*)J.C)[(size_t)rw * J.N + col] = f2bf(v);
        else            J.C[(size_t)rw * J.N + col] = v;
      }
    }
  }
}

// -------- weight transpose+split: src fp32 [K=2048][N] -> hi/lo bf16 [N][2048] --------
struct TJob { const float* src; unsigned short* dh; unsigned short* dl; int N, ntn, tile_end; };
struct TJobs { TJob j[8]; };

__global__ __launch_bounds__(256) void wtrans(TJobs P) {
  __shared__ float t[64][65];
  int bx = blockIdx.x, ji = 0;
  while (bx >= P.j[ji].tile_end) ++ji;
  TJob J = P.j[ji];
  int tix = bx - (ji ? P.j[ji - 1].tile_end : 0);
  int kt = tix / J.ntn, nt = tix % J.ntn;
  int k0 = kt * 64, n0 = nt * 64;
  int tid = threadIdx.x;
  #pragma unroll
  for (int p = 0; p < 16; ++p) {
    int flat = p * 256 + tid;
    int r = flat >> 6, c = flat & 63;
    int n = n0 + c;
    t[r][c] = (n < J.N) ? J.src[(size_t)(k0 + r) * J.N + n] : 0.0f;
  }
  __syncthreads();
  #pragma unroll
  for (int p = 0; p < 8; ++p) {
    int flat = p * 256 + tid;
    int rr = flat >> 5, cc = (flat & 31) * 2;
    if (n0 + rr < J.N) {
      float w0v = t[cc][rr], w1v = t[cc + 1][rr];
      unsigned short h0 = f2bf(w0v), h1 = f2bf(w1v);
      us2v oh, ol;
      oh.x = h0; oh.y = h1;
      ol.x = f2bf(w0v - bf2f(h0));
      ol.y = f2bf(w1v - bf2f(h1));
      size_t off = (size_t)(n0 + rr) * 2048 + k0 + cc;
      *(us2v*)(J.dh + off) = oh;
      *(us2v*)(J.dl + off) = ol;
    }
  }
}

// ---------- split-bf16 MFMA GEMM, 128x256 tile: C = A[M,K] @ Wt[N,K]^T ----------
struct GJob {
  const float* A; const unsigned short* Wh; const unsigned short* Wl; float* C;
  const float* mixv; const float* shift;
  int N, K, ntn, kbeg, kend, atomicC, tile_end;
};
struct GJobs { GJob j[8]; };

__global__ __launch_bounds__(256, 2) void gemm_w256(GJobs P) {
  __shared__ unsigned short Ash[128][40];
  __shared__ unsigned short Asl[128][40];
  __shared__ unsigned short Bsh[256][32];
  __shared__ unsigned short Bsl[256][32];
  int bx = blockIdx.x, ji = 0;
  while (bx >= P.j[ji].tile_end) ++ji;
  GJob J = P.j[ji];
  int tix = bx - (ji ? P.j[ji - 1].tile_end : 0);
  int mt = tix / J.ntn, nt = tix % J.ntn;
  int m0 = mt * 128, n0 = nt * 256;
  int tid = threadIdx.x;
  int lane = tid & 63, wid = tid >> 6;
  int wr = wid >> 1, wc = wid & 1;
  int l15 = lane & 15, lg = lane >> 4;
  f32x4 acc[4][8] = {};

  int sr = tid >> 3, skq = tid & 7;
  float ax[4][4], aq[4][4], amv[4];

  auto loadA = [&](int k0) {
    int kk = k0 + skq * 4;
    if (J.mixv) *(float4*)amv = *(const float4*)(J.mixv + kk);
    #pragma unroll
    for (int p = 0; p < 4; ++p) {
      int m = m0 + p * 32 + sr;
      const float* xp0 = J.A + (size_t)m * J.K + kk;
      *(float4*)ax[p] = *(const float4*)xp0;
      if (J.mixv) {
        const float* pp = ((m & (T_ - 1)) == 0)
            ? (J.shift + (size_t)(m >> 10) * C_ + kk)
            : (xp0 - C_);
        *(float4*)aq[p] = *(const float4*)pp;
      }
    }
  };
  auto writeA = [&]() {
    #pragma unroll
    for (int p = 0; p < 4; ++p) {
      us4v oh, ol;
      #pragma unroll
      for (int q = 0; q < 4; ++q) {
        float va = J.mixv ? (ax[p][q] + (aq[p][q] - ax[p][q]) * amv[q]) : ax[p][q];
        unsigned short hq = f2bf(va);
        oh[q] = hq;
        ol[q] = f2bf(va - bf2f(hq));
      }
      int r = p * 32 + sr;
      *(us4v*)&Ash[r][skq * 4] = oh;
      *(us4v*)&Asl[r][skq * 4] = ol;
    }
  };
  auto stageB = [&](int k0) {
    #pragma unroll
    for (int j = 0; j < 4; ++j) {
      int r0 = wid * 64 + j * 16;
      int nrow = n0 + r0 + (lane >> 2);
      if (nrow >= J.N) nrow = J.N - 1;
      size_t gofs = (size_t)nrow * J.K + k0 + (lane & 3) * 8;
      gload16u(J.Wh + gofs, &Bsh[r0][0]);
      gload16u(J.Wl + gofs, &Bsl[r0][0]);
    }
  };

  loadA(J.kbeg);
  stageB(J.kbeg);
  writeA();
  asm volatile("s_waitcnt vmcnt(0)" ::: "memory");
  __syncthreads();

  for (int k0 = J.kbeg; k0 < J.kend; k0 += 32) {
    bool more = (k0 + 32 < J.kend);
    if (more) loadA(k0 + 32);
    bf16x8 afh[4], afl[4];
    #pragma unroll
    for (int i = 0; i < 4; ++i) {
      int rr = wr * 64 + i * 16 + l15;
      afh[i] = __builtin_bit_cast(bf16x8, *(const us8v*)&Ash[rr][lg * 8]);
      afl[i] = __builtin_bit_cast(bf16x8, *(const us8v*)&Asl[rr][lg * 8]);
    }
    #pragma unroll
    for (int jn = 0; jn < 8; ++jn) {
      int rb = wc * 128 + jn * 16 + l15;
      bf16x8 bh = __builtin_bit_cast(bf16x8, *(const us8v*)&Bsh[rb][lg * 8]);
      bf16x8 bl = __builtin_bit_cast(bf16x8, *(const us8v*)&Bsl[rb][lg * 8]);
      #pragma unroll
      for (int i = 0; i < 4; ++i) {
        acc[i][jn] = __builtin_amdgcn_mfma_f32_16x16x32_bf16(afh[i], bh, acc[i][jn], 0, 0, 0);
        acc[i][jn] = __builtin_amdgcn_mfma_f32_16x16x32_bf16(afl[i], bh, acc[i][jn], 0, 0, 0);
        acc[i][jn] = __builtin_amdgcn_mfma_f32_16x16x32_bf16(afh[i], bl, acc[i][jn], 0, 0, 0);
      }
    }
    __syncthreads();
    if (more) { stageB(k0 + 32); writeA(); }
    asm volatile("s_waitcnt vmcnt(0)" ::: "memory");
    __syncthreads();
  }

  int orow0 = m0 + wr * 64 + 4 * lg;
  int ocol0 = n0 + wc * 128 + l15;
  #pragma unroll
  for (int i = 0; i < 4; ++i) {
    #pragma unroll
    for (int jn = 0; jn < 8; ++jn) {
      int col = ocol0 + jn * 16;
      if (col < J.N) {
        #pragma unroll
        for (int rr = 0; rr < 4; ++rr) {
          size_t idx = (size_t)(orow0 + i * 16 + rr) * J.N + col;
          float v = acc[i][jn][rr];
          if (J.atomicC) atomicAdd(&J.C[idx], v);
          else           J.C[idx] = v;
        }
      }
    }
  }
}

// ---------------- prescan: one block per (b,t,h); LDS tree reduction ----------------
__global__ __launch_bounds__(64) void prescan(
    float* __restrict__ kio, float* __restrict__ vio,
    float* __restrict__ amat_ain, float* __restrict__ vmix_bin,
    const float* __restrict__ vfirst,
    const float* __restrict__ k_k, const float* __restrict__ k_a) {
  __shared__ float red[64];
  int bid = blockIdx.x, tid = threadIdx.x;
  int h = bid & (H_ - 1);
  size_t base = (size_t)bid * 64 + tid;
  int cc = h * 64 + tid;
  float kv = kio[base];
  float kkv = kv * k_k[cc];
  red[tid] = kkv * kkv;
  __syncthreads();
  for (int s = 32; s > 0; s >>= 1) { if (tid < s) red[tid] += red[tid + s]; __syncthreads(); }
  float nrm = fmaxf(sqrtf(red[0]), 1e-12f);
  float kkn = kkv / nrm;
  float av = amat_ain[base];
  float vmv = vmix_bin[base];
  float vv = vio[base];
  kio[base] = kv * (1.0f + (av - 1.0f) * k_a[cc]);
  vio[base] = vv + (vfirst[base] - vv) * vmv;
  amat_ain[base] = -kkn;
  vmix_bin[base] = kkn * av;
}

// ------ wkv scan v6: 1024 blocks (16 v-split siblings/chain, same XCD) x 64 thr ------
// Lane: vl = lane>>4 (4 v-rows), kq = lane&15 (16 k-slices of 4); S[4] in VGPRs.
// 16-lane k-reduce: DPP xor1 + xor2 + half_mirror + row_mirror. CH=8 dbuf LDS.
static constexpr int CH = 8;

#define LOADSTEP(BUF, S_, Aa, Ww, Kk, Bb, Rr, Vt)                  \
  {                                                                \
    *(float4*)&Aa[0] = *(const float4*)&lds[BUF][3][S_][kb];       \
    *(float4*)&Ww[0] = *(const float4*)&lds[BUF][2][S_][kb];       \
    *(float4*)&Kk[0] = *(const float4*)&lds[BUF][1][S_][kb];       \
    *(float4*)&Bb[0] = *(const float4*)&lds[BUF][4][S_][kb];       \
    *(float4*)&Rr[0] = *(const float4*)&lds[BUF][0][S_][kb];       \
    Vt = vtl[BUF][S_][vl];                                         \
  }

#define COMPSTEP(Aa, Ww, Kk, Bb, Rr, Vt, TIDX)                              \
  {                                                                         \
    float p0 = S[0] * Aa[0], p1 = S[1] * Aa[1];                             \
    p0 = fmaf(S[2], Aa[2], p0);                                             \
    p1 = fmaf(S[3], Aa[3], p1);                                             \
    float sa = p0 + p1;                                                     \
    sa = dpp_xor1_add(sa);                                                  \
    sa = dpp_xor2_add(sa);                                                  \
    sa = dpp_hm_add(sa);                                                    \
    sa = dpp_mir_add(sa);                                                   \
    S[0] = fmaf(S[0], Ww[0], fmaf(Vt, Kk[0], sa * Bb[0]));                  \
    S[1] = fmaf(S[1], Ww[1], fmaf(Vt, Kk[1], sa * Bb[1]));                  \
    S[2] = fmaf(S[2], Ww[2], fmaf(Vt, Kk[2], sa * Bb[2]));                  \
    S[3] = fmaf(S[3], Ww[3], fmaf(Vt, Kk[3], sa * Bb[3]));                  \
    float y0 = S[0] * Rr[0], y1 = S[1] * Rr[1];                             \
    y0 = fmaf(S[2], Rr[2], y0);                                             \
    y1 = fmaf(S[3], Rr[3], y1);                                             \
    float y = y0 + y1;                                                      \
    y = dpp_xor1_add(y);                                                    \
    y = dpp_xor2_add(y);                                                    \
    y = dpp_hm_add(y);                                                      \
    y = dpp_mir_add(y);                                                     \
    if (kq == 0) obf[bh + (size_t)(TIDX)*2048 + v0 + vl] = f2bf(y);         \
  }

__global__ __launch_bounds__(64) void wkv_scan_v6(
    const float* __restrict__ r, const float* __restrict__ k2,
    const float* __restrict__ w, const float* __restrict__ ain,
    const float* __restrict__ bin, const float* __restrict__ vp,
    const float* __restrict__ sInit, unsigned short* __restrict__ obf) {
  __shared__ float lds[2][5][CH][64];      // 20 KiB
  __shared__ float vtl[2][16][4];          // 512 B (rows 8..15 = clamp spill)
  int D = blockIdx.x;
  int chain = (D & 7) + 8 * (D >> 7);      // all 16 siblings share D&7 -> same XCD
  int vblk = (D >> 3) & 15;
  int b = chain >> 5, h = chain & 31;
  int v0 = vblk * 4;
  int lane = threadIdx.x;
  int vl = lane >> 4, kq = lane & 15;
  int kb = kq * 4;
  size_t bh = (size_t)(b * T_) * 2048 + (size_t)h * 64;

  float S[4];
  {
    const float* sp = sInit + (((size_t)chain * 64 + v0 + vl) * 64) + kb;
    float4 s0 = *(const float4*)sp;
    S[0] = s0.x; S[1] = s0.y; S[2] = s0.z; S[3] = s0.w;
  }

  const float* arr[5] = {r, k2, w, ain, bin};

  auto stage = [&](int buf, int t0) {
    #pragma unroll
    for (int a = 0; a < 5; ++a) {
      #pragma unroll
      for (int jj = 0; jj < 2; ++jj) {     // CH=8 steps x 64 floats = 2 DMAs/array
        size_t gofs = bh + (size_t)(t0 + jj * 4 + (lane >> 4)) * 2048 + (lane & 15) * 4;
        gload16(arr[a] + gofs, &lds[buf][a][jj * 4][0]);
      }
    }
    {                                      // vt: 8 steps x 4 v (lanes 32-63 clamp)
      int tt = t0 + (lane >> 2);
      if (tt > T_ - 1) tt = T_ - 1;
      size_t gofs = bh + (size_t)tt * 2048 + v0 + (lane & 3);
      gload4(vp + gofs, &vtl[buf][0][0]);
    }
  };

  stage(0, 0);
  asm volatile("s_waitcnt vmcnt(0)" ::: "memory");

  float A0[4], W0[4], K0[4], B0[4], R0[4], vt0;
  float A1[4], W1[4], K1[4], B1[4], R1[4], vt1;

  for (int c = 0; c < T_ / CH; ++c) {
    int cur = c & 1;
    if (c + 1 < T_ / CH) stage(cur ^ 1, (c + 1) * CH);
    int t0 = c * CH;
    LOADSTEP(cur, 0, A0, W0, K0, B0, R0, vt0);
    #pragma unroll 2
    for (int s = 0; s < CH; s += 2) {
      LOADSTEP(cur, s + 1, A1, W1, K1, B1, R1, vt1);
      COMPSTEP(A0, W0, K0, B0, R0, vt0, t0 + s);
      if (s + 2 < CH) LOADSTEP(cur, s + 2, A0, W0, K0, B0, R0, vt0);
      COMPSTEP(A1, W1, K1, B1, R1, vt1, t0 + s + 1);
    }
    asm volatile("s_waitcnt vmcnt(0)" ::: "memory");
  }
}

// ---------------- post: GroupNorm + bonus + gate; one block per (b,t,h) ----------------
__global__ __launch_bounds__(64) void post(
    const unsigned short* __restrict__ obf, const float* __restrict__ r,
    const float* __restrict__ k2, const float* __restrict__ vp,
    const unsigned short* __restrict__ gbf, const float* __restrict__ r_k,
    const float* __restrict__ lnw, const float* __restrict__ lnb,
    float* __restrict__ afin) {
  __shared__ float red[64];
  int bid = blockIdx.x, tid = threadIdx.x;
  int h = bid & 31;
  size_t base = (size_t)bid * 64 + tid;
  int cc = h * 64 + tid;
  float ov = bf2f(obf[base]);
  red[tid] = ov; __syncthreads();
  for (int s = 32; s > 0; s >>= 1) { if (tid < s) red[tid] += red[tid + s]; __syncthreads(); }
  float mu = red[0] * (1.0f / 64.0f);
  __syncthreads();
  float dv = ov - mu;
  red[tid] = dv * dv; __syncthreads();
  for (int s = 32; s > 0; s >>= 1) { if (tid < s) red[tid] += red[tid + s]; __syncthreads(); }
  float var = red[0] * (1.0f / 64.0f);
  __syncthreads();
  float on = dv * rsqrtf(var + 6.4e-4f) * lnw[cc] + lnb[cc];
  float pr = r[base] * k2[base] * r_k[cc];
  red[tid] = pr; __syncthreads();
  for (int s = 32; s > 0; s >>= 1) { if (tid < s) red[tid] += red[tid + s]; __syncthreads(); }
  float dot = red[0];
  float val = (on + dot * vp[base]) * bf2f(gbf[base]);
  afin[base] = val;
}

// ---------------- host ----------------
static constexpr size_t KB = 1024;
static constexpr size_t O_R    = 0;
static constexpr size_t O_K    = 16384;
static constexpr size_t O_V    = 32768;
static constexpr size_t O_WDEC = 49152;
static constexpr size_t O_AMAT = 65536;
static constexpr size_t O_VMIX = 81920;
static constexpr size_t O_AIN  = O_AMAT;
static constexpr size_t O_BIN  = O_VMIX;
static constexpr size_t O_AFIN = O_VMIX;
static constexpr size_t O_WRT_H = 49152, O_WRT_L = 57344;
static constexpr size_t O_WKT_H = 65536, O_WKT_L = 73728;
static constexpr size_t O_WVT_H = 81920, O_WVT_L = 90112;   // ends 98304
static constexpr size_t O_W1T_H = 98304, O_W1T_L = 98560;
static constexpr size_t O_A1T_H = 98816, O_A1T_L = 99072;
static constexpr size_t O_V1T_H = 99328, O_V1T_L = 99456;
static constexpr size_t O_G1T_H = 99584, O_G1T_L = 100096;  // ends 100608
static constexpr size_t O_WOT_H = 0, O_WOT_L = 8192;

extern "C" void kernel_launch(void* const* d_in, const int* in_sizes, int n_in,
                              void* d_out, int out_size, void* d_ws, size_t ws_size,
                              hipStream_t stream) {
  const float* x      = (const float*)d_in[0];
  const float* vfirst = (const float*)d_in[1];
  const float* shift  = (const float*)d_in[2];
  const float* wkv0   = (const float*)d_in[3];
  const float* x_r = (const float*)d_in[4];
  const float* x_w = (const float*)d_in[5];
  const float* x_k = (const float*)d_in[6];
  const float* x_v = (const float*)d_in[7];
  const float* x_a = (const float*)d_in[8];
  const float* x_g = (const float*)d_in[9];
  const float* w0 = (const float*)d_in[10];
  const float* w1 = (const float*)d_in[11];
  const float* w2 = (const float*)d_in[12];
  const float* a0 = (const float*)d_in[13];
  const float* a1 = (const float*)d_in[14];
  const float* a2 = (const float*)d_in[15];
  const float* v0 = (const float*)d_in[16];
  const float* v1 = (const float*)d_in[17];
  const float* v2 = (const float*)d_in[18];
  const float* g1 = (const float*)d_in[19];
  const float* g2 = (const float*)d_in[20];
  const float* k_k = (const float*)d_in[21];
  const float* k_a = (const float*)d_in[22];
  const float* r_k = (const float*)d_in[23];
  const float* W_r = (const float*)d_in[24];
  const float* W_k = (const float*)d_in[25];
  const float* W_v = (const float*)d_in[26];
  const float* W_o = (const float*)d_in[27];
  const float* ln_w = (const float*)d_in[28];
  const float* ln_b = (const float*)d_in[29];

  char* ws = (char*)d_ws;
  auto F = [&](size_t kb) { return (float*)(ws + kb * KB); };
  auto U = [&](size_t kb) { return (unsigned short*)(ws + kb * KB); };
  float* outp = (float*)d_out;
  unsigned short* gbf = (unsigned short*)d_out;                       // 8 MiB
  unsigned short* obf = (unsigned short*)((char*)d_out + 8192 * KB);  // 8 MiB
  float* HW2 = (float*)((char*)d_out + 8192 * KB);                    // 512 KiB
  float* HA2 = (float*)((char*)d_out + 8704 * KB);                    // 512 KiB
  float* HV2 = (float*)((char*)d_out + 9216 * KB);                    // 256 KiB
  float* HG2 = (float*)((char*)d_out + 9472 * KB);                    // 1024 KiB

  // T1: transpose+split ALL seven weights (big + small exact-N).
  {
    TJobs TG{};
    int cum = 0, i = 0;
    auto addT = [&](const float* src, size_t hkb, size_t lkb, int N) {
      int ntn = (N + 63) / 64;
      cum += 32 * ntn;
      TG.j[i++] = TJob{src, U(hkb), U(lkb), N, ntn, cum};
    };
    addT(W_r, O_WRT_H, O_WRT_L, 2048);
    addT(W_k, O_WKT_H, O_WKT_L, 2048);
    addT(W_v, O_WVT_H, O_WVT_L, 2048);
    addT(w1, O_W1T_H, O_W1T_L, 64);
    addT(a1, O_A1T_H, O_A1T_L, 64);
    addT(v1, O_V1T_H, O_V1T_L, 32);
    addT(g1, O_G1T_H, O_G1T_L, 128);
    wtrans<<<dim3(cum), dim3(256), 0, stream>>>(TG);
  }

  // G1 (split MFMA, 128x256 tile): r,k,v + 4 LoRA-downs with fused mixes.
  {
    GJobs G{};
    int cum = 0, i = 0;
    auto add = [&](size_t hkb, size_t lkb, float* Cp, const float* mixv, int N) {
      int ntn = (N + 255) / 256;
      cum += 16 * ntn;
      G.j[i++] = GJob{x, U(hkb), U(lkb), Cp, mixv, shift, N, 2048, ntn, 0, 2048, 0, cum};
    };
    add(O_WRT_H, O_WRT_L, F(O_R), x_r, 2048);
    add(O_WKT_H, O_WKT_L, F(O_K), x_k, 2048);
    add(O_WVT_H, O_WVT_L, F(O_V), x_v, 2048);
    add(O_W1T_H, O_W1T_L, HW2, x_w, 64);
    add(O_A1T_H, O_A1T_L, HA2, x_a, 64);
    add(O_V1T_H, O_V1T_L, HV2, x_v, 32);
    add(O_G1T_H, O_G1T_L, HG2, x_g, 128);
    gemm_w256<<<dim3(cum), dim3(256), 0, stream>>>(G);
  }

  // G2 (fp32 oracle): LoRA-up with fused activations/epilogues. g stored bf16 (epi 3).
  {
    Jobs G{};
    int cum = 0, i = 0;
    auto add = [&](const float* A, const float* W, float* C, const float* bias,
                   int K, int aact, int epi) {
      cum += 32 * 32;
      G.j[i++] = Job{A, W, C, bias, nullptr, nullptr, nullptr, 2048, K, 32, aact, epi, cum};
    };
    add(HW2, w2, F(O_WDEC), w0, 64, 1, 2);
    add(HA2, a2, F(O_AMAT), a0, 64, 0, 1);
    add(HV2, v2, F(O_VMIX), v0, 32, 0, 1);
    add(HG2, g2, (float*)gbf, nullptr, 128, 2, 3);
    gemm_oracle<<<dim3(cum), dim3(256), 0, stream>>>(G);
  }

  // prescan: kk-norm; k->k2, v->v', amat->a_in, vmix->b_in.
  prescan<<<dim3(65536), dim3(64), 0, stream>>>(F(O_K), F(O_V), F(O_AMAT), F(O_VMIX),
                                                vfirst, k_k, k_a);

  // scan v6: 1024 XCD-grouped blocks x 64 threads; o -> bf16 in d_out upper half.
  wkv_scan_v6<<<dim3(1024), dim3(64), 0, stream>>>(F(O_R), F(O_K), F(O_WDEC), F(O_AIN),
                                                   F(O_BIN), F(O_V), wkv0, obf);

  // post: GroupNorm + bonus + gate -> afin (bf16 o/g inputs).
  post<<<dim3(65536), dim3(64), 0, stream>>>(obf, F(O_R), F(O_K), F(O_V),
                                             gbf, r_k, ln_w, ln_b, F(O_AFIN));

  // d_out consumed by post -> zero it for G3's split-K atomic accumulation.
  hipMemsetAsync(d_out, 0, (size_t)16384 * KB, stream);

  // T2: W_o transpose+split into dead r region.
  {
    TJobs TO{};
    TO.j[0] = TJob{W_o, U(O_WOT_H), U(O_WOT_L), 2048, 32, 1024};
    wtrans<<<dim3(1024), dim3(256), 0, stream>>>(TO);
  }

  // G3 (split MFMA 128x256, split-K 2, atomic): out = afin @ W_o.
  {
    GJobs G{};
    G.j[0] = GJob{F(O_AFIN), U(O_WOT_H), U(O_WOT_L), outp, nullptr, nullptr,
                  2048, 2048, 8, 0, 1024, 1, 128};
    G.j[1] = GJob{F(O_AFIN), U(O_WOT_H), U(O_WOT_L), outp, nullptr, nullptr,
                  2048, 2048, 8, 1024, 2048, 1, 256};
    gemm_w256<<<dim3(256), dim3(256), 0, stream>>>(G);
  }

  (void)in_sizes; (void)n_in; (void)out_size; (void)ws_size;
}

// Round 10
// 830.347 us; speedup vs baseline: 1.6387x; 1.0037x over previous
//
#include <hip/hip_runtime.h>
#include <cstdint>
#include <cstddef>

// RWKV-7 Tmix forward, MI355X gfx950 — ROUND 14: B-LDS XOR swizzle (T2/G21).
// r13 profile: gemm_w256 G1 233 µs, Mfma 33.5%, BANK_CONFLICT 1.47e7 = exactly
// 8 per B-frag read: linear [256][32] B tile has 64B row stride -> bank =
// (row&1)*16 + slot*4 -> 16 lanes over 2 bank quads = 8-way conflict, 565 cy
// of B reads vs 466 cy MFMA per k-step. Fix per G21: LDS dest stays linear
// (global_load_lds), global SOURCE slot pre-swizzled ssrc = s ^ ((row>>1)&3),
// read applies same XOR -> 2 lanes/bank (free). Pure layout, no numeric change.
// Everything else (scan v6, G2 oracle, prescan/post, split-K G3) unchanged.

#define DI __device__ __forceinline__
static constexpr int T_ = 1024, C_ = 2048, H_ = 32;

typedef __attribute__((ext_vector_type(8))) __bf16 bf16x8;
typedef __attribute__((ext_vector_type(4))) float f32x4;
typedef __attribute__((ext_vector_type(8))) unsigned short us8v;
typedef __attribute__((ext_vector_type(4))) unsigned short us4v;
typedef __attribute__((ext_vector_type(2))) unsigned short us2v;

DI float sig_(float z) { return 1.0f / (1.0f + expf(-z)); }

DI unsigned short f2bf(float f) {           // round-to-nearest-even f32 -> bf16
  union { float f; uint32_t u; } v; v.f = f;
  uint32_t u = v.u;
  return (unsigned short)((u + 0x7FFFu + ((u >> 16) & 1u)) >> 16);
}
DI float bf2f(unsigned short h) {
  union { uint32_t u; float f; } v; v.u = ((uint32_t)h) << 16;
  return v.f;
}

// DPP butterfly adds over 16 k-lanes (kq = lane&15): quad xor1, xor2,
// row_half_mirror (within 8), row_mirror (within 16). All VALU.
DI float dpp_xor1_add(float x) {
  int r = __builtin_amdgcn_update_dpp(0, __float_as_int(x), 0xB1, 0xF, 0xF, true);
  return x + __int_as_float(r);
}
DI float dpp_xor2_add(float x) {
  int r = __builtin_amdgcn_update_dpp(0, __float_as_int(x), 0x4E, 0xF, 0xF, true);
  return x + __int_as_float(r);
}
DI float dpp_hm_add(float x) {
  int r = __builtin_amdgcn_update_dpp(0, __float_as_int(x), 0x141, 0xF, 0xF, true);
  return x + __int_as_float(r);
}
DI float dpp_mir_add(float x) {
  int r = __builtin_amdgcn_update_dpp(0, __float_as_int(x), 0x140, 0xF, 0xF, true);
  return x + __int_as_float(r);
}

// async global -> LDS DMA (dest = wave-uniform base + lane*size).
DI void gload16(const float* g, float* l) {
  __builtin_amdgcn_global_load_lds(
      (const __attribute__((address_space(1))) uint32_t*)g,
      (__attribute__((address_space(3))) uint32_t*)l, 16, 0, 0);
}
DI void gload16u(const unsigned short* g, unsigned short* l) {
  __builtin_amdgcn_global_load_lds(
      (const __attribute__((address_space(1))) uint32_t*)g,
      (__attribute__((address_space(3))) uint32_t*)l, 16, 0, 0);
}
DI void gload4(const float* g, float* l) {
  __builtin_amdgcn_global_load_lds(
      (const __attribute__((address_space(1))) uint32_t*)g,
      (__attribute__((address_space(3))) uint32_t*)l, 4, 0, 0);
}

// ---------------- fp32 oracle GEMM (G2: K<=128 LoRA-up jobs) ----------------
// epi: 0 fp32 store; 1 sigmoid(bias+v); 2 e^-0.5*sigmoid(bias+v); 3 bf16 store.
struct Job {
  const float* A; const float* W; float* C; const float* bias;
  const float* mixv; const float* x; const float* shift;
  int N, K, ntn, aact, epi, tile_end;
};
struct Jobs { Job j[7]; };

__global__ __launch_bounds__(256) void gemm_oracle(Jobs P) {
  __shared__ float As[64][33];
  __shared__ float Ws[32][65];
  int bx = blockIdx.x, ji = 0;
  while (bx >= P.j[ji].tile_end) ++ji;
  Job J = P.j[ji];
  int tix = bx - (ji ? P.j[ji - 1].tile_end : 0);
  int mt = tix / J.ntn, nt = tix % J.ntn;
  int m0 = mt * 64, n0 = nt * 64;
  int tid = threadIdx.x, tx = tid & 15, ty = tid >> 4;
  float acc[4][4] = {};
  for (int k0 = 0; k0 < J.K; k0 += 32) {
    #pragma unroll
    for (int p = 0; p < 8; ++p) {
      int idx = p * 256 + tid;
      int r = idx >> 5, kc = idx & 31;
      int m = m0 + r, k = k0 + kc;
      float a;
      if (J.mixv) {
        float xv = J.x[(size_t)m * C_ + k];
        int t = m & (T_ - 1);
        float xp = (t == 0) ? J.shift[(size_t)(m >> 10) * C_ + k]
                            : J.x[(size_t)(m - 1) * C_ + k];
        a = xv + (xp - xv) * J.mixv[k];
      } else {
        a = J.A[(size_t)m * J.K + k];
        if (J.aact == 1) a = tanhf(a);
        else if (J.aact == 2) a = sig_(a);
      }
      As[r][kc] = a;
    }
    #pragma unroll
    for (int p = 0; p < 8; ++p) {
      int idx = p * 256 + tid;
      int kr = idx >> 6, nc = idx & 63;
      int n = n0 + nc;
      Ws[kr][nc] = (n < J.N) ? J.W[(size_t)(k0 + kr) * J.N + n] : 0.0f;
    }
    __syncthreads();
    #pragma unroll 4
    for (int kc = 0; kc < 32; ++kc) {
      float av[4], bv[4];
      #pragma unroll
      for (int i = 0; i < 4; ++i) av[i] = As[ty * 4 + i][kc];
      #pragma unroll
      for (int jn = 0; jn < 4; ++jn) bv[jn] = Ws[kc][tx * 4 + jn];
      #pragma unroll
      for (int i = 0; i < 4; ++i)
        #pragma unroll
        for (int jn = 0; jn < 4; ++jn) acc[i][jn] += av[i] * bv[jn];
    }
    __syncthreads();
  }
  #pragma unroll
  for (int i = 0; i < 4; ++i) {
    int rw = m0 + ty * 4 + i;
    #pragma unroll
    for (int jn = 0; jn < 4; ++jn) {
      int col = n0 + tx * 4 + jn;
      if (col < J.N) {
        float v = acc[i][jn];
        if (J.epi == 1) v = sig_(J.bias[col] + v);
        else if (J.epi == 2) v = 0.60653065971263342f * sig_(J.bias[col] + v);
        if (J.epi == 3) ((unsigned short*)J.C)[(size_t)rw * J.N + col] = f2bf(v);
        else            J.C[(size_t)rw * J.N + col] = v;
      }
    }
  }
}

// -------- weight transpose+split: src fp32 [K=2048][N] -> hi/lo bf16 [N][2048] --------
struct TJob { const float* src; unsigned short* dh; unsigned short* dl; int N, ntn, tile_end; };
struct TJobs { TJob j[8]; };

__global__ __launch_bounds__(256) void wtrans(TJobs P) {
  __shared__ float t[64][65];
  int bx = blockIdx.x, ji = 0;
  while (bx >= P.j[ji].tile_end) ++ji;
  TJob J = P.j[ji];
  int tix = bx - (ji ? P.j[ji - 1].tile_end : 0);
  int kt = tix / J.ntn, nt = tix % J.ntn;
  int k0 = kt * 64, n0 = nt * 64;
  int tid = threadIdx.x;
  #pragma unroll
  for (int p = 0; p < 16; ++p) {
    int flat = p * 256 + tid;
    int r = flat >> 6, c = flat & 63;
    int n = n0 + c;
    t[r][c] = (n < J.N) ? J.src[(size_t)(k0 + r) * J.N + n] : 0.0f;
  }
  __syncthreads();
  #pragma unroll
  for (int p = 0; p < 8; ++p) {
    int flat = p * 256 + tid;
    int rr = flat >> 5, cc = (flat & 31) * 2;
    if (n0 + rr < J.N) {
      float w0v = t[cc][rr], w1v = t[cc + 1][rr];
      unsigned short h0 = f2bf(w0v), h1 = f2bf(w1v);
      us2v oh, ol;
      oh.x = h0; oh.y = h1;
      ol.x = f2bf(w0v - bf2f(h0));
      ol.y = f2bf(w1v - bf2f(h1));
      size_t off = (size_t)(n0 + rr) * 2048 + k0 + cc;
      *(us2v*)(J.dh + off) = oh;
      *(us2v*)(J.dl + off) = ol;
    }
  }
}

// ---------- split-bf16 MFMA GEMM, 128x256 tile: C = A[M,K] @ Wt[N,K]^T ----------
// B LDS is linear [256][32] staged by global_load_lds with SOURCE-slot XOR
// swizzle ssrc = s ^ ((row>>1)&3); fragment reads use the same XOR -> banks
// spread to the free 2-lanes/bank minimum (was 8-way, 1.47e7 conflicts).
struct GJob {
  const float* A; const unsigned short* Wh; const unsigned short* Wl; float* C;
  const float* mixv; const float* shift;
  int N, K, ntn, kbeg, kend, atomicC, tile_end;
};
struct GJobs { GJob j[8]; };

__global__ __launch_bounds__(256, 2) void gemm_w256(GJobs P) {
  __shared__ unsigned short Ash[128][40];
  __shared__ unsigned short Asl[128][40];
  __shared__ unsigned short Bsh[256][32];
  __shared__ unsigned short Bsl[256][32];
  int bx = blockIdx.x, ji = 0;
  while (bx >= P.j[ji].tile_end) ++ji;
  GJob J = P.j[ji];
  int tix = bx - (ji ? P.j[ji - 1].tile_end : 0);
  int mt = tix / J.ntn, nt = tix % J.ntn;
  int m0 = mt * 128, n0 = nt * 256;
  int tid = threadIdx.x;
  int lane = tid & 63, wid = tid >> 6;
  int wr = wid >> 1, wc = wid & 1;
  int l15 = lane & 15, lg = lane >> 4;
  f32x4 acc[4][8] = {};

  int sr = tid >> 3, skq = tid & 7;
  float ax[4][4], aq[4][4], amv[4];

  auto loadA = [&](int k0) {
    int kk = k0 + skq * 4;
    if (J.mixv) *(float4*)amv = *(const float4*)(J.mixv + kk);
    #pragma unroll
    for (int p = 0; p < 4; ++p) {
      int m = m0 + p * 32 + sr;
      const float* xp0 = J.A + (size_t)m * J.K + kk;
      *(float4*)ax[p] = *(const float4*)xp0;
      if (J.mixv) {
        const float* pp = ((m & (T_ - 1)) == 0)
            ? (J.shift + (size_t)(m >> 10) * C_ + kk)
            : (xp0 - C_);
        *(float4*)aq[p] = *(const float4*)pp;
      }
    }
  };
  auto writeA = [&]() {
    #pragma unroll
    for (int p = 0; p < 4; ++p) {
      us4v oh, ol;
      #pragma unroll
      for (int q = 0; q < 4; ++q) {
        float va = J.mixv ? (ax[p][q] + (aq[p][q] - ax[p][q]) * amv[q]) : ax[p][q];
        unsigned short hq = f2bf(va);
        oh[q] = hq;
        ol[q] = f2bf(va - bf2f(hq));
      }
      int r = p * 32 + sr;
      *(us4v*)&Ash[r][skq * 4] = oh;
      *(us4v*)&Asl[r][skq * 4] = ol;
    }
  };
  // B staging: linear LDS dest; global source slot pre-swizzled (G21).
  auto stageB = [&](int k0) {
    #pragma unroll
    for (int j = 0; j < 4; ++j) {
      int r0 = wid * 64 + j * 16;
      int rdst = r0 + (lane >> 2);              // LDS row this lane fills
      int nrow = n0 + rdst;
      if (nrow >= J.N) nrow = J.N - 1;          // clamp: values unused (col>=N guarded)
      int ssrc = (lane & 3) ^ ((rdst >> 1) & 3);  // inverse(=same) XOR of read side
      size_t gofs = (size_t)nrow * J.K + k0 + ssrc * 8;
      gload16u(J.Wh + gofs, &Bsh[r0][0]);
      gload16u(J.Wl + gofs, &Bsl[r0][0]);
    }
  };

  loadA(J.kbeg);
  stageB(J.kbeg);
  writeA();
  asm volatile("s_waitcnt vmcnt(0)" ::: "memory");
  __syncthreads();

  for (int k0 = J.kbeg; k0 < J.kend; k0 += 32) {
    bool more = (k0 + 32 < J.kend);
    if (more) loadA(k0 + 32);
    bf16x8 afh[4], afl[4];
    #pragma unroll
    for (int i = 0; i < 4; ++i) {
      int rr = wr * 64 + i * 16 + l15;
      afh[i] = __builtin_bit_cast(bf16x8, *(const us8v*)&Ash[rr][lg * 8]);
      afl[i] = __builtin_bit_cast(bf16x8, *(const us8v*)&Asl[rr][lg * 8]);
    }
    #pragma unroll
    for (int jn = 0; jn < 8; ++jn) {
      int rb = wc * 128 + jn * 16 + l15;
      int sl = (lg ^ ((rb >> 1) & 3)) * 8;      // swizzled slot (matches source XOR)
      bf16x8 bh = __builtin_bit_cast(bf16x8, *(const us8v*)&Bsh[rb][sl]);
      bf16x8 bl = __builtin_bit_cast(bf16x8, *(const us8v*)&Bsl[rb][sl]);
      #pragma unroll
      for (int i = 0; i < 4; ++i) {
        acc[i][jn] = __builtin_amdgcn_mfma_f32_16x16x32_bf16(afh[i], bh, acc[i][jn], 0, 0, 0);
        acc[i][jn] = __builtin_amdgcn_mfma_f32_16x16x32_bf16(afl[i], bh, acc[i][jn], 0, 0, 0);
        acc[i][jn] = __builtin_amdgcn_mfma_f32_16x16x32_bf16(afh[i], bl, acc[i][jn], 0, 0, 0);
      }
    }
    __syncthreads();
    if (more) { stageB(k0 + 32); writeA(); }
    asm volatile("s_waitcnt vmcnt(0)" ::: "memory");
    __syncthreads();
  }

  int orow0 = m0 + wr * 64 + 4 * lg;
  int ocol0 = n0 + wc * 128 + l15;
  #pragma unroll
  for (int i = 0; i < 4; ++i) {
    #pragma unroll
    for (int jn = 0; jn < 8; ++jn) {
      int col = ocol0 + jn * 16;
      if (col < J.N) {
        #pragma unroll
        for (int rr = 0; rr < 4; ++rr) {
          size_t idx = (size_t)(orow0 + i * 16 + rr) * J.N + col;
          float v = acc[i][jn][rr];
          if (J.atomicC) atomicAdd(&J.C[idx], v);
          else           J.C[idx] = v;
        }
      }
    }
  }
}

// ---------------- prescan: one block per (b,t,h); LDS tree reduction ----------------
__global__ __launch_bounds__(64) void prescan(
    float* __restrict__ kio, float* __restrict__ vio,
    float* __restrict__ amat_ain, float* __restrict__ vmix_bin,
    const float* __restrict__ vfirst,
    const float* __restrict__ k_k, const float* __restrict__ k_a) {
  __shared__ float red[64];
  int bid = blockIdx.x, tid = threadIdx.x;
  int h = bid & (H_ - 1);
  size_t base = (size_t)bid * 64 + tid;
  int cc = h * 64 + tid;
  float kv = kio[base];
  float kkv = kv * k_k[cc];
  red[tid] = kkv * kkv;
  __syncthreads();
  for (int s = 32; s > 0; s >>= 1) { if (tid < s) red[tid] += red[tid + s]; __syncthreads(); }
  float nrm = fmaxf(sqrtf(red[0]), 1e-12f);
  float kkn = kkv / nrm;
  float av = amat_ain[base];
  float vmv = vmix_bin[base];
  float vv = vio[base];
  kio[base] = kv * (1.0f + (av - 1.0f) * k_a[cc]);
  vio[base] = vv + (vfirst[base] - vv) * vmv;
  amat_ain[base] = -kkn;
  vmix_bin[base] = kkn * av;
}

// ------ wkv scan v6: 1024 blocks (16 v-split siblings/chain, same XCD) x 64 thr ------
static constexpr int CH = 8;

#define LOADSTEP(BUF, S_, Aa, Ww, Kk, Bb, Rr, Vt)                  \
  {                                                                \
    *(float4*)&Aa[0] = *(const float4*)&lds[BUF][3][S_][kb];       \
    *(float4*)&Ww[0] = *(const float4*)&lds[BUF][2][S_][kb];       \
    *(float4*)&Kk[0] = *(const float4*)&lds[BUF][1][S_][kb];       \
    *(float4*)&Bb[0] = *(const float4*)&lds[BUF][4][S_][kb];       \
    *(float4*)&Rr[0] = *(const float4*)&lds[BUF][0][S_][kb];       \
    Vt = vtl[BUF][S_][vl];                                         \
  }

#define COMPSTEP(Aa, Ww, Kk, Bb, Rr, Vt, TIDX)                              \
  {                                                                         \
    float p0 = S[0] * Aa[0], p1 = S[1] * Aa[1];                             \
    p0 = fmaf(S[2], Aa[2], p0);                                             \
    p1 = fmaf(S[3], Aa[3], p1);                                             \
    float sa = p0 + p1;                                                     \
    sa = dpp_xor1_add(sa);                                                  \
    sa = dpp_xor2_add(sa);                                                  \
    sa = dpp_hm_add(sa);                                                    \
    sa = dpp_mir_add(sa);                                                   \
    S[0] = fmaf(S[0], Ww[0], fmaf(Vt, Kk[0], sa * Bb[0]));                  \
    S[1] = fmaf(S[1], Ww[1], fmaf(Vt, Kk[1], sa * Bb[1]));                  \
    S[2] = fmaf(S[2], Ww[2], fmaf(Vt, Kk[2], sa * Bb[2]));                  \
    S[3] = fmaf(S[3], Ww[3], fmaf(Vt, Kk[3], sa * Bb[3]));                  \
    float y0 = S[0] * Rr[0], y1 = S[1] * Rr[1];                             \
    y0 = fmaf(S[2], Rr[2], y0);                                             \
    y1 = fmaf(S[3], Rr[3], y1);                                             \
    float y = y0 + y1;                                                      \
    y = dpp_xor1_add(y);                                                    \
    y = dpp_xor2_add(y);                                                    \
    y = dpp_hm_add(y);                                                      \
    y = dpp_mir_add(y);                                                     \
    if (kq == 0) obf[bh + (size_t)(TIDX)*2048 + v0 + vl] = f2bf(y);         \
  }

__global__ __launch_bounds__(64) void wkv_scan_v6(
    const float* __restrict__ r, const float* __restrict__ k2,
    const float* __restrict__ w, const float* __restrict__ ain,
    const float* __restrict__ bin, const float* __restrict__ vp,
    const float* __restrict__ sInit, unsigned short* __restrict__ obf) {
  __shared__ float lds[2][5][CH][64];      // 20 KiB
  __shared__ float vtl[2][16][4];          // 512 B (rows 8..15 = clamp spill)
  int D = blockIdx.x;
  int chain = (D & 7) + 8 * (D >> 7);      // all 16 siblings share D&7 -> same XCD
  int vblk = (D >> 3) & 15;
  int b = chain >> 5, h = chain & 31;
  int v0 = vblk * 4;
  int lane = threadIdx.x;
  int vl = lane >> 4, kq = lane & 15;
  int kb = kq * 4;
  size_t bh = (size_t)(b * T_) * 2048 + (size_t)h * 64;

  float S[4];
  {
    const float* sp = sInit + (((size_t)chain * 64 + v0 + vl) * 64) + kb;
    float4 s0 = *(const float4*)sp;
    S[0] = s0.x; S[1] = s0.y; S[2] = s0.z; S[3] = s0.w;
  }

  const float* arr[5] = {r, k2, w, ain, bin};

  auto stage = [&](int buf, int t0) {
    #pragma unroll
    for (int a = 0; a < 5; ++a) {
      #pragma unroll
      for (int jj = 0; jj < 2; ++jj) {
        size_t gofs = bh + (size_t)(t0 + jj * 4 + (lane >> 4)) * 2048 + (lane & 15) * 4;
        gload16(arr[a] + gofs, &lds[buf][a][jj * 4][0]);
      }
    }
    {
      int tt = t0 + (lane >> 2);
      if (tt > T_ - 1) tt = T_ - 1;
      size_t gofs = bh + (size_t)tt * 2048 + v0 + (lane & 3);
      gload4(vp + gofs, &vtl[buf][0][0]);
    }
  };

  stage(0, 0);
  asm volatile("s_waitcnt vmcnt(0)" ::: "memory");

  float A0[4], W0[4], K0[4], B0[4], R0[4], vt0;
  float A1[4], W1[4], K1[4], B1[4], R1[4], vt1;

  for (int c = 0; c < T_ / CH; ++c) {
    int cur = c & 1;
    if (c + 1 < T_ / CH) stage(cur ^ 1, (c + 1) * CH);
    int t0 = c * CH;
    LOADSTEP(cur, 0, A0, W0, K0, B0, R0, vt0);
    #pragma unroll 2
    for (int s = 0; s < CH; s += 2) {
      LOADSTEP(cur, s + 1, A1, W1, K1, B1, R1, vt1);
      COMPSTEP(A0, W0, K0, B0, R0, vt0, t0 + s);
      if (s + 2 < CH) LOADSTEP(cur, s + 2, A0, W0, K0, B0, R0, vt0);
      COMPSTEP(A1, W1, K1, B1, R1, vt1, t0 + s + 1);
    }
    asm volatile("s_waitcnt vmcnt(0)" ::: "memory");
  }
}

// ---------------- post: GroupNorm + bonus + gate; one block per (b,t,h) ----------------
__global__ __launch_bounds__(64) void post(
    const unsigned short* __restrict__ obf, const float* __restrict__ r,
    const float* __restrict__ k2, const float* __restrict__ vp,
    const unsigned short* __restrict__ gbf, const float* __restrict__ r_k,
    const float* __restrict__ lnw, const float* __restrict__ lnb,
    float* __restrict__ afin) {
  __shared__ float red[64];
  int bid = blockIdx.x, tid = threadIdx.x;
  int h = bid & 31;
  size_t base = (size_t)bid * 64 + tid;
  int cc = h * 64 + tid;
  float ov = bf2f(obf[base]);
  red[tid] = ov; __syncthreads();
  for (int s = 32; s > 0; s >>= 1) { if (tid < s) red[tid] += red[tid + s]; __syncthreads(); }
  float mu = red[0] * (1.0f / 64.0f);
  __syncthreads();
  float dv = ov - mu;
  red[tid] = dv * dv; __syncthreads();
  for (int s = 32; s > 0; s >>= 1) { if (tid < s) red[tid] += red[tid + s]; __syncthreads(); }
  float var = red[0] * (1.0f / 64.0f);
  __syncthreads();
  float on = dv * rsqrtf(var + 6.4e-4f) * lnw[cc] + lnb[cc];
  float pr = r[base] * k2[base] * r_k[cc];
  red[tid] = pr; __syncthreads();
  for (int s = 32; s > 0; s >>= 1) { if (tid < s) red[tid] += red[tid + s]; __syncthreads(); }
  float dot = red[0];
  float val = (on + dot * vp[base]) * bf2f(gbf[base]);
  afin[base] = val;
}

// ---------------- host ----------------
static constexpr size_t KB = 1024;
static constexpr size_t O_R    = 0;
static constexpr size_t O_K    = 16384;
static constexpr size_t O_V    = 32768;
static constexpr size_t O_WDEC = 49152;
static constexpr size_t O_AMAT = 65536;
static constexpr size_t O_VMIX = 81920;
static constexpr size_t O_AIN  = O_AMAT;
static constexpr size_t O_BIN  = O_VMIX;
static constexpr size_t O_AFIN = O_VMIX;
static constexpr size_t O_WRT_H = 49152, O_WRT_L = 57344;
static constexpr size_t O_WKT_H = 65536, O_WKT_L = 73728;
static constexpr size_t O_WVT_H = 81920, O_WVT_L = 90112;   // ends 98304
static constexpr size_t O_W1T_H = 98304, O_W1T_L = 98560;
static constexpr size_t O_A1T_H = 98816, O_A1T_L = 99072;
static constexpr size_t O_V1T_H = 99328, O_V1T_L = 99456;
static constexpr size_t O_G1T_H = 99584, O_G1T_L = 100096;  // ends 100608
static constexpr size_t O_WOT_H = 0, O_WOT_L = 8192;

extern "C" void kernel_launch(void* const* d_in, const int* in_sizes, int n_in,
                              void* d_out, int out_size, void* d_ws, size_t ws_size,
                              hipStream_t stream) {
  const float* x      = (const float*)d_in[0];
  const float* vfirst = (const float*)d_in[1];
  const float* shift  = (const float*)d_in[2];
  const float* wkv0   = (const float*)d_in[3];
  const float* x_r = (const float*)d_in[4];
  const float* x_w = (const float*)d_in[5];
  const float* x_k = (const float*)d_in[6];
  const float* x_v = (const float*)d_in[7];
  const float* x_a = (const float*)d_in[8];
  const float* x_g = (const float*)d_in[9];
  const float* w0 = (const float*)d_in[10];
  const float* w1 = (const float*)d_in[11];
  const float* w2 = (const float*)d_in[12];
  const float* a0 = (const float*)d_in[13];
  const float* a1 = (const float*)d_in[14];
  const float* a2 = (const float*)d_in[15];
  const float* v0 = (const float*)d_in[16];
  const float* v1 = (const float*)d_in[17];
  const float* v2 = (const float*)d_in[18];
  const float* g1 = (const float*)d_in[19];
  const float* g2 = (const float*)d_in[20];
  const float* k_k = (const float*)d_in[21];
  const float* k_a = (const float*)d_in[22];
  const float* r_k = (const float*)d_in[23];
  const float* W_r = (const float*)d_in[24];
  const float* W_k = (const float*)d_in[25];
  const float* W_v = (const float*)d_in[26];
  const float* W_o = (const float*)d_in[27];
  const float* ln_w = (const float*)d_in[28];
  const float* ln_b = (const float*)d_in[29];

  char* ws = (char*)d_ws;
  auto F = [&](size_t kb) { return (float*)(ws + kb * KB); };
  auto U = [&](size_t kb) { return (unsigned short*)(ws + kb * KB); };
  float* outp = (float*)d_out;
  unsigned short* gbf = (unsigned short*)d_out;                       // 8 MiB
  unsigned short* obf = (unsigned short*)((char*)d_out + 8192 * KB);  // 8 MiB
  float* HW2 = (float*)((char*)d_out + 8192 * KB);                    // 512 KiB
  float* HA2 = (float*)((char*)d_out + 8704 * KB);                    // 512 KiB
  float* HV2 = (float*)((char*)d_out + 9216 * KB);                    // 256 KiB
  float* HG2 = (float*)((char*)d_out + 9472 * KB);                    // 1024 KiB

  // T1: transpose+split ALL seven weights (big + small exact-N).
  {
    TJobs TG{};
    int cum = 0, i = 0;
    auto addT = [&](const float* src, size_t hkb, size_t lkb, int N) {
      int ntn = (N + 63) / 64;
      cum += 32 * ntn;
      TG.j[i++] = TJob{src, U(hkb), U(lkb), N, ntn, cum};
    };
    addT(W_r, O_WRT_H, O_WRT_L, 2048);
    addT(W_k, O_WKT_H, O_WKT_L, 2048);
    addT(W_v, O_WVT_H, O_WVT_L, 2048);
    addT(w1, O_W1T_H, O_W1T_L, 64);
    addT(a1, O_A1T_H, O_A1T_L, 64);
    addT(v1, O_V1T_H, O_V1T_L, 32);
    addT(g1, O_G1T_H, O_G1T_L, 128);
    wtrans<<<dim3(cum), dim3(256), 0, stream>>>(TG);
  }

  // G1 (split MFMA, 128x256 tile): r,k,v + 4 LoRA-downs with fused mixes.
  {
    GJobs G{};
    int cum = 0, i = 0;
    auto add = [&](size_t hkb, size_t lkb, float* Cp, const float* mixv, int N) {
      int ntn = (N + 255) / 256;
      cum += 16 * ntn;
      G.j[i++] = GJob{x, U(hkb), U(lkb), Cp, mixv, shift, N, 2048, ntn, 0, 2048, 0, cum};
    };
    add(O_WRT_H, O_WRT_L, F(O_R), x_r, 2048);
    add(O_WKT_H, O_WKT_L, F(O_K), x_k, 2048);
    add(O_WVT_H, O_WVT_L, F(O_V), x_v, 2048);
    add(O_W1T_H, O_W1T_L, HW2, x_w, 64);
    add(O_A1T_H, O_A1T_L, HA2, x_a, 64);
    add(O_V1T_H, O_V1T_L, HV2, x_v, 32);
    add(O_G1T_H, O_G1T_L, HG2, x_g, 128);
    gemm_w256<<<dim3(cum), dim3(256), 0, stream>>>(G);
  }

  // G2 (fp32 oracle): LoRA-up with fused activations/epilogues. g stored bf16 (epi 3).
  {
    Jobs G{};
    int cum = 0, i = 0;
    auto add = [&](const float* A, const float* W, float* C, const float* bias,
                   int K, int aact, int epi) {
      cum += 32 * 32;
      G.j[i++] = Job{A, W, C, bias, nullptr, nullptr, nullptr, 2048, K, 32, aact, epi, cum};
    };
    add(HW2, w2, F(O_WDEC), w0, 64, 1, 2);
    add(HA2, a2, F(O_AMAT), a0, 64, 0, 1);
    add(HV2, v2, F(O_VMIX), v0, 32, 0, 1);
    add(HG2, g2, (float*)gbf, nullptr, 128, 2, 3);
    gemm_oracle<<<dim3(cum), dim3(256), 0, stream>>>(G);
  }

  // prescan: kk-norm; k->k2, v->v', amat->a_in, vmix->b_in.
  prescan<<<dim3(65536), dim3(64), 0, stream>>>(F(O_K), F(O_V), F(O_AMAT), F(O_VMIX),
                                                vfirst, k_k, k_a);

  // scan v6: 1024 XCD-grouped blocks x 64 threads; o -> bf16 in d_out upper half.
  wkv_scan_v6<<<dim3(1024), dim3(64), 0, stream>>>(F(O_R), F(O_K), F(O_WDEC), F(O_AIN),
                                                   F(O_BIN), F(O_V), wkv0, obf);

  // post: GroupNorm + bonus + gate -> afin (bf16 o/g inputs).
  post<<<dim3(65536), dim3(64), 0, stream>>>(obf, F(O_R), F(O_K), F(O_V),
                                             gbf, r_k, ln_w, ln_b, F(O_AFIN));

  // d_out consumed by post -> zero it for G3's split-K atomic accumulation.
  hipMemsetAsync(d_out, 0, (size_t)16384 * KB, stream);

  // T2: W_o transpose+split into dead r region.
  {
    TJobs TO{};
    TO.j[0] = TJob{W_o, U(O_WOT_H), U(O_WOT_L), 2048, 32, 1024};
    wtrans<<<dim3(1024), dim3(256), 0, stream>>>(TO);
  }

  // G3 (split MFMA 128x256, split-K 2, atomic): out = afin @ W_o.
  {
    GJobs G{};
    G.j[0] = GJob{F(O_AFIN), U(O_WOT_H), U(O_WOT_L), outp, nullptr, nullptr,
                  2048, 2048, 8, 0, 1024, 1, 128};
    G.j[1] = GJob{F(O_AFIN), U(O_WOT_H), U(O_WOT_L), outp, nullptr, nullptr,
                  2048, 2048, 8, 1024, 2048, 1, 256};
    gemm_w256<<<dim3(256), dim3(256), 0, stream>>>(G);
  }

  (void)in_sizes; (void)n_in; (void)out_size; (void)ws_size;
}